// Round 4
// baseline (461.766 us; speedup 1.0000x reference)
//
#include <hip/hip_runtime.h>
#include <math.h>

#define NEG_SLOPE 0.2f
#define LOG2E 1.4426950408889634f

typedef __attribute__((ext_vector_type(8))) short short8;   // 8 bf16 = 4 VGPRs
typedef __attribute__((ext_vector_type(4))) float f32x4;    // MFMA acc

__device__ inline float b2f(unsigned short u) {
    union { unsigned int i; float f; } x; x.i = ((unsigned int)u) << 16; return x.f;
}
__device__ inline float b2f_lo(unsigned int u) {
    union { unsigned int i; float f; } x; x.i = u << 16; return x.f;
}
__device__ inline float b2f_hi(unsigned int u) {
    union { unsigned int i; float f; } x; x.i = u & 0xFFFF0000u; return x.f;
}
__device__ inline unsigned short f2b(float f) {
    union { float f; unsigned int i; } u; u.f = f;
    unsigned int r = u.i + 0x7FFF + ((u.i >> 16) & 1);   // round-to-nearest-even
    return (unsigned short)(r >> 16);
}

// ---------------- combined prep: weight transposes, u1 vectors, and ALL zero-init ----------------
__global__ void prep_kernel(const float* __restrict__ W1, const float* __restrict__ W2,
                            const float* __restrict__ W3, const float* __restrict__ as1,
                            const float* __restrict__ ad1,
                            unsigned short* __restrict__ Wt1, unsigned short* __restrict__ Wt2,
                            unsigned short* __restrict__ Wt3,
                            float* __restrict__ u1s, float* __restrict__ u1d,
                            int* __restrict__ counts, float* __restrict__ pooledP,
                            float* __restrict__ cntP, int N, int G, int zc) {
    const int b = blockIdx.x;
    const int t = threadIdx.x;
    if (b < 64) {
        int i = b * 256 + t;                    // K=64, M=256
        int k = i >> 8, m = i & 255;
        Wt1[(size_t)m * 64 + k] = f2b(W1[i]);
    } else if (b < 320) {
        int i = (b - 64) * 256 + t;             // K=256, M=256
        int k = i >> 8, m = i & 255;
        Wt2[(size_t)m * 256 + k] = f2b(W2[i]);
    } else if (b < 384) {
        int i = (b - 320) * 256 + t;            // K=256, M=64
        int k = i >> 6, m = i & 63;
        Wt3[(size_t)m * 256 + k] = f2b(W3[i]);
    } else if (b == 384) {
        int k = t >> 2, h = t & 3;
        float s = 0.0f, d = 0.0f;
        for (int c = 0; c < 64; c++) {
            float w = W1[k * 256 + h * 64 + c];
            s += w * as1[h * 64 + c];
            d += w * ad1[h * 64 + c];
        }
        u1s[k * 4 + h] = s;
        u1d[k * 4 + h] = d;
    } else if (b < 385 + zc) {
        int i = (b - 385) * 256 + t;
        if (i < N) counts[i] = 0;
    } else {
        int i = (b - 385 - zc) * 256 + t;
        if (i < 64 * G * 64) pooledP[i] = 0.0f;   // [64 partitions][G][64]
        if (i < 64 * G) cntP[i] = 0.0f;           // [64 partitions][G]
    }
}

// ---------------- encoder GEMM: fp32 compute, bf16 out + bias; fused conv1 scores ----------------
__global__ __launch_bounds__(256) void gemm_enc(const float* __restrict__ A,
                                                const float* __restrict__ B,
                                                const float* __restrict__ bias,
                                                unsigned short* __restrict__ C16,
                                                const float* __restrict__ u1s,
                                                const float* __restrict__ u1d,
                                                float* __restrict__ a_s,   // [N,4]
                                                float* __restrict__ a_d,
                                                int Nrows, int K, int M) {
    __shared__ float sA[16][64];
    __shared__ float sB[16][64];
    const int tx = threadIdx.x & 15;
    const int ty = threadIdx.x >> 4;
    const int row0 = blockIdx.x * 64;
    const int lr = threadIdx.x >> 2;
    const int lk = (threadIdx.x & 3) << 2;
    const int br = threadIdx.x >> 4;
    const int bc = (threadIdx.x & 15) << 2;

    const int aRow = row0 + lr;
    const bool aValid = aRow < Nrows;
    const float* Aptr = A + (size_t)aRow * K + lk;
    const float* Bptr = B + (size_t)br * M + bc;

    float acc[4][4] = {{0,0,0,0},{0,0,0,0},{0,0,0,0},{0,0,0,0}};
    float4 a = aValid ? *(const float4*)Aptr : float4{0,0,0,0};
    float4 b = *(const float4*)Bptr;

    for (int kt = 0; kt < K; kt += 16) {
        __syncthreads();
        sA[lk+0][lr] = a.x; sA[lk+1][lr] = a.y; sA[lk+2][lr] = a.z; sA[lk+3][lr] = a.w;
        *(float4*)&sB[br][bc] = b;
        __syncthreads();
        if (kt + 16 < K) {
            a = aValid ? *(const float4*)(Aptr + kt + 16) : float4{0,0,0,0};
            b = *(const float4*)(Bptr + (size_t)(kt + 16) * M);
        }
        #pragma unroll
        for (int k = 0; k < 16; k++) {
            const float4 av = *(const float4*)&sA[k][ty << 2];
            const float4 bv = *(const float4*)&sB[k][tx << 2];
            acc[0][0] += av.x*bv.x; acc[0][1] += av.x*bv.y; acc[0][2] += av.x*bv.z; acc[0][3] += av.x*bv.w;
            acc[1][0] += av.y*bv.x; acc[1][1] += av.y*bv.y; acc[1][2] += av.y*bv.z; acc[1][3] += av.y*bv.w;
            acc[2][0] += av.z*bv.x; acc[2][1] += av.z*bv.y; acc[2][2] += av.z*bv.z; acc[2][3] += av.z*bv.w;
            acc[3][0] += av.w*bv.x; acc[3][1] += av.w*bv.y; acc[3][2] += av.w*bv.z; acc[3][3] += av.w*bv.w;
        }
    }
    float4 bb = *(const float4*)&bias[tx << 2];
    #pragma unroll
    for (int i = 0; i < 4; i++) {
        acc[i][0] += bb.x; acc[i][1] += bb.y; acc[i][2] += bb.z; acc[i][3] += bb.w;
    }
    float4 us[4], ud[4];
    #pragma unroll
    for (int j = 0; j < 4; j++) {
        us[j] = *(const float4*)&u1s[((tx << 2) + j) * 4];
        ud[j] = *(const float4*)&u1d[((tx << 2) + j) * 4];
    }
    #pragma unroll
    for (int i = 0; i < 4; i++) {
        float4 ps = {0,0,0,0}, pd = {0,0,0,0};
        #pragma unroll
        for (int j = 0; j < 4; j++) {
            ps.x += acc[i][j] * us[j].x; ps.y += acc[i][j] * us[j].y;
            ps.z += acc[i][j] * us[j].z; ps.w += acc[i][j] * us[j].w;
            pd.x += acc[i][j] * ud[j].x; pd.y += acc[i][j] * ud[j].y;
            pd.z += acc[i][j] * ud[j].z; pd.w += acc[i][j] * ud[j].w;
        }
        #pragma unroll
        for (int off = 1; off < 16; off <<= 1) {
            ps.x += __shfl_xor(ps.x, off); ps.y += __shfl_xor(ps.y, off);
            ps.z += __shfl_xor(ps.z, off); ps.w += __shfl_xor(ps.w, off);
            pd.x += __shfl_xor(pd.x, off); pd.y += __shfl_xor(pd.y, off);
            pd.z += __shfl_xor(pd.z, off); pd.w += __shfl_xor(pd.w, off);
        }
        int r = row0 + (ty << 2) + i;
        if (tx == 0 && r < Nrows) {
            float4 o1 = {ps.x * LOG2E, ps.y * LOG2E, ps.z * LOG2E, ps.w * LOG2E};
            float4 o2 = {pd.x * LOG2E, pd.y * LOG2E, pd.z * LOG2E, pd.w * LOG2E};
            *(float4*)&a_s[r * 4] = o1;
            *(float4*)&a_d[r * 4] = o2;
        }
    }
    #pragma unroll
    for (int i = 0; i < 4; i++) {
        int r = row0 + (ty << 2) + i;
        if (r < Nrows) {
            ushort4 o = {f2b(acc[i][0]), f2b(acc[i][1]), f2b(acc[i][2]), f2b(acc[i][3])};
            *(ushort4*)&C16[(size_t)r * M + (tx << 2)] = o;
        }
    }
}

// ---------------- MFMA GEMM: C16[N,M] = A16[N,K] @ Wt16^T; optional fused scores ----------------
template<int CPW, int SCORES>
__global__ __launch_bounds__(256) void gemm_mfma(const unsigned short* __restrict__ A16,
                                                 const unsigned short* __restrict__ Bt16,
                                                 unsigned short* __restrict__ C16,
                                                 const float* __restrict__ att_s,
                                                 const float* __restrict__ att_d,
                                                 float* __restrict__ a_s,
                                                 float* __restrict__ a_d,
                                                 int Nrows, int K, int M, int H) {
    constexpr int BN = CPW * 64;
    __shared__ unsigned short sA[64][40];
    __shared__ unsigned short sB[BN][40];
    const int tid = threadIdx.x;
    const int wave = tid >> 6;
    const int lane = tid & 63;
    const int quad = lane >> 4;
    const int l16 = lane & 15;
    const int row0 = blockIdx.x * 64;
    const int col0 = blockIdx.y * BN;
    const int sr = tid >> 2;
    const int sk = (tid & 3) << 3;

    f32x4 acc[4][CPW];
    #pragma unroll
    for (int i = 0; i < 4; i++)
        #pragma unroll
        for (int j = 0; j < CPW; j++) acc[i][j] = (f32x4){0,0,0,0};

    for (int kt = 0; kt < K; kt += 32) {
        __syncthreads();
        {
            int r = row0 + sr;
            uint4 z = {0,0,0,0};
            *(uint4*)&sA[sr][sk] = (r < Nrows) ? *(const uint4*)&A16[(size_t)r * K + kt + sk] : z;
        }
        #pragma unroll
        for (int i = 0; i < CPW; i++) {
            int c = col0 + sr + i * 64;
            *(uint4*)&sB[sr + i * 64][sk] = *(const uint4*)&Bt16[(size_t)c * K + kt + sk];
        }
        __syncthreads();
        short8 bf[CPW];
        #pragma unroll
        for (int j = 0; j < CPW; j++)
            bf[j] = *(const short8*)&sB[wave * (CPW * 16) + j * 16 + l16][quad * 8];
        #pragma unroll
        for (int i = 0; i < 4; i++) {
            short8 af = *(const short8*)&sA[i * 16 + l16][quad * 8];
            #pragma unroll
            for (int j = 0; j < CPW; j++)
                acc[i][j] = __builtin_amdgcn_mfma_f32_16x16x32_bf16(af, bf[j], acc[i][j], 0, 0, 0);
        }
    }
    if (SCORES) {
        __shared__ float sSD[64][CPW][2];
        for (int t = tid; t < 64 * CPW * 2; t += 256) ((float*)sSD)[t] = 0.0f;
        __syncthreads();
        const int hib = (wave * CPW * 16) >> 6;
        float avs[CPW], avd[CPW];
        #pragma unroll
        for (int j = 0; j < CPW; j++) {
            int c = col0 + wave * (CPW * 16) + j * 16 + l16;
            avs[j] = att_s[c];
            avd[j] = att_d[c];
        }
        #pragma unroll
        for (int i = 0; i < 4; i++) {
            float ps[4] = {0,0,0,0}, pd[4] = {0,0,0,0};
            #pragma unroll
            for (int j = 0; j < CPW; j++)
                #pragma unroll
                for (int r = 0; r < 4; r++) {
                    ps[r] += acc[i][j][r] * avs[j];
                    pd[r] += acc[i][j][r] * avd[j];
                }
            #pragma unroll
            for (int off = 1; off < 16; off <<= 1)
                #pragma unroll
                for (int r = 0; r < 4; r++) {
                    ps[r] += __shfl_xor(ps[r], off);
                    pd[r] += __shfl_xor(pd[r], off);
                }
            if (l16 == 0) {
                #pragma unroll
                for (int r = 0; r < 4; r++) {
                    atomicAdd(&sSD[i * 16 + quad * 4 + r][hib][0], ps[r]);
                    atomicAdd(&sSD[i * 16 + quad * 4 + r][hib][1], pd[r]);
                }
            }
        }
        __syncthreads();
        for (int t = tid; t < 64 * CPW; t += 256) {
            int row = t & 63, hb = t >> 6;
            int r = row0 + row;
            if (r < Nrows) {
                int hg = (col0 >> 6) + hb;
                a_s[r * H + hg] = sSD[row][hb][0] * LOG2E;
                a_d[r * H + hg] = sSD[row][hb][1] * LOG2E;
            }
        }
    }
    #pragma unroll
    for (int i = 0; i < 4; i++) {
        #pragma unroll
        for (int j = 0; j < CPW; j++) {
            int col = col0 + wave * (CPW * 16) + j * 16 + l16;
            #pragma unroll
            for (int r = 0; r < 4; r++) {
                int row = row0 + i * 16 + quad * 4 + r;
                if (row < Nrows) C16[(size_t)row * M + col] = f2b(acc[i][j][r]);
            }
        }
    }
}

// ---------------- block-diagonal MFMA GEMM (conv1): out[:,h*64:+64] = ELU(agg_h @ W1_h + b) ----------------
__global__ __launch_bounds__(256) void gemm_bd64(const unsigned short* __restrict__ A16,
                                                 const unsigned short* __restrict__ Bt16,
                                                 const float* __restrict__ bias,
                                                 unsigned short* __restrict__ C16,
                                                 int Nrows) {
    __shared__ unsigned short sA[64][40];
    __shared__ unsigned short sB[64][40];
    const int tid = threadIdx.x;
    const int wave = tid >> 6;
    const int lane = tid & 63;
    const int quad = lane >> 4;
    const int l16 = lane & 15;
    const int h = blockIdx.y;
    const int row0 = blockIdx.x * 64;
    const int sr = tid >> 2;
    const int sk = (tid & 3) << 3;

    f32x4 acc[4];
    #pragma unroll
    for (int i = 0; i < 4; i++) acc[i] = (f32x4){0,0,0,0};

    #pragma unroll
    for (int kt = 0; kt < 64; kt += 32) {
        __syncthreads();
        {
            int r = row0 + sr;
            uint4 z = {0,0,0,0};
            *(uint4*)&sA[sr][sk] = (r < Nrows)
                ? *(const uint4*)&A16[(size_t)r * 256 + h * 64 + kt + sk] : z;
        }
        *(uint4*)&sB[sr][sk] = *(const uint4*)&Bt16[(size_t)(h * 64 + sr) * 64 + kt + sk];
        __syncthreads();
        short8 bf = *(const short8*)&sB[wave * 16 + l16][quad * 8];
        #pragma unroll
        for (int i = 0; i < 4; i++) {
            short8 af = *(const short8*)&sA[i * 16 + l16][quad * 8];
            acc[i] = __builtin_amdgcn_mfma_f32_16x16x32_bf16(af, bf, acc[i], 0, 0, 0);
        }
    }
    const int col = h * 64 + wave * 16 + l16;
    const float bb = bias[col];
    #pragma unroll
    for (int i = 0; i < 4; i++) {
        #pragma unroll
        for (int r = 0; r < 4; r++) {
            int row = row0 + i * 16 + quad * 4 + r;
            if (row < Nrows) {
                float v = acc[i][r] + bb;
                v = (v > 0.0f) ? v : expm1f(v);        // ELU
                C16[(size_t)row * 256 + col] = f2b(v);
            }
        }
    }
}

// ------------- CSR build -------------
__global__ void edge_hist_kernel(const int* __restrict__ ei, int* __restrict__ counts,
                                 int E, int Et) {
    int e = blockIdx.x * 256 + threadIdx.x;
    if (e >= Et) return;
    int d = (e < E) ? ei[E + e] : e - E;
    atomicAdd(&counts[d], 1);
}

__global__ __launch_bounds__(1024) void scan_blocks(int* __restrict__ counts,
                                                    int* __restrict__ blockSums, int N) {
    __shared__ int wsum[16];
    const int tid = threadIdx.x;
    const int lane = tid & 63;
    const int wave = tid >> 6;
    int i = blockIdx.x * 1024 + tid;
    int v = (i < N) ? counts[i] : 0;
    int s = v;
    #pragma unroll
    for (int off = 1; off < 64; off <<= 1) {
        int t = __shfl_up(s, off);
        if (lane >= off) s += t;
    }
    if (lane == 63) wsum[wave] = s;
    __syncthreads();
    if (wave == 0 && lane < 16) {
        int ws = wsum[lane];
        #pragma unroll
        for (int off = 1; off < 16; off <<= 1) {
            int t = __shfl_up(ws, off);
            if (lane >= off) ws += t;
        }
        wsum[lane] = ws;
    }
    __syncthreads();
    int waveOff = (wave > 0) ? wsum[wave - 1] : 0;
    int incl = s + waveOff;
    if (i < N) counts[i] = incl - v;
    if (tid == 1023) blockSums[blockIdx.x] = incl;
}

__global__ void scan_add2(const int* __restrict__ excl, const int* __restrict__ blockSums,
                          int nb, int* __restrict__ offsets, int* __restrict__ cursor,
                          int N, int Et) {
    __shared__ int sbs[64];
    if (threadIdx.x < 64) {
        int lane = threadIdx.x;
        int v = (lane < nb) ? blockSums[lane] : 0;
        int s = v;
        #pragma unroll
        for (int off = 1; off < 64; off <<= 1) {
            int t = __shfl_up(s, off);
            if (lane >= off) s += t;
        }
        sbs[lane] = s - v;                 // exclusive
    }
    __syncthreads();
    int i = blockIdx.x * 256 + threadIdx.x;
    if (i < N) {
        int o = excl[i] + sbs[i >> 10];
        offsets[i] = o;
        cursor[i] = o;
    }
    if (i == N) offsets[N] = Et;
}

__global__ void edge_sort_kernel(const int* __restrict__ ei, int* __restrict__ cursor,
                                 int* __restrict__ srcS, int E, int Et) {
    int e = blockIdx.x * 256 + threadIdx.x;
    if (e >= Et) return;
    int s, d;
    if (e < E) { s = ei[e]; d = ei[E + e]; } else { s = d = e - E; }
    int pos = atomicAdd(&cursor[d], 1);
    srcS[pos] = s;
}

// ------------- conv1 aggregate in INPUT space (64-dim, 4 per-head accumulators) -------------
__global__ __launch_bounds__(256) void gat_agg_in64(
        const int* __restrict__ offsets, const int* __restrict__ srcS,
        const float4* __restrict__ a_s4, const float4* __restrict__ a_d4,
        const unsigned short* __restrict__ h16,    // [N,64]
        unsigned short* __restrict__ out16,        // [N,256] = [head][64]
        int N) {
    __shared__ float wlds[4][64][4];
    __shared__ int slds[4][64];
    const int wid = threadIdx.x >> 6;
    const int n = blockIdx.x * 4 + wid;
    if (n >= N) return;
    const int lane = threadIdx.x & 63;
    const int half = lane >> 5;
    const int l32 = lane & 31;
    const int start = offsets[n], end = offsets[n + 1];
    const float4 ad = a_d4[n];
    float2 acc[4] = {{0,0},{0,0},{0,0},{0,0}};
    float4 den = {0,0,0,0};
    const int loff = l32 << 1;

    for (int e0 = start; e0 < end; e0 += 64) {
        const int cnt = min(64, end - e0);
        if (lane < cnt) {
            int sB = srcS[e0 + lane];
            slds[wid][lane] = sB;
            const float4 as = a_s4[sB];
            float x0 = as.x + ad.x; x0 = fmaxf(x0, NEG_SLOPE * x0);
            float x1 = as.y + ad.y; x1 = fmaxf(x1, NEG_SLOPE * x1);
            float x2 = as.z + ad.z; x2 = fmaxf(x2, NEG_SLOPE * x2);
            float x3 = as.w + ad.w; x3 = fmaxf(x3, NEG_SLOPE * x3);
            wlds[wid][lane][0] = exp2f(x0);
            wlds[wid][lane][1] = exp2f(x1);
            wlds[wid][lane][2] = exp2f(x2);
            wlds[wid][lane][3] = exp2f(x3);
        }
        int j = half;
        for (; j + 8 <= cnt + half; j += 8) {
            int ss[4]; float4 ww[4]; unsigned int gg[4];
            #pragma unroll
            for (int u = 0; u < 4; u++) {
                ss[u] = slds[wid][j + 2 * u];
                ww[u] = *(const float4*)&wlds[wid][j + 2 * u][0];
            }
            #pragma unroll
            for (int u = 0; u < 4; u++)
                gg[u] = *(const unsigned int*)&h16[((size_t)ss[u] << 6) + loff];
            #pragma unroll
            for (int u = 0; u < 4; u++) {
                const float vl = b2f_lo(gg[u]), vh = b2f_hi(gg[u]);
                acc[0].x += ww[u].x * vl; acc[0].y += ww[u].x * vh;
                acc[1].x += ww[u].y * vl; acc[1].y += ww[u].y * vh;
                acc[2].x += ww[u].z * vl; acc[2].y += ww[u].z * vh;
                acc[3].x += ww[u].w * vl; acc[3].y += ww[u].w * vh;
                den.x += ww[u].x; den.y += ww[u].y; den.z += ww[u].z; den.w += ww[u].w;
            }
        }
        for (; j < cnt; j += 2) {
            const int s = slds[wid][j];
            const float4 w = *(const float4*)&wlds[wid][j][0];
            const unsigned int g = *(const unsigned int*)&h16[((size_t)s << 6) + loff];
            const float vl = b2f_lo(g), vh = b2f_hi(g);
            acc[0].x += w.x * vl; acc[0].y += w.x * vh;
            acc[1].x += w.y * vl; acc[1].y += w.y * vh;
            acc[2].x += w.z * vl; acc[2].y += w.z * vh;
            acc[3].x += w.w * vl; acc[3].y += w.w * vh;
            den.x += w.x; den.y += w.y; den.z += w.z; den.w += w.w;
        }
    }
    #pragma unroll
    for (int h = 0; h < 4; h++) {
        acc[h].x += __shfl_xor(acc[h].x, 32);
        acc[h].y += __shfl_xor(acc[h].y, 32);
    }
    den.x += __shfl_xor(den.x, 32); den.y += __shfl_xor(den.y, 32);
    den.z += __shfl_xor(den.z, 32); den.w += __shfl_xor(den.w, 32);
    if (half == 0) {
        const float i0 = 1.0f / (den.x + 1e-16f);
        const float i1 = 1.0f / (den.y + 1e-16f);
        const float i2 = 1.0f / (den.z + 1e-16f);
        const float i3 = 1.0f / (den.w + 1e-16f);
        unsigned int o0 = (unsigned int)f2b(acc[0].x * i0) | ((unsigned int)f2b(acc[0].y * i0) << 16);
        unsigned int o1 = (unsigned int)f2b(acc[1].x * i1) | ((unsigned int)f2b(acc[1].y * i1) << 16);
        unsigned int o2 = (unsigned int)f2b(acc[2].x * i2) | ((unsigned int)f2b(acc[2].y * i2) << 16);
        unsigned int o3 = (unsigned int)f2b(acc[3].x * i3) | ((unsigned int)f2b(acc[3].y * i3) << 16);
        *(unsigned int*)&out16[(size_t)n * 256 + 0 * 64 + loff] = o0;
        *(unsigned int*)&out16[(size_t)n * 256 + 1 * 64 + loff] = o1;
        *(unsigned int*)&out16[(size_t)n * 256 + 2 * 64 + loff] = o2;
        *(unsigned int*)&out16[(size_t)n * 256 + 3 * 64 + loff] = o3;
    }
}

// ------------- conv2 aggregate, HEAD-SPLIT (grid.y = head): gathers 128B/edge from a 6.4MB
// per-pass line working set (vs 25.6MB full-row) for L2 locality. Inner loop clones the
// proven half-wave/4-deep pattern of gat_fused1. +bias+ELU fused. -------------
__global__ __launch_bounds__(256) void gat_fused4h(
        const int* __restrict__ offsets, const int* __restrict__ srcS,
        const float* __restrict__ a_s,   // [N,4]
        const float* __restrict__ a_d,   // [N,4]
        const unsigned short* __restrict__ hW16,   // [N,256]
        const float* __restrict__ bias,            // [256]
        unsigned short* __restrict__ out16,        // [N,256]
        int N) {
    __shared__ float wlds[4][64];
    __shared__ int slds[4][64];
    const int wid = threadIdx.x >> 6;
    const int n = blockIdx.x * 4 + wid;
    if (n >= N) return;
    const int h = blockIdx.y;
    const int lane = threadIdx.x & 63;
    const int half = lane >> 5;
    const int l32 = lane & 31;
    const int start = offsets[n], end = offsets[n + 1];
    const float ad = a_d[n * 4 + h];
    float accx = 0.0f, accy = 0.0f, den = 0.0f;
    const int loff = l32 << 1;                       // channel pair within head
    const size_t colbase = (size_t)h * 64 + loff;    // offset within 256-ch row

    for (int e0 = start; e0 < end; e0 += 64) {
        const int cnt_ = min(64, end - e0);
        if (lane < cnt_) {
            int sB = srcS[e0 + lane];
            slds[wid][lane] = sB;
            float ev = a_s[sB * 4 + h] + ad;
            ev = fmaxf(ev, NEG_SLOPE * ev);
            wlds[wid][lane] = exp2f(ev);
        }
        int j = half;
        for (; j + 8 <= cnt_ + half; j += 8) {
            const int s0 = slds[wid][j + 0];
            const int s1 = slds[wid][j + 2];
            const int s2 = slds[wid][j + 4];
            const int s3 = slds[wid][j + 6];
            const float w0 = wlds[wid][j + 0];
            const float w1 = wlds[wid][j + 2];
            const float w2 = wlds[wid][j + 4];
            const float w3 = wlds[wid][j + 6];
            const unsigned int h0 = *(const unsigned int*)&hW16[((size_t)s0 << 8) + colbase];
            const unsigned int h1 = *(const unsigned int*)&hW16[((size_t)s1 << 8) + colbase];
            const unsigned int h2 = *(const unsigned int*)&hW16[((size_t)s2 << 8) + colbase];
            const unsigned int h3 = *(const unsigned int*)&hW16[((size_t)s3 << 8) + colbase];
            accx += w0 * b2f_lo(h0); accy += w0 * b2f_hi(h0);
            accx += w1 * b2f_lo(h1); accy += w1 * b2f_hi(h1);
            accx += w2 * b2f_lo(h2); accy += w2 * b2f_hi(h2);
            accx += w3 * b2f_lo(h3); accy += w3 * b2f_hi(h3);
            den += (w0 + w1) + (w2 + w3);
        }
        for (; j < cnt_; j += 2) {
            const int s = slds[wid][j];
            const float w = wlds[wid][j];
            const unsigned int hv = *(const unsigned int*)&hW16[((size_t)s << 8) + colbase];
            accx += w * b2f_lo(hv);
            accy += w * b2f_hi(hv);
            den += w;
        }
    }
    accx += __shfl_xor(accx, 32);
    accy += __shfl_xor(accy, 32);
    den  += __shfl_xor(den, 32);
    if (half == 0) {
        const float inv = 1.0f / (den + 1e-16f);
        const float2 bb = *(const float2*)&bias[h * 64 + loff];
        float v0 = accx * inv + bb.x; v0 = (v0 > 0.0f) ? v0 : expm1f(v0);
        float v1 = accy * inv + bb.y; v1 = (v1 > 0.0f) ? v1 : expm1f(v1);
        unsigned int o = (unsigned int)f2b(v0) | ((unsigned int)f2b(v1) << 16);
        *(unsigned int*)&out16[(size_t)n * 256 + h * 64 + loff] = o;
    }
}

// ------------- H=1 fused (conv3): wave/node gather + PARTITIONED fused mean-pool -------------
// Block pre-reduces its 4 nodes, then atomics into partition (blockIdx & 63):
// chain depth per (partition,address) ~ 12  (vs 781 unpartitioned -> 175us stall).
__global__ __launch_bounds__(256) void gat_fused1(
        const int* __restrict__ offsets, const int* __restrict__ srcS,
        const float* __restrict__ a_s, const float* __restrict__ a_d,
        const unsigned short* __restrict__ hW16, const float* __restrict__ bias,
        const int* __restrict__ batch,
        float* __restrict__ pooledP, float* __restrict__ cntP, int N, int G) {
    __shared__ float wlds[4][64];
    __shared__ int slds[4][64];
    __shared__ float2 sOut[4][32];
    __shared__ int sG[4];
    const int wid = threadIdx.x >> 6;
    const int n = blockIdx.x * 4 + wid;
    const bool valid = n < N;                  // no early return: all waves reach the barrier
    const int lane = threadIdx.x & 63;
    const int half = lane >> 5;
    const int l32 = lane & 31;
    const int start = valid ? offsets[n] : 0;
    const int end   = valid ? offsets[n + 1] : 0;
    const float ad  = valid ? a_d[n] : 0.0f;
    float accx = 0.0f, accy = 0.0f, den = 0.0f;
    const int loff = l32 << 1;

    for (int e0 = start; e0 < end; e0 += 64) {
        const int cnt_ = min(64, end - e0);
        if (lane < cnt_) {
            int sB = srcS[e0 + lane];
            slds[wid][lane] = sB;
            float ev = a_s[sB] + ad;
            ev = fmaxf(ev, NEG_SLOPE * ev);
            wlds[wid][lane] = exp2f(ev);
        }
        int j = half;
        for (; j + 8 <= cnt_ + half; j += 8) {
            const int s0 = slds[wid][j + 0];
            const int s1 = slds[wid][j + 2];
            const int s2 = slds[wid][j + 4];
            const int s3 = slds[wid][j + 6];
            const float w0 = wlds[wid][j + 0];
            const float w1 = wlds[wid][j + 2];
            const float w2 = wlds[wid][j + 4];
            const float w3 = wlds[wid][j + 6];
            const unsigned int h0 = *(const unsigned int*)&hW16[((size_t)s0 << 6) + loff];
            const unsigned int h1 = *(const unsigned int*)&hW16[((size_t)s1 << 6) + loff];
            const unsigned int h2 = *(const unsigned int*)&hW16[((size_t)s2 << 6) + loff];
            const unsigned int h3 = *(const unsigned int*)&hW16[((size_t)s3 << 6) + loff];
            accx += w0 * b2f_lo(h0); accy += w0 * b2f_hi(h0);
            accx += w1 * b2f_lo(h1); accy += w1 * b2f_hi(h1);
            accx += w2 * b2f_lo(h2); accy += w2 * b2f_hi(h2);
            accx += w3 * b2f_lo(h3); accy += w3 * b2f_hi(h3);
            den += (w0 + w1) + (w2 + w3);
        }
        for (; j < cnt_; j += 2) {
            const int s = slds[wid][j];
            const float w = wlds[wid][j];
            const unsigned int hv = *(const unsigned int*)&hW16[((size_t)s << 6) + loff];
            accx += w * b2f_lo(hv);
            accy += w * b2f_hi(hv);
            den += w;
        }
    }
    accx += __shfl_xor(accx, 32);
    accy += __shfl_xor(accy, 32);
    den  += __shfl_xor(den, 32);
    if (half == 0) {
        if (valid) {
            const float inv = 1.0f / (den + 1e-16f);
            sOut[wid][l32] = (float2){accx * inv + bias[loff], accy * inv + bias[loff + 1]};
        } else {
            sOut[wid][l32] = (float2){0.0f, 0.0f};
        }
        if (l32 == 0) sG[wid] = valid ? batch[n] : -1;
    }
    __syncthreads();
    const int p = blockIdx.x & 63;
    if (wid == 0 && half == 0) {
        const int g0 = sG[0], g1 = sG[1], g2 = sG[2], g3 = sG[3];
        if (g0 >= 0 && g1 == g0 && g2 == g0 && g3 == g0) {
            const float2 s0 = sOut[0][l32], s1 = sOut[1][l32];
            const float2 s2 = sOut[2][l32], s3 = sOut[3][l32];
            float* base = pooledP + ((size_t)p * G + g0) * 64;
            atomicAdd(&base[loff],     (s0.x + s1.x) + (s2.x + s3.x));
            atomicAdd(&base[loff + 1], (s0.y + s1.y) + (s2.y + s3.y));
            if (l32 == 0) atomicAdd(&cntP[p * G + g0], 4.0f);
        } else {
            #pragma unroll
            for (int w = 0; w < 4; w++) {
                const int g = sG[w];
                if (g >= 0) {
                    const float2 s = sOut[w][l32];
                    float* base = pooledP + ((size_t)p * G + g) * 64;
                    atomicAdd(&base[loff], s.x);
                    atomicAdd(&base[loff + 1], s.y);
                    if (l32 == 0) atomicAdd(&cntP[p * G + g], 1.0f);
                }
            }
        }
    }
}

// ------------- decoder head: one block per graph (reduces 64 pool partitions first) -------------
__global__ __launch_bounds__(256) void final_kernel(
        const float* __restrict__ pooledP, const float* __restrict__ cntP,
        const float* __restrict__ gf, const float* __restrict__ Wg,
        const float* __restrict__ bg, const float* __restrict__ Wd1,
        const float* __restrict__ bd1, const float* __restrict__ gamma,
        const float* __restrict__ beta, const float* __restrict__ Wd2,
        const float* __restrict__ bd2, float* __restrict__ out, int G) {
    const int g = blockIdx.x;
    const int tid = threadIdx.x;
    const int lane = tid & 63;
    const int wave = tid >> 6;
    __shared__ float sPart[4][64];
    __shared__ float sCntTot;
    __shared__ float spg[128];
    __shared__ float sz[64];
    __shared__ float wred[8];

    {   // partition reduce: wave pg sums partitions [pg*16, pg*16+16)
        const int c = lane;
        const int pg = wave;
        float a = 0.0f;
        #pragma unroll
        for (int p = 0; p < 16; p++)
            a += pooledP[((size_t)(pg * 16 + p) * G + g) * 64 + c];
        sPart[pg][c] = a;
        if (pg == 1) {
            float cv = cntP[c * G + g];
            #pragma unroll
            for (int off = 32; off > 0; off >>= 1) cv += __shfl_xor(cv, off);
            if (c == 0) sCntTot = cv;
        }
    }
    __syncthreads();
    if (tid < 64) {
        spg[tid] = (sPart[0][tid] + sPart[1][tid] + sPart[2][tid] + sPart[3][tid])
                   / fmaxf(sCntTot, 1.0f);
    } else if (tid < 128) {
        int c = tid - 64;
        float v = bg[c];
        #pragma unroll
        for (int k = 0; k < 4; k++) v += gf[g * 4 + k] * Wg[k * 64 + c];
        spg[64 + c] = fmaxf(v, 0.0f);
    }
    __syncthreads();
    if (tid < 64) {
        float v = bd1[tid];
        #pragma unroll 8
        for (int k = 0; k < 128; k++) v += spg[k] * Wd1[k * 64 + tid];
        v = v * gamma[tid] + beta[tid];
        sz[tid] = fmaxf(v, 0.0f);
    }
    __syncthreads();
    float v = bd2[tid];
    #pragma unroll 8
    for (int k = 0; k < 64; k++) v += sz[k] * Wd2[k * 256 + tid];
    float m = v;
    #pragma unroll
    for (int off = 32; off > 0; off >>= 1) m = fmaxf(m, __shfl_xor(m, off));
    if (lane == 0) wred[wave] = m;
    __syncthreads();
    float M = fmaxf(fmaxf(wred[0], wred[1]), fmaxf(wred[2], wred[3]));
    float e = expf(v - M);
    float s = e;
    #pragma unroll
    for (int off = 32; off > 0; off >>= 1) s += __shfl_xor(s, off);
    if (lane == 0) wred[4 + wave] = s;
    __syncthreads();
    float S = (wred[4] + wred[5]) + (wred[6] + wred[7]);
    out[g * 256 + tid] = e / S;
}

extern "C" void kernel_launch(void* const* d_in, const int* in_sizes, int n_in,
                              void* d_out, int out_size, void* d_ws, size_t ws_size,
                              hipStream_t stream) {
    const float* x     = (const float*)d_in[0];
    const int*   ei    = (const int*)  d_in[1];
    const int*   batch = (const int*)  d_in[2];
    const float* gf    = (const float*)d_in[3];
    const float* W_enc = (const float*)d_in[4];
    const float* b_enc = (const float*)d_in[5];
    const float* W1  = (const float*)d_in[6];
    const float* as1 = (const float*)d_in[7];
    const float* ad1 = (const float*)d_in[8];
    const float* b1  = (const float*)d_in[9];
    const float* W2  = (const float*)d_in[10];
    const float* as2 = (const float*)d_in[11];
    const float* ad2 = (const float*)d_in[12];
    const float* b2  = (const float*)d_in[13];
    const float* W3  = (const float*)d_in[14];
    const float* as3 = (const float*)d_in[15];
    const float* ad3 = (const float*)d_in[16];
    const float* b3  = (const float*)d_in[17];
    const float* Wg  = (const float*)d_in[18];
    const float* bg  = (const float*)d_in[19];
    const float* Wd1 = (const float*)d_in[20];
    const float* bd1 = (const float*)d_in[21];
    const float* gm  = (const float*)d_in[22];
    const float* bt  = (const float*)d_in[23];
    const float* Wd2 = (const float*)d_in[24];
    const float* bd2 = (const float*)d_in[25];

    const int N  = in_sizes[2];
    const int E  = in_sizes[1] / 2;
    const int G  = in_sizes[3] / 4;
    const int Et = E + N;

    unsigned short* h16a = (unsigned short*)d_ws;                // [N,256] bf16
    unsigned short* h16b = h16a + (size_t)N * 256;               // [N,256] bf16
    unsigned short* h1_16 = h16b + (size_t)N * 256;              // [N,64] bf16
    unsigned short* Wt1  = h1_16 + (size_t)N * 64;               // [256,64]
    unsigned short* Wt2  = Wt1 + 256 * 64;                       // [256,256]
    unsigned short* Wt3  = Wt2 + 256 * 256;                      // [64,256]
    float* a_s    = (float*)(Wt3 + 64 * 256);                    // [N,4]
    float* a_d    = a_s + (size_t)N * 4;                         // [N,4]
    float* u1s    = a_d + (size_t)N * 4;                         // [64,4]
    float* u1d    = u1s + 256;                                   // [64,4]
    float* pooledP = u1d + 256;                                  // [64][G][64]
    float* cntP   = pooledP + (size_t)64 * G * 64;               // [64][G]
    int*   offsets = (int*)(cntP + 64 * G);                      // [N+1]
    int*   srcS    = offsets + (N + 1);                          // [Et]
    int*   counts  = srcS + Et;                                  // [N]
    int*   cursor  = counts + N;                                 // [N]
    int*   blockSums = cursor + N;                               // [cdiv(N,1024)]

    dim3 blk(256);
    auto cdiv = [](int a, int b) { return (a + b - 1) / b; };
    const int eBlocks = cdiv(Et, 256);
    const int rowBlocks = cdiv(N, 64);
    const int nScanBlocks = cdiv(N, 1024);
    const int zc = cdiv(N, 256);
    const int z2 = cdiv(64 * G * 64, 256);

    // ---------------- prep (weights + zero-init) + CSR build ----------------
    prep_kernel<<<385 + zc + z2, blk, 0, stream>>>(W1, W2, W3, as1, ad1, Wt1, Wt2, Wt3,
                                                   u1s, u1d, counts, pooledP, cntP, N, G, zc);
    edge_hist_kernel<<<eBlocks, blk, 0, stream>>>(ei, counts, E, Et);
    scan_blocks<<<nScanBlocks, 1024, 0, stream>>>(counts, blockSums, N);
    scan_add2<<<cdiv(N + 1, 256), blk, 0, stream>>>(counts, blockSums, nScanBlocks,
                                                    offsets, cursor, N, Et);
    edge_sort_kernel<<<eBlocks, blk, 0, stream>>>(ei, cursor, srcS, E, Et);

    // encoder: x -> h1 bf16, + fused conv1 scores
    gemm_enc<<<dim3(rowBlocks, 1), blk, 0, stream>>>(x, W_enc, b_enc, h1_16,
                                                     u1s, u1d, a_s, a_d, N, 32, 64);

    // ---------------- conv1: aggregate in input space, then block-diag GEMM ----------------
    gat_agg_in64<<<cdiv(N, 4), blk, 0, stream>>>(offsets, srcS, (const float4*)a_s,
                                                 (const float4*)a_d, h1_16, h16a, N);
    gemm_bd64<<<dim3(rowBlocks, 4), blk, 0, stream>>>(h16a, Wt1, b1, h16b, N);

    // ---------------- conv2: GEMM (+fused scores) -> head-split aggregate ----------------
    gemm_mfma<2, 1><<<dim3(rowBlocks, 2), blk, 0, stream>>>(h16b, Wt2, h16a,
                                                            as2, ad2, a_s, a_d, N, 256, 256, 4);
    gat_fused4h<<<dim3(cdiv(N, 4), 4), blk, 0, stream>>>(offsets, srcS, a_s, a_d,
                                                         h16a, b2, h16b, N);

    // ---------------- conv3: GEMM (+fused scores) -> aggregate + partitioned pool ----------------
    gemm_mfma<1, 1><<<dim3(rowBlocks, 1), blk, 0, stream>>>(h16b, Wt3, h1_16,
                                                            as3, ad3, a_s, a_d, N, 256, 64, 1);
    gat_fused1<<<cdiv(N, 4), blk, 0, stream>>>(offsets, srcS, a_s, a_d, h1_16, b3,
                                               batch, pooledP, cntP, N, G);

    // ---------------- decoder head ----------------
    final_kernel<<<G, blk, 0, stream>>>(pooledP, cntP, gf, Wg, bg, Wd1, bd1, gm, bt, Wd2, bd2,
                                        (float*)d_out, G);
}

// Round 5
// 424.640 us; speedup vs baseline: 1.0874x; 1.0874x over previous
//
#include <hip/hip_runtime.h>
#include <math.h>

#define NEG_SLOPE 0.2f
#define LOG2E 1.4426950408889634f

typedef __attribute__((ext_vector_type(8))) short short8;   // 8 bf16 = 4 VGPRs
typedef __attribute__((ext_vector_type(4))) float f32x4;    // MFMA acc

__device__ inline float b2f_lo(unsigned int u) {
    union { unsigned int i; float f; } x; x.i = u << 16; return x.f;
}
__device__ inline float b2f_hi(unsigned int u) {
    union { unsigned int i; float f; } x; x.i = u & 0xFFFF0000u; return x.f;
}
__device__ inline unsigned short f2b(float f) {
    union { float f; unsigned int i; } u; u.f = f;
    unsigned int r = u.i + 0x7FFF + ((u.i >> 16) & 1);   // round-to-nearest-even
    return (unsigned short)(r >> 16);
}

// ---------------- prep: folded conv1 weights (Wc1 = W_enc@W1, bc1), u1 vectors,
// Wt2/Wt3 transposes, and ALL zero-init ----------------
__global__ void prep_kernel(const float* __restrict__ W_enc, const float* __restrict__ b_enc,
                            const float* __restrict__ W1, const float* __restrict__ W2,
                            const float* __restrict__ W3, const float* __restrict__ as1,
                            const float* __restrict__ ad1, const float* __restrict__ b1,
                            unsigned short* __restrict__ Wc1t, float* __restrict__ bc1,
                            unsigned short* __restrict__ Wt2, unsigned short* __restrict__ Wt3,
                            float* __restrict__ u1s, float* __restrict__ u1d,
                            int* __restrict__ counts, float* __restrict__ pooledP,
                            float* __restrict__ cntP, int N, int G, int zc) {
    const int b = blockIdx.x;
    const int t = threadIdx.x;
    if (b < 32) {
        // Wc1t[h][o][j] = sum_k W_enc[j][k] * W1[k][h*64+o]   (bf16, B^T layout for bd32)
        int i = b * 256 + t;                       // 8192 values
        int h = i >> 11, rem = i & 2047, o = rem >> 5, j = rem & 31;
        float s = 0.0f;
        for (int k = 0; k < 64; k++)
            s += W_enc[j * 64 + k] * W1[k * 256 + h * 64 + o];
        Wc1t[i] = f2b(s);
    } else if (b == 32) {
        // bc1[c] = b1[c] + sum_k b_enc[k] * W1[k][c]   (uses sum(alpha)=1)
        float s = b1[t];
        for (int k = 0; k < 64; k++) s += b_enc[k] * W1[k * 256 + t];
        bc1[t] = s;
    } else if (b == 33) {
        // u1 score projections in h1-space (consumed by score_x to build x-space proj)
        int k = t >> 2, h = t & 3;
        float s = 0.0f, d = 0.0f;
        for (int c = 0; c < 64; c++) {
            float w = W1[k * 256 + h * 64 + c];
            s += w * as1[h * 64 + c];
            d += w * ad1[h * 64 + c];
        }
        u1s[k * 4 + h] = s;
        u1d[k * 4 + h] = d;
    } else if (b < 34 + 256) {
        int i = (b - 34) * 256 + t;                // K=256, M=256
        int k = i >> 8, m = i & 255;
        Wt2[(size_t)m * 256 + k] = f2b(W2[i]);
    } else if (b < 34 + 256 + 64) {
        int i = (b - 290) * 256 + t;               // K=256, M=64
        int k = i >> 6, m = i & 63;
        Wt3[(size_t)m * 256 + k] = f2b(W3[i]);
    } else if (b < 354 + zc) {
        int i = (b - 354) * 256 + t;
        if (i < N) counts[i] = 0;
    } else {
        int i = (b - 354 - zc) * 256 + t;
        if (i < 64 * G * 64) pooledP[i] = 0.0f;    // [64 partitions][G][64]
        if (i < 64 * G) cntP[i] = 0.0f;            // [64 partitions][G]
    }
}

// ---------------- score_x: conv1 scores directly from x (a = x*(W_enc@u1) + b_enc@u1),
// plus x -> bf16 conversion. Replaces the whole encoder GEMM. ----------------
__global__ __launch_bounds__(256) void score_x(
        const float* __restrict__ x, const float* __restrict__ W_enc,
        const float* __restrict__ b_enc,
        const float* __restrict__ u1s, const float* __restrict__ u1d,
        unsigned short* __restrict__ x16, float* __restrict__ a_s,
        float* __restrict__ a_d, int N) {
    __shared__ float sUs[32][4], sUd[32][4], sC[8];
    __shared__ float sX[32][33];
    const int t = threadIdx.x;
    if (t < 128) {
        int j = t >> 2, h = t & 3;
        float s = 0.0f, d = 0.0f;
        for (int k = 0; k < 64; k++) {
            float w = W_enc[j * 64 + k];
            s += w * u1s[k * 4 + h];
            d += w * u1d[k * 4 + h];
        }
        sUs[j][h] = s; sUd[j][h] = d;
    } else if (t < 136) {
        int hh = t - 128;                           // 0..3 -> s, 4..7 -> d
        const float* u = (hh < 4) ? u1s : u1d;
        int h = hh & 3;
        float c = 0.0f;
        for (int k = 0; k < 64; k++) c += b_enc[k] * u[k * 4 + h];
        sC[hh] = c;
    }
    const int n0 = blockIdx.x * 32;
    const int row = t >> 3, col = (t & 7) << 2;
    float4 xv = {0, 0, 0, 0};
    if (n0 + row < N) xv = *(const float4*)&x[(size_t)(n0 + row) * 32 + col];
    sX[row][col + 0] = xv.x; sX[row][col + 1] = xv.y;
    sX[row][col + 2] = xv.z; sX[row][col + 3] = xv.w;
    __syncthreads();
    const int ni = t >> 3, oi = t & 7, h = oi & 3;
    const bool isS = oi < 4;
    float acc = sC[oi];
    #pragma unroll 8
    for (int j = 0; j < 32; j++) acc += sX[ni][j] * (isS ? sUs[j][h] : sUd[j][h]);
    if (n0 + ni < N) {
        float* out = isS ? a_s : a_d;
        out[(size_t)(n0 + ni) * 4 + h] = acc * LOG2E;
    }
    if (n0 + row < N) {
        ushort4 o = {f2b(xv.x), f2b(xv.y), f2b(xv.z), f2b(xv.w)};
        *(ushort4*)&x16[(size_t)(n0 + row) * 32 + col] = o;
    }
}

// ---------------- MFMA GEMM: C16[N,M] = A16[N,K] @ Wt16^T; optional fused scores ----------------
template<int CPW, int SCORES>
__global__ __launch_bounds__(256) void gemm_mfma(const unsigned short* __restrict__ A16,
                                                 const unsigned short* __restrict__ Bt16,
                                                 unsigned short* __restrict__ C16,
                                                 const float* __restrict__ att_s,
                                                 const float* __restrict__ att_d,
                                                 float* __restrict__ a_s,
                                                 float* __restrict__ a_d,
                                                 int Nrows, int K, int M, int H) {
    constexpr int BN = CPW * 64;
    __shared__ unsigned short sA[64][40];
    __shared__ unsigned short sB[BN][40];
    const int tid = threadIdx.x;
    const int wave = tid >> 6;
    const int lane = tid & 63;
    const int quad = lane >> 4;
    const int l16 = lane & 15;
    const int row0 = blockIdx.x * 64;
    const int col0 = blockIdx.y * BN;
    const int sr = tid >> 2;
    const int sk = (tid & 3) << 3;

    f32x4 acc[4][CPW];
    #pragma unroll
    for (int i = 0; i < 4; i++)
        #pragma unroll
        for (int j = 0; j < CPW; j++) acc[i][j] = (f32x4){0,0,0,0};

    for (int kt = 0; kt < K; kt += 32) {
        __syncthreads();
        {
            int r = row0 + sr;
            uint4 z = {0,0,0,0};
            *(uint4*)&sA[sr][sk] = (r < Nrows) ? *(const uint4*)&A16[(size_t)r * K + kt + sk] : z;
        }
        #pragma unroll
        for (int i = 0; i < CPW; i++) {
            int c = col0 + sr + i * 64;
            *(uint4*)&sB[sr + i * 64][sk] = *(const uint4*)&Bt16[(size_t)c * K + kt + sk];
        }
        __syncthreads();
        short8 bf[CPW];
        #pragma unroll
        for (int j = 0; j < CPW; j++)
            bf[j] = *(const short8*)&sB[wave * (CPW * 16) + j * 16 + l16][quad * 8];
        #pragma unroll
        for (int i = 0; i < 4; i++) {
            short8 af = *(const short8*)&sA[i * 16 + l16][quad * 8];
            #pragma unroll
            for (int j = 0; j < CPW; j++)
                acc[i][j] = __builtin_amdgcn_mfma_f32_16x16x32_bf16(af, bf[j], acc[i][j], 0, 0, 0);
        }
    }
    if (SCORES) {
        __shared__ float sSD[64][CPW][2];
        for (int t = tid; t < 64 * CPW * 2; t += 256) ((float*)sSD)[t] = 0.0f;
        __syncthreads();
        const int hib = (wave * CPW * 16) >> 6;
        float avs[CPW], avd[CPW];
        #pragma unroll
        for (int j = 0; j < CPW; j++) {
            int c = col0 + wave * (CPW * 16) + j * 16 + l16;
            avs[j] = att_s[c];
            avd[j] = att_d[c];
        }
        #pragma unroll
        for (int i = 0; i < 4; i++) {
            float ps[4] = {0,0,0,0}, pd[4] = {0,0,0,0};
            #pragma unroll
            for (int j = 0; j < CPW; j++)
                #pragma unroll
                for (int r = 0; r < 4; r++) {
                    ps[r] += acc[i][j][r] * avs[j];
                    pd[r] += acc[i][j][r] * avd[j];
                }
            #pragma unroll
            for (int off = 1; off < 16; off <<= 1)
                #pragma unroll
                for (int r = 0; r < 4; r++) {
                    ps[r] += __shfl_xor(ps[r], off);
                    pd[r] += __shfl_xor(pd[r], off);
                }
            if (l16 == 0) {
                #pragma unroll
                for (int r = 0; r < 4; r++) {
                    atomicAdd(&sSD[i * 16 + quad * 4 + r][hib][0], ps[r]);
                    atomicAdd(&sSD[i * 16 + quad * 4 + r][hib][1], pd[r]);
                }
            }
        }
        __syncthreads();
        for (int t = tid; t < 64 * CPW; t += 256) {
            int row = t & 63, hb = t >> 6;
            int r = row0 + row;
            if (r < Nrows) {
                int hg = (col0 >> 6) + hb;
                a_s[r * H + hg] = sSD[row][hb][0] * LOG2E;
                a_d[r * H + hg] = sSD[row][hb][1] * LOG2E;
            }
        }
    }
    #pragma unroll
    for (int i = 0; i < 4; i++) {
        #pragma unroll
        for (int j = 0; j < CPW; j++) {
            int col = col0 + wave * (CPW * 16) + j * 16 + l16;
            #pragma unroll
            for (int r = 0; r < 4; r++) {
                int row = row0 + i * 16 + quad * 4 + r;
                if (row < Nrows) C16[(size_t)row * M + col] = f2b(acc[i][j][r]);
            }
        }
    }
}

// ---------------- block-diag MFMA GEMM (conv1, folded): out[:,h*64:+64] = ELU(aggX_h @ Wc1_h + bc1)
// K=32: single MFMA k-step. ----------------
__global__ __launch_bounds__(256) void gemm_bd32(const unsigned short* __restrict__ A16, // [N,128]
                                                 const unsigned short* __restrict__ Bt16,// [4][64][32]
                                                 const float* __restrict__ bias,         // [256]
                                                 unsigned short* __restrict__ C16,       // [N,256]
                                                 int Nrows) {
    __shared__ unsigned short sA[64][40];
    __shared__ unsigned short sB[64][40];
    const int tid = threadIdx.x;
    const int wave = tid >> 6;
    const int lane = tid & 63;
    const int quad = lane >> 4;
    const int l16 = lane & 15;
    const int h = blockIdx.y;
    const int row0 = blockIdx.x * 64;
    const int sr = tid >> 2;
    const int sk = (tid & 3) << 3;

    {
        int r = row0 + sr;
        uint4 z = {0,0,0,0};
        *(uint4*)&sA[sr][sk] = (r < Nrows)
            ? *(const uint4*)&A16[(size_t)r * 128 + h * 32 + sk] : z;
        *(uint4*)&sB[sr][sk] = *(const uint4*)&Bt16[(size_t)(h * 64 + sr) * 32 + sk];
    }
    __syncthreads();
    short8 bf = *(const short8*)&sB[wave * 16 + l16][quad * 8];
    f32x4 acc[4];
    #pragma unroll
    for (int i = 0; i < 4; i++) {
        short8 af = *(const short8*)&sA[i * 16 + l16][quad * 8];
        acc[i] = __builtin_amdgcn_mfma_f32_16x16x32_bf16(af, bf, (f32x4){0,0,0,0}, 0, 0, 0);
    }
    const int col = h * 64 + wave * 16 + l16;
    const float bb = bias[col];
    #pragma unroll
    for (int i = 0; i < 4; i++) {
        #pragma unroll
        for (int r = 0; r < 4; r++) {
            int row = row0 + i * 16 + quad * 4 + r;
            if (row < Nrows) {
                float v = acc[i][r] + bb;
                v = (v > 0.0f) ? v : expm1f(v);        // ELU
                C16[(size_t)row * 256 + col] = f2b(v);
            }
        }
    }
}

// ------------- CSR build -------------
__global__ void edge_hist_kernel(const int* __restrict__ ei, int* __restrict__ counts,
                                 int E, int Et) {
    int e = blockIdx.x * 256 + threadIdx.x;
    if (e >= Et) return;
    int d = (e < E) ? ei[E + e] : e - E;
    atomicAdd(&counts[d], 1);
}

__global__ __launch_bounds__(1024) void scan_blocks(int* __restrict__ counts,
                                                    int* __restrict__ blockSums, int N) {
    __shared__ int wsum[16];
    const int tid = threadIdx.x;
    const int lane = tid & 63;
    const int wave = tid >> 6;
    int i = blockIdx.x * 1024 + tid;
    int v = (i < N) ? counts[i] : 0;
    int s = v;
    #pragma unroll
    for (int off = 1; off < 64; off <<= 1) {
        int t = __shfl_up(s, off);
        if (lane >= off) s += t;
    }
    if (lane == 63) wsum[wave] = s;
    __syncthreads();
    if (wave == 0 && lane < 16) {
        int ws = wsum[lane];
        #pragma unroll
        for (int off = 1; off < 16; off <<= 1) {
            int t = __shfl_up(ws, off);
            if (lane >= off) ws += t;
        }
        wsum[lane] = ws;
    }
    __syncthreads();
    int waveOff = (wave > 0) ? wsum[wave - 1] : 0;
    int incl = s + waveOff;
    if (i < N) counts[i] = incl - v;
    if (tid == 1023) blockSums[blockIdx.x] = incl;
}

__global__ void scan_add2(const int* __restrict__ excl, const int* __restrict__ blockSums,
                          int nb, int* __restrict__ offsets, int* __restrict__ cursor,
                          int N, int Et) {
    __shared__ int sbs[64];
    if (threadIdx.x < 64) {
        int lane = threadIdx.x;
        int v = (lane < nb) ? blockSums[lane] : 0;
        int s = v;
        #pragma unroll
        for (int off = 1; off < 64; off <<= 1) {
            int t = __shfl_up(s, off);
            if (lane >= off) s += t;
        }
        sbs[lane] = s - v;                 // exclusive
    }
    __syncthreads();
    int i = blockIdx.x * 256 + threadIdx.x;
    if (i < N) {
        int o = excl[i] + sbs[i >> 10];
        offsets[i] = o;
        cursor[i] = o;
    }
    if (i == N) offsets[N] = Et;
}

__global__ void edge_sort_kernel(const int* __restrict__ ei, int* __restrict__ cursor,
                                 int* __restrict__ srcS, int E, int Et) {
    int e = blockIdx.x * 256 + threadIdx.x;
    if (e >= Et) return;
    int s, d;
    if (e < E) { s = ei[e]; d = ei[E + e]; } else { s = d = e - E; }
    int pos = atomicAdd(&cursor[d], 1);
    srcS[pos] = s;
}

// ------------- conv1 aggregate of RAW x (32-dim bf16, 64 B/row, 3.2 MB table) -------------
// Quarter-wave: 16 lanes x uint (2ch) per edge row, 4 edges in flight x4 unroll.
// Output aggX[N,128] = [head][32] bf16 (normalized), consumed by gemm_bd32.
__global__ __launch_bounds__(256) void gat_agg_x32(
        const int* __restrict__ offsets, const int* __restrict__ srcS,
        const float4* __restrict__ a_s4, const float4* __restrict__ a_d4,
        const unsigned short* __restrict__ x16,    // [N,32]
        unsigned short* __restrict__ aggX,         // [N,128]
        int N) {
    __shared__ float4 wlds[4][64];
    __shared__ int slds[4][64];
    const int wid = threadIdx.x >> 6;
    const int n = blockIdx.x * 4 + wid;
    if (n >= N) return;
    const int lane = threadIdx.x & 63;
    const int q = lane >> 4;
    const int l16 = lane & 15;
    const int start = offsets[n], end = offsets[n + 1];
    const float4 ad = a_d4[n];
    float2 acc0 = {0,0}, acc1 = {0,0}, acc2 = {0,0}, acc3 = {0,0};
    float4 den = {0,0,0,0};
    const int loff = l16 << 1;     // 2 channels of 32

    for (int e0 = start; e0 < end; e0 += 64) {
        const int cnt = min(64, end - e0);
        if (lane < cnt) {
            int sB = srcS[e0 + lane];
            slds[wid][lane] = sB;
            const float4 as = a_s4[sB];
            float x0 = as.x + ad.x; x0 = fmaxf(x0, NEG_SLOPE * x0);
            float x1 = as.y + ad.y; x1 = fmaxf(x1, NEG_SLOPE * x1);
            float x2 = as.z + ad.z; x2 = fmaxf(x2, NEG_SLOPE * x2);
            float x3 = as.w + ad.w; x3 = fmaxf(x3, NEG_SLOPE * x3);
            wlds[wid][lane] = (float4){exp2f(x0), exp2f(x1), exp2f(x2), exp2f(x3)};
        }
        int j = q;
        for (; j + 12 < cnt; j += 16) {
            int ss[4]; float4 ww[4]; unsigned int gg[4];
            #pragma unroll
            for (int u = 0; u < 4; u++) {
                ss[u] = slds[wid][j + 4 * u];
                ww[u] = wlds[wid][j + 4 * u];
            }
            #pragma unroll
            for (int u = 0; u < 4; u++)
                gg[u] = *(const unsigned int*)&x16[((size_t)ss[u] << 5) + loff];
            #pragma unroll
            for (int u = 0; u < 4; u++) {
                const float vl = b2f_lo(gg[u]), vh = b2f_hi(gg[u]);
                acc0.x += ww[u].x * vl; acc0.y += ww[u].x * vh;
                acc1.x += ww[u].y * vl; acc1.y += ww[u].y * vh;
                acc2.x += ww[u].z * vl; acc2.y += ww[u].z * vh;
                acc3.x += ww[u].w * vl; acc3.y += ww[u].w * vh;
                den.x += ww[u].x; den.y += ww[u].y; den.z += ww[u].z; den.w += ww[u].w;
            }
        }
        for (; j + 4 < cnt; j += 8) {
            const int s0 = slds[wid][j], s1 = slds[wid][j + 4];
            const float4 w0 = wlds[wid][j], w1 = wlds[wid][j + 4];
            const unsigned int g0 = *(const unsigned int*)&x16[((size_t)s0 << 5) + loff];
            const unsigned int g1 = *(const unsigned int*)&x16[((size_t)s1 << 5) + loff];
            const float vl0 = b2f_lo(g0), vh0 = b2f_hi(g0);
            const float vl1 = b2f_lo(g1), vh1 = b2f_hi(g1);
            acc0.x += w0.x * vl0 + w1.x * vl1; acc0.y += w0.x * vh0 + w1.x * vh1;
            acc1.x += w0.y * vl0 + w1.y * vl1; acc1.y += w0.y * vh0 + w1.y * vh1;
            acc2.x += w0.z * vl0 + w1.z * vl1; acc2.y += w0.z * vh0 + w1.z * vh1;
            acc3.x += w0.w * vl0 + w1.w * vl1; acc3.y += w0.w * vh0 + w1.w * vh1;
            den.x += w0.x + w1.x; den.y += w0.y + w1.y;
            den.z += w0.z + w1.z; den.w += w0.w + w1.w;
        }
        for (; j < cnt; j += 4) {
            const int s = slds[wid][j];
            const float4 w = wlds[wid][j];
            const unsigned int g = *(const unsigned int*)&x16[((size_t)s << 5) + loff];
            const float vl = b2f_lo(g), vh = b2f_hi(g);
            acc0.x += w.x * vl; acc0.y += w.x * vh;
            acc1.x += w.y * vl; acc1.y += w.y * vh;
            acc2.x += w.z * vl; acc2.y += w.z * vh;
            acc3.x += w.w * vl; acc3.y += w.w * vh;
            den.x += w.x; den.y += w.y; den.z += w.z; den.w += w.w;
        }
    }
    #pragma unroll
    for (int off = 16; off < 64; off <<= 1) {
        acc0.x += __shfl_xor(acc0.x, off); acc0.y += __shfl_xor(acc0.y, off);
        acc1.x += __shfl_xor(acc1.x, off); acc1.y += __shfl_xor(acc1.y, off);
        acc2.x += __shfl_xor(acc2.x, off); acc2.y += __shfl_xor(acc2.y, off);
        acc3.x += __shfl_xor(acc3.x, off); acc3.y += __shfl_xor(acc3.y, off);
        den.x += __shfl_xor(den.x, off); den.y += __shfl_xor(den.y, off);
        den.z += __shfl_xor(den.z, off); den.w += __shfl_xor(den.w, off);
    }
    if (q == 0) {
        const float i0 = 1.0f / (den.x + 1e-16f);
        const float i1 = 1.0f / (den.y + 1e-16f);
        const float i2 = 1.0f / (den.z + 1e-16f);
        const float i3 = 1.0f / (den.w + 1e-16f);
        unsigned int o0 = (unsigned int)f2b(acc0.x * i0) | ((unsigned int)f2b(acc0.y * i0) << 16);
        unsigned int o1 = (unsigned int)f2b(acc1.x * i1) | ((unsigned int)f2b(acc1.y * i1) << 16);
        unsigned int o2 = (unsigned int)f2b(acc2.x * i2) | ((unsigned int)f2b(acc2.y * i2) << 16);
        unsigned int o3 = (unsigned int)f2b(acc3.x * i3) | ((unsigned int)f2b(acc3.y * i3) << 16);
        *(unsigned int*)&aggX[((size_t)n << 7) + 0 * 32 + loff] = o0;
        *(unsigned int*)&aggX[((size_t)n << 7) + 1 * 32 + loff] = o1;
        *(unsigned int*)&aggX[((size_t)n << 7) + 2 * 32 + loff] = o2;
        *(unsigned int*)&aggX[((size_t)n << 7) + 3 * 32 + loff] = o3;
    }
}

// ------------- conv2 aggregate (output space, 256-dim), x4 unrolled gather, +bias+ELU -------------
__global__ __launch_bounds__(256) void gat_fused4(
        const int* __restrict__ offsets, const int* __restrict__ srcS,
        const float4* __restrict__ a_s4, const float4* __restrict__ a_d4,
        const unsigned short* __restrict__ hW16, const float* __restrict__ bias,
        unsigned short* __restrict__ out16, int N) {
    __shared__ float wlds[4][64][4];
    __shared__ int slds[4][64];
    const int wid = threadIdx.x >> 6;
    const int n = blockIdx.x * 4 + wid;
    if (n >= N) return;
    const int lane = threadIdx.x & 63;
    const int quad = lane >> 4;
    const int start = offsets[n], end = offsets[n + 1];
    const float4 ad = a_d4[n];
    float4 acc = {0, 0, 0, 0};
    float den = 0.0f;
    const int loff = lane << 2;

    for (int e0 = start; e0 < end; e0 += 64) {
        const int cnt = min(64, end - e0);
        if (lane < cnt) {
            int sB = srcS[e0 + lane];
            slds[wid][lane] = sB;
            const float4 as = a_s4[sB];
            float x0 = as.x + ad.x; x0 = fmaxf(x0, NEG_SLOPE * x0);
            float x1 = as.y + ad.y; x1 = fmaxf(x1, NEG_SLOPE * x1);
            float x2 = as.z + ad.z; x2 = fmaxf(x2, NEG_SLOPE * x2);
            float x3 = as.w + ad.w; x3 = fmaxf(x3, NEG_SLOPE * x3);
            wlds[wid][lane][0] = exp2f(x0);
            wlds[wid][lane][1] = exp2f(x1);
            wlds[wid][lane][2] = exp2f(x2);
            wlds[wid][lane][3] = exp2f(x3);
        }
        int j = 0;
        for (; j + 4 <= cnt; j += 4) {
            const int s0 = __builtin_amdgcn_readfirstlane(slds[wid][j + 0]);
            const int s1 = __builtin_amdgcn_readfirstlane(slds[wid][j + 1]);
            const int s2 = __builtin_amdgcn_readfirstlane(slds[wid][j + 2]);
            const int s3 = __builtin_amdgcn_readfirstlane(slds[wid][j + 3]);
            const float w0 = wlds[wid][j + 0][quad];
            const float w1 = wlds[wid][j + 1][quad];
            const float w2 = wlds[wid][j + 2][quad];
            const float w3 = wlds[wid][j + 3][quad];
            const uint2 h0 = *(const uint2*)&hW16[((size_t)s0 << 8) + loff];
            const uint2 h1 = *(const uint2*)&hW16[((size_t)s1 << 8) + loff];
            const uint2 h2 = *(const uint2*)&hW16[((size_t)s2 << 8) + loff];
            const uint2 h3 = *(const uint2*)&hW16[((size_t)s3 << 8) + loff];
            acc.x += w0 * b2f_lo(h0.x); acc.y += w0 * b2f_hi(h0.x);
            acc.z += w0 * b2f_lo(h0.y); acc.w += w0 * b2f_hi(h0.y);
            acc.x += w1 * b2f_lo(h1.x); acc.y += w1 * b2f_hi(h1.x);
            acc.z += w1 * b2f_lo(h1.y); acc.w += w1 * b2f_hi(h1.y);
            acc.x += w2 * b2f_lo(h2.x); acc.y += w2 * b2f_hi(h2.x);
            acc.z += w2 * b2f_lo(h2.y); acc.w += w2 * b2f_hi(h2.y);
            acc.x += w3 * b2f_lo(h3.x); acc.y += w3 * b2f_hi(h3.x);
            acc.z += w3 * b2f_lo(h3.y); acc.w += w3 * b2f_hi(h3.y);
            den += (w0 + w1) + (w2 + w3);
        }
        for (; j < cnt; j++) {
            const int s = __builtin_amdgcn_readfirstlane(slds[wid][j]);
            const float w = wlds[wid][j][quad];
            const uint2 hv = *(const uint2*)&hW16[((size_t)s << 8) + loff];
            acc.x += w * b2f_lo(hv.x); acc.y += w * b2f_hi(hv.x);
            acc.z += w * b2f_lo(hv.y); acc.w += w * b2f_hi(hv.y);
            den += w;
        }
    }

    const float inv = 1.0f / (den + 1e-16f);
    const float4 bb = *(const float4*)&bias[loff];
    float v0 = acc.x * inv + bb.x; v0 = (v0 > 0.0f) ? v0 : expm1f(v0);
    float v1 = acc.y * inv + bb.y; v1 = (v1 > 0.0f) ? v1 : expm1f(v1);
    float v2 = acc.z * inv + bb.z; v2 = (v2 > 0.0f) ? v2 : expm1f(v2);
    float v3 = acc.w * inv + bb.w; v3 = (v3 > 0.0f) ? v3 : expm1f(v3);
    uint2 o;
    o.x = (unsigned int)f2b(v0) | ((unsigned int)f2b(v1) << 16);
    o.y = (unsigned int)f2b(v2) | ((unsigned int)f2b(v3) << 16);
    *(uint2*)&out16[(size_t)n * 256 + loff] = o;
}

// ------------- H=1 fused (conv3): wave/node gather + PARTITIONED fused mean-pool -------------
__global__ __launch_bounds__(256) void gat_fused1(
        const int* __restrict__ offsets, const int* __restrict__ srcS,
        const float* __restrict__ a_s, const float* __restrict__ a_d,
        const unsigned short* __restrict__ hW16, const float* __restrict__ bias,
        const int* __restrict__ batch,
        float* __restrict__ pooledP, float* __restrict__ cntP, int N, int G) {
    __shared__ float wlds[4][64];
    __shared__ int slds[4][64];
    __shared__ float2 sOut[4][32];
    __shared__ int sG[4];
    const int wid = threadIdx.x >> 6;
    const int n = blockIdx.x * 4 + wid;
    const bool valid = n < N;                  // no early return: all waves reach the barrier
    const int lane = threadIdx.x & 63;
    const int half = lane >> 5;
    const int l32 = lane & 31;
    const int start = valid ? offsets[n] : 0;
    const int end   = valid ? offsets[n + 1] : 0;
    const float ad  = valid ? a_d[n] : 0.0f;
    float accx = 0.0f, accy = 0.0f, den = 0.0f;
    const int loff = l32 << 1;

    for (int e0 = start; e0 < end; e0 += 64) {
        const int cnt_ = min(64, end - e0);
        if (lane < cnt_) {
            int sB = srcS[e0 + lane];
            slds[wid][lane] = sB;
            float ev = a_s[sB] + ad;
            ev = fmaxf(ev, NEG_SLOPE * ev);
            wlds[wid][lane] = exp2f(ev);
        }
        int j = half;
        for (; j + 8 <= cnt_ + half; j += 8) {
            const int s0 = slds[wid][j + 0];
            const int s1 = slds[wid][j + 2];
            const int s2 = slds[wid][j + 4];
            const int s3 = slds[wid][j + 6];
            const float w0 = wlds[wid][j + 0];
            const float w1 = wlds[wid][j + 2];
            const float w2 = wlds[wid][j + 4];
            const float w3 = wlds[wid][j + 6];
            const unsigned int h0 = *(const unsigned int*)&hW16[((size_t)s0 << 6) + loff];
            const unsigned int h1 = *(const unsigned int*)&hW16[((size_t)s1 << 6) + loff];
            const unsigned int h2 = *(const unsigned int*)&hW16[((size_t)s2 << 6) + loff];
            const unsigned int h3 = *(const unsigned int*)&hW16[((size_t)s3 << 6) + loff];
            accx += w0 * b2f_lo(h0); accy += w0 * b2f_hi(h0);
            accx += w1 * b2f_lo(h1); accy += w1 * b2f_hi(h1);
            accx += w2 * b2f_lo(h2); accy += w2 * b2f_hi(h2);
            accx += w3 * b2f_lo(h3); accy += w3 * b2f_hi(h3);
            den += (w0 + w1) + (w2 + w3);
        }
        for (; j < cnt_; j += 2) {
            const int s = slds[wid][j];
            const float w = wlds[wid][j];
            const unsigned int hv = *(const unsigned int*)&hW16[((size_t)s << 6) + loff];
            accx += w * b2f_lo(hv);
            accy += w * b2f_hi(hv);
            den += w;
        }
    }
    accx += __shfl_xor(accx, 32);
    accy += __shfl_xor(accy, 32);
    den  += __shfl_xor(den, 32);
    if (half == 0) {
        if (valid) {
            const float inv = 1.0f / (den + 1e-16f);
            sOut[wid][l32] = (float2){accx * inv + bias[loff], accy * inv + bias[loff + 1]};
        } else {
            sOut[wid][l32] = (float2){0.0f, 0.0f};
        }
        if (l32 == 0) sG[wid] = valid ? batch[n] : -1;
    }
    __syncthreads();
    const int p = blockIdx.x & 63;
    if (wid == 0 && half == 0) {
        const int g0 = sG[0], g1 = sG[1], g2 = sG[2], g3 = sG[3];
        if (g0 >= 0 && g1 == g0 && g2 == g0 && g3 == g0) {
            const float2 s0 = sOut[0][l32], s1 = sOut[1][l32];
            const float2 s2 = sOut[2][l32], s3 = sOut[3][l32];
            float* base = pooledP + ((size_t)p * G + g0) * 64;
            atomicAdd(&base[loff],     (s0.x + s1.x) + (s2.x + s3.x));
            atomicAdd(&base[loff + 1], (s0.y + s1.y) + (s2.y + s3.y));
            if (l32 == 0) atomicAdd(&cntP[p * G + g0], 4.0f);
        } else {
            #pragma unroll
            for (int w = 0; w < 4; w++) {
                const int g = sG[w];
                if (g >= 0) {
                    const float2 s = sOut[w][l32];
                    float* base = pooledP + ((size_t)p * G + g) * 64;
                    atomicAdd(&base[loff], s.x);
                    atomicAdd(&base[loff + 1], s.y);
                    if (l32 == 0) atomicAdd(&cntP[p * G + g], 1.0f);
                }
            }
        }
    }
}

// ------------- decoder head: one block per graph (reduces 64 pool partitions first) -------------
__global__ __launch_bounds__(256) void final_kernel(
        const float* __restrict__ pooledP, const float* __restrict__ cntP,
        const float* __restrict__ gf, const float* __restrict__ Wg,
        const float* __restrict__ bg, const float* __restrict__ Wd1,
        const float* __restrict__ bd1, const float* __restrict__ gamma,
        const float* __restrict__ beta, const float* __restrict__ Wd2,
        const float* __restrict__ bd2, float* __restrict__ out, int G) {
    const int g = blockIdx.x;
    const int tid = threadIdx.x;
    const int lane = tid & 63;
    const int wave = tid >> 6;
    __shared__ float sPart[4][64];
    __shared__ float sCntTot;
    __shared__ float spg[128];
    __shared__ float sz[64];
    __shared__ float wred[8];

    {   // partition reduce: wave pg sums partitions [pg*16, pg*16+16)
        const int c = lane;
        const int pg = wave;
        float a = 0.0f;
        #pragma unroll
        for (int p = 0; p < 16; p++)
            a += pooledP[((size_t)(pg * 16 + p) * G + g) * 64 + c];
        sPart[pg][c] = a;
        if (pg == 1) {
            float cv = cntP[c * G + g];
            #pragma unroll
            for (int off = 32; off > 0; off >>= 1) cv += __shfl_xor(cv, off);
            if (c == 0) sCntTot = cv;
        }
    }
    __syncthreads();
    if (tid < 64) {
        spg[tid] = (sPart[0][tid] + sPart[1][tid] + sPart[2][tid] + sPart[3][tid])
                   / fmaxf(sCntTot, 1.0f);
    } else if (tid < 128) {
        int c = tid - 64;
        float v = bg[c];
        #pragma unroll
        for (int k = 0; k < 4; k++) v += gf[g * 4 + k] * Wg[k * 64 + c];
        spg[64 + c] = fmaxf(v, 0.0f);
    }
    __syncthreads();
    if (tid < 64) {
        float v = bd1[tid];
        #pragma unroll 8
        for (int k = 0; k < 128; k++) v += spg[k] * Wd1[k * 64 + tid];
        v = v * gamma[tid] + beta[tid];
        sz[tid] = fmaxf(v, 0.0f);
    }
    __syncthreads();
    float v = bd2[tid];
    #pragma unroll 8
    for (int k = 0; k < 64; k++) v += sz[k] * Wd2[k * 256 + tid];
    float m = v;
    #pragma unroll
    for (int off = 32; off > 0; off >>= 1) m = fmaxf(m, __shfl_xor(m, off));
    if (lane == 0) wred[wave] = m;
    __syncthreads();
    float M = fmaxf(fmaxf(wred[0], wred[1]), fmaxf(wred[2], wred[3]));
    float e = expf(v - M);
    float s = e;
    #pragma unroll
    for (int off = 32; off > 0; off >>= 1) s += __shfl_xor(s, off);
    if (lane == 0) wred[4 + wave] = s;
    __syncthreads();
    float S = (wred[4] + wred[5]) + (wred[6] + wred[7]);
    out[g * 256 + tid] = e / S;
}

extern "C" void kernel_launch(void* const* d_in, const int* in_sizes, int n_in,
                              void* d_out, int out_size, void* d_ws, size_t ws_size,
                              hipStream_t stream) {
    const float* x     = (const float*)d_in[0];
    const int*   ei    = (const int*)  d_in[1];
    const int*   batch = (const int*)  d_in[2];
    const float* gf    = (const float*)d_in[3];
    const float* W_enc = (const float*)d_in[4];
    const float* b_enc = (const float*)d_in[5];
    const float* W1  = (const float*)d_in[6];
    const float* as1 = (const float*)d_in[7];
    const float* ad1 = (const float*)d_in[8];
    const float* b1  = (const float*)d_in[9];
    const float* W2  = (const float*)d_in[10];
    const float* as2 = (const float*)d_in[11];
    const float* ad2 = (const float*)d_in[12];
    const float* b2  = (const float*)d_in[13];
    const float* W3  = (const float*)d_in[14];
    const float* as3 = (const float*)d_in[15];
    const float* ad3 = (const float*)d_in[16];
    const float* b3  = (const float*)d_in[17];
    const float* Wg  = (const float*)d_in[18];
    const float* bg  = (const float*)d_in[19];
    const float* Wd1 = (const float*)d_in[20];
    const float* bd1 = (const float*)d_in[21];
    const float* gm  = (const float*)d_in[22];
    const float* bt  = (const float*)d_in[23];
    const float* Wd2 = (const float*)d_in[24];
    const float* bd2 = (const float*)d_in[25];

    const int N  = in_sizes[2];
    const int E  = in_sizes[1] / 2;
    const int G  = in_sizes[3] / 4;
    const int Et = E + N;

    unsigned short* h16a = (unsigned short*)d_ws;                // [N,256] bf16 (also aggX [N,128])
    unsigned short* h16b = h16a + (size_t)N * 256;               // [N,256] bf16
    unsigned short* h1_16 = h16b + (size_t)N * 256;              // [N,64] bf16 (conv3 table)
    unsigned short* x16  = h1_16 + (size_t)N * 64;               // [N,32] bf16
    unsigned short* Wc1t = x16 + (size_t)N * 32;                 // [4][64][32]
    unsigned short* Wt2  = Wc1t + 4 * 64 * 32;                   // [256,256]
    unsigned short* Wt3  = Wt2 + 256 * 256;                      // [64,256]
    float* bc1    = (float*)(Wt3 + 64 * 256);                    // [256]
    float* a_s    = bc1 + 256;                                   // [N,4]
    float* a_d    = a_s + (size_t)N * 4;                         // [N,4]
    float* u1s    = a_d + (size_t)N * 4;                         // [64,4]
    float* u1d    = u1s + 256;                                   // [64,4]
    float* pooledP = u1d + 256;                                  // [64][G][64]
    float* cntP   = pooledP + (size_t)64 * G * 64;               // [64][G]
    int*   offsets = (int*)(cntP + 64 * G);                      // [N+1]
    int*   srcS    = offsets + (N + 1);                          // [Et]
    int*   counts  = srcS + Et;                                  // [N]
    int*   cursor  = counts + N;                                 // [N]
    int*   blockSums = cursor + N;                               // [cdiv(N,1024)]

    dim3 blk(256);
    auto cdiv = [](int a, int b) { return (a + b - 1) / b; };
    const int eBlocks = cdiv(Et, 256);
    const int rowBlocks = cdiv(N, 64);
    const int nScanBlocks = cdiv(N, 1024);
    const int zc = cdiv(N, 256);
    const int z2 = cdiv(64 * G * 64, 256);

    // ---------------- prep (folded weights + zero-init) + CSR build ----------------
    prep_kernel<<<354 + zc + z2, blk, 0, stream>>>(W_enc, b_enc, W1, W2, W3, as1, ad1, b1,
                                                   Wc1t, bc1, Wt2, Wt3, u1s, u1d,
                                                   counts, pooledP, cntP, N, G, zc);
    edge_hist_kernel<<<eBlocks, blk, 0, stream>>>(ei, counts, E, Et);
    scan_blocks<<<nScanBlocks, 1024, 0, stream>>>(counts, blockSums, N);
    scan_add2<<<cdiv(N + 1, 256), blk, 0, stream>>>(counts, blockSums, nScanBlocks,
                                                    offsets, cursor, N, Et);
    edge_sort_kernel<<<eBlocks, blk, 0, stream>>>(ei, cursor, srcS, E, Et);

    // conv1 scores from raw x + x->bf16 (replaces the encoder GEMM entirely)
    score_x<<<cdiv(N, 32), blk, 0, stream>>>(x, W_enc, b_enc, u1s, u1d, x16, a_s, a_d, N);

    // ---------------- conv1: aggregate raw x per head, then folded K=32 block-diag GEMM ----------------
    gat_agg_x32<<<cdiv(N, 4), blk, 0, stream>>>(offsets, srcS, (const float4*)a_s,
                                                (const float4*)a_d, x16, h16a, N);
    gemm_bd32<<<dim3(rowBlocks, 4), blk, 0, stream>>>(h16a, Wc1t, bc1, h16b, N);

    // ---------------- conv2: GEMM (+fused scores) -> aggregate ----------------
    gemm_mfma<2, 1><<<dim3(rowBlocks, 2), blk, 0, stream>>>(h16b, Wt2, h16a,
                                                            as2, ad2, a_s, a_d, N, 256, 256, 4);
    gat_fused4<<<cdiv(N, 4), blk, 0, stream>>>(offsets, srcS, (const float4*)a_s,
                                               (const float4*)a_d, h16a, b2, h16b, N);

    // ---------------- conv3: GEMM (+fused scores) -> aggregate + partitioned pool ----------------
    gemm_mfma<1, 1><<<dim3(rowBlocks, 1), blk, 0, stream>>>(h16b, Wt3, h1_16,
                                                            as3, ad3, a_s, a_d, N, 256, 64, 1);
    gat_fused1<<<cdiv(N, 4), blk, 0, stream>>>(offsets, srcS, a_s, a_d, h1_16, b3,
                                               batch, pooledP, cntP, N, G);

    // ---------------- decoder head ----------------
    final_kernel<<<G, blk, 0, stream>>>(pooledP, cntP, gf, Wg, bg, Wd1, bd1, gm, bt, Wd2, bd2,
                                        (float*)d_out, G);
}

// Round 6
// 404.572 us; speedup vs baseline: 1.1414x; 1.0496x over previous
//
#include <hip/hip_runtime.h>
#include <math.h>

#define NEG_SLOPE 0.2f
#define LOG2E 1.4426950408889634f

typedef __attribute__((ext_vector_type(8))) short short8;   // 8 bf16 = 4 VGPRs
typedef __attribute__((ext_vector_type(4))) float f32x4;    // MFMA acc

__device__ inline float b2f_lo(unsigned int u) {
    union { unsigned int i; float f; } x; x.i = u << 16; return x.f;
}
__device__ inline float b2f_hi(unsigned int u) {
    union { unsigned int i; float f; } x; x.i = u & 0xFFFF0000u; return x.f;
}
__device__ inline unsigned short f2b(float f) {
    union { float f; unsigned int i; } u; u.f = f;
    unsigned int r = u.i + 0x7FFF + ((u.i >> 16) & 1);   // round-to-nearest-even
    return (unsigned short)(r >> 16);
}

// ---------------- prep: folded conv1 weights (Wc1 = W_enc@W1, bc1), u1/u3 vectors,
// Wt2/Wt3 transposes, and ALL zero-init ----------------
__global__ void prep_kernel(const float* __restrict__ W_enc, const float* __restrict__ b_enc,
                            const float* __restrict__ W1, const float* __restrict__ W2,
                            const float* __restrict__ W3, const float* __restrict__ as1,
                            const float* __restrict__ ad1, const float* __restrict__ b1,
                            const float* __restrict__ as3, const float* __restrict__ ad3,
                            unsigned short* __restrict__ Wc1t, float* __restrict__ bc1,
                            unsigned short* __restrict__ Wt2, unsigned short* __restrict__ Wt3,
                            float* __restrict__ u1s, float* __restrict__ u1d,
                            float* __restrict__ u3s, float* __restrict__ u3d,
                            int* __restrict__ counts, float* __restrict__ pooledP,
                            float* __restrict__ cntP, int N, int G, int zc) {
    const int b = blockIdx.x;
    const int t = threadIdx.x;
    if (b < 32) {
        // Wc1t[h][o][j] = sum_k W_enc[j][k] * W1[k][h*64+o]   (bf16, B^T layout)
        int i = b * 256 + t;                       // 8192 values
        int h = i >> 11, rem = i & 2047, o = rem >> 5, j = rem & 31;
        float s = 0.0f;
        for (int k = 0; k < 64; k++)
            s += W_enc[j * 64 + k] * W1[k * 256 + h * 64 + o];
        Wc1t[i] = f2b(s);
    } else if (b == 32) {
        // bc1[c] = b1[c] + sum_k b_enc[k] * W1[k][c]   (uses sum(alpha)=1)
        float s = b1[t];
        for (int k = 0; k < 64; k++) s += b_enc[k] * W1[k * 256 + t];
        bc1[t] = s;
    } else if (b == 33) {
        // u1 score projections in h1-space (consumed by score_x)
        int k = t >> 2, h = t & 3;
        float s = 0.0f, d = 0.0f;
        for (int c = 0; c < 64; c++) {
            float w = W1[k * 256 + h * 64 + c];
            s += w * as1[h * 64 + c];
            d += w * ad1[h * 64 + c];
        }
        u1s[k * 4 + h] = s;
        u1d[k * 4 + h] = d;
    } else if (b == 34) {
        // u3 = W3 @ as3 (conv3 scores computed from h3 directly: a3 = h3 . u3)
        float s = 0.0f, d = 0.0f;
        for (int o = 0; o < 64; o++) {
            float w = W3[t * 64 + o];
            s += w * as3[o];
            d += w * ad3[o];
        }
        u3s[t] = s; u3d[t] = d;
    } else if (b < 35 + 256) {
        int i = (b - 35) * 256 + t;                // K=256, M=256
        int k = i >> 8, m = i & 255;
        Wt2[(size_t)m * 256 + k] = f2b(W2[i]);
    } else if (b < 35 + 256 + 64) {
        int i = (b - 291) * 256 + t;               // K=256, M=64
        int k = i >> 6, m = i & 63;
        Wt3[(size_t)m * 256 + k] = f2b(W3[i]);
    } else if (b < 355 + zc) {
        int i = (b - 355) * 256 + t;
        if (i < N) counts[i] = 0;
    } else {
        int i = (b - 355 - zc) * 256 + t;
        if (i < 64 * G * 64) pooledP[i] = 0.0f;    // [64 partitions][G][64]
        if (i < 64 * G) cntP[i] = 0.0f;            // [64 partitions][G]
    }
}

// ---------------- score_x: conv1 scores directly from x (a = x*(W_enc@u1) + b_enc@u1),
// plus x -> bf16 conversion. ----------------
__global__ __launch_bounds__(256) void score_x(
        const float* __restrict__ x, const float* __restrict__ W_enc,
        const float* __restrict__ b_enc,
        const float* __restrict__ u1s, const float* __restrict__ u1d,
        unsigned short* __restrict__ x16, float* __restrict__ a_s,
        float* __restrict__ a_d, int N) {
    __shared__ float sUs[32][4], sUd[32][4], sC[8];
    __shared__ float sX[32][33];
    const int t = threadIdx.x;
    if (t < 128) {
        int j = t >> 2, h = t & 3;
        float s = 0.0f, d = 0.0f;
        for (int k = 0; k < 64; k++) {
            float w = W_enc[j * 64 + k];
            s += w * u1s[k * 4 + h];
            d += w * u1d[k * 4 + h];
        }
        sUs[j][h] = s; sUd[j][h] = d;
    } else if (t < 136) {
        int hh = t - 128;                           // 0..3 -> s, 4..7 -> d
        const float* u = (hh < 4) ? u1s : u1d;
        int h = hh & 3;
        float c = 0.0f;
        for (int k = 0; k < 64; k++) c += b_enc[k] * u[k * 4 + h];
        sC[hh] = c;
    }
    const int n0 = blockIdx.x * 32;
    const int row = t >> 3, col = (t & 7) << 2;
    float4 xv = {0, 0, 0, 0};
    if (n0 + row < N) xv = *(const float4*)&x[(size_t)(n0 + row) * 32 + col];
    sX[row][col + 0] = xv.x; sX[row][col + 1] = xv.y;
    sX[row][col + 2] = xv.z; sX[row][col + 3] = xv.w;
    __syncthreads();
    const int ni = t >> 3, oi = t & 7, h = oi & 3;
    const bool isS = oi < 4;
    float acc = sC[oi];
    #pragma unroll 8
    for (int j = 0; j < 32; j++) acc += sX[ni][j] * (isS ? sUs[j][h] : sUd[j][h]);
    if (n0 + ni < N) {
        float* out = isS ? a_s : a_d;
        out[(size_t)(n0 + ni) * 4 + h] = acc * LOG2E;
    }
    if (n0 + row < N) {
        ushort4 o = {f2b(xv.x), f2b(xv.y), f2b(xv.z), f2b(xv.w)};
        *(ushort4*)&x16[(size_t)(n0 + row) * 32 + col] = o;
    }
}

// ---------------- MFMA GEMM: C16[N,M] = A16[N,K] @ Wt16^T; optional fused scores ----------------
template<int CPW, int SCORES>
__global__ __launch_bounds__(256) void gemm_mfma(const unsigned short* __restrict__ A16,
                                                 const unsigned short* __restrict__ Bt16,
                                                 unsigned short* __restrict__ C16,
                                                 const float* __restrict__ att_s,
                                                 const float* __restrict__ att_d,
                                                 float* __restrict__ a_s,
                                                 float* __restrict__ a_d,
                                                 int Nrows, int K, int M, int H) {
    constexpr int BN = CPW * 64;
    __shared__ unsigned short sA[64][40];
    __shared__ unsigned short sB[BN][40];
    const int tid = threadIdx.x;
    const int wave = tid >> 6;
    const int lane = tid & 63;
    const int quad = lane >> 4;
    const int l16 = lane & 15;
    const int row0 = blockIdx.x * 64;
    const int col0 = blockIdx.y * BN;
    const int sr = tid >> 2;
    const int sk = (tid & 3) << 3;

    f32x4 acc[4][CPW];
    #pragma unroll
    for (int i = 0; i < 4; i++)
        #pragma unroll
        for (int j = 0; j < CPW; j++) acc[i][j] = (f32x4){0,0,0,0};

    for (int kt = 0; kt < K; kt += 32) {
        __syncthreads();
        {
            int r = row0 + sr;
            uint4 z = {0,0,0,0};
            *(uint4*)&sA[sr][sk] = (r < Nrows) ? *(const uint4*)&A16[(size_t)r * K + kt + sk] : z;
        }
        #pragma unroll
        for (int i = 0; i < CPW; i++) {
            int c = col0 + sr + i * 64;
            *(uint4*)&sB[sr + i * 64][sk] = *(const uint4*)&Bt16[(size_t)c * K + kt + sk];
        }
        __syncthreads();
        short8 bf[CPW];
        #pragma unroll
        for (int j = 0; j < CPW; j++)
            bf[j] = *(const short8*)&sB[wave * (CPW * 16) + j * 16 + l16][quad * 8];
        #pragma unroll
        for (int i = 0; i < 4; i++) {
            short8 af = *(const short8*)&sA[i * 16 + l16][quad * 8];
            #pragma unroll
            for (int j = 0; j < CPW; j++)
                acc[i][j] = __builtin_amdgcn_mfma_f32_16x16x32_bf16(af, bf[j], acc[i][j], 0, 0, 0);
        }
    }
    if (SCORES) {
        __shared__ float sSD[64][CPW][2];
        for (int t = tid; t < 64 * CPW * 2; t += 256) ((float*)sSD)[t] = 0.0f;
        __syncthreads();
        const int hib = (wave * CPW * 16) >> 6;
        float avs[CPW], avd[CPW];
        #pragma unroll
        for (int j = 0; j < CPW; j++) {
            int c = col0 + wave * (CPW * 16) + j * 16 + l16;
            avs[j] = att_s[c];
            avd[j] = att_d[c];
        }
        #pragma unroll
        for (int i = 0; i < 4; i++) {
            float ps[4] = {0,0,0,0}, pd[4] = {0,0,0,0};
            #pragma unroll
            for (int j = 0; j < CPW; j++)
                #pragma unroll
                for (int r = 0; r < 4; r++) {
                    ps[r] += acc[i][j][r] * avs[j];
                    pd[r] += acc[i][j][r] * avd[j];
                }
            #pragma unroll
            for (int off = 1; off < 16; off <<= 1)
                #pragma unroll
                for (int r = 0; r < 4; r++) {
                    ps[r] += __shfl_xor(ps[r], off);
                    pd[r] += __shfl_xor(pd[r], off);
                }
            if (l16 == 0) {
                #pragma unroll
                for (int r = 0; r < 4; r++) {
                    atomicAdd(&sSD[i * 16 + quad * 4 + r][hib][0], ps[r]);
                    atomicAdd(&sSD[i * 16 + quad * 4 + r][hib][1], pd[r]);
                }
            }
        }
        __syncthreads();
        for (int t = tid; t < 64 * CPW; t += 256) {
            int row = t & 63, hb = t >> 6;
            int r = row0 + row;
            if (r < Nrows) {
                int hg = (col0 >> 6) + hb;
                a_s[r * H + hg] = sSD[row][hb][0] * LOG2E;
                a_d[r * H + hg] = sSD[row][hb][1] * LOG2E;
            }
        }
    }
    #pragma unroll
    for (int i = 0; i < 4; i++) {
        #pragma unroll
        for (int j = 0; j < CPW; j++) {
            int col = col0 + wave * (CPW * 16) + j * 16 + l16;
            #pragma unroll
            for (int r = 0; r < 4; r++) {
                int row = row0 + i * 16 + quad * 4 + r;
                if (row < Nrows) C16[(size_t)row * M + col] = f2b(acc[i][j][r]);
            }
        }
    }
}

// ---------------- FUSED conv1-GEMM + conv2-GEMM: h2 tile computed in-register/LDS,
// never materialized to HBM. Phase1: per-head K=32 MFMA (bd32 structure) -> ELU -> sH bf16.
// Phase2: conv2 K=256 loop, A-fragments from sH, BN=256 (full row in one pass), fused scores.
// Saves ~77MB HBM round-trip (h2 write + 2x col-block A reads) + one dispatch. ----------------
__global__ __launch_bounds__(256) void gemm_c12(
        const unsigned short* __restrict__ aggX,   // [N,128]
        const unsigned short* __restrict__ Wc1t,   // [(h*64+o)*32 + j]
        const float* __restrict__ bc1,             // [256]
        const unsigned short* __restrict__ Wt2,    // [256][256] B^T
        const float* __restrict__ att_s,           // as2 [256]
        const float* __restrict__ att_d,
        float* __restrict__ a_s, float* __restrict__ a_d,   // [N,4] conv2 scores
        unsigned short* __restrict__ C16,          // [N,256] conv2 pre-agg output
        int Nrows) {
    __shared__ unsigned short sH[64][264];   // h2 tile (row stride 528B: 16B-aligned, 2-way max)
    __shared__ unsigned short sB[256][40];   // phase1: aggX[0..63]+Wc1[64..127]; phase2: B chunk
    __shared__ float sSD[64][4][2];
    const int tid = threadIdx.x;
    const int wave = tid >> 6;
    const int lane = tid & 63;
    const int quad = lane >> 4;
    const int l16 = lane & 15;
    const int row0 = blockIdx.x * 64;
    const int sr = tid >> 2;
    const int sk = (tid & 3) << 3;

    // ---- phase 1: conv1 (folded, K=32) per head -> sH ----
    #pragma unroll
    for (int h = 0; h < 4; h++) {
        __syncthreads();
        {
            int r = row0 + sr;
            uint4 z = {0,0,0,0};
            *(uint4*)&sB[sr][sk] = (r < Nrows)
                ? *(const uint4*)&aggX[(size_t)r * 128 + h * 32 + sk] : z;
            *(uint4*)&sB[64 + sr][sk] = *(const uint4*)&Wc1t[(size_t)(h * 64 + sr) * 32 + sk];
        }
        __syncthreads();
        short8 bf = *(const short8*)&sB[64 + wave * 16 + l16][quad * 8];
        const int col = h * 64 + wave * 16 + l16;
        const float bb = bc1[col];
        #pragma unroll
        for (int i = 0; i < 4; i++) {
            short8 af = *(const short8*)&sB[i * 16 + l16][quad * 8];
            f32x4 acc = __builtin_amdgcn_mfma_f32_16x16x32_bf16(af, bf, (f32x4){0,0,0,0}, 0, 0, 0);
            #pragma unroll
            for (int r = 0; r < 4; r++) {
                float v = acc[r] + bb;
                v = (v > 0.0f) ? v : expm1f(v);        // ELU
                sH[i * 16 + quad * 4 + r][col] = f2b(v);
            }
        }
    }

    // ---- phase 2: conv2 GEMM, A from sH, BN=256 ----
    f32x4 acc2[4][4];
    #pragma unroll
    for (int i = 0; i < 4; i++)
        #pragma unroll
        for (int j = 0; j < 4; j++) acc2[i][j] = (f32x4){0,0,0,0};

    for (int kt = 0; kt < 256; kt += 32) {
        __syncthreads();                           // protects sB reuse + sH completeness (kt=0)
        #pragma unroll
        for (int i = 0; i < 4; i++) {
            int c = sr + i * 64;
            *(uint4*)&sB[c][sk] = *(const uint4*)&Wt2[(size_t)c * 256 + kt + sk];
        }
        __syncthreads();
        short8 bf2[4];
        #pragma unroll
        for (int j = 0; j < 4; j++)
            bf2[j] = *(const short8*)&sB[wave * 64 + j * 16 + l16][quad * 8];
        #pragma unroll
        for (int i = 0; i < 4; i++) {
            short8 af = *(const short8*)&sH[i * 16 + l16][kt + quad * 8];
            #pragma unroll
            for (int j = 0; j < 4; j++)
                acc2[i][j] = __builtin_amdgcn_mfma_f32_16x16x32_bf16(af, bf2[j], acc2[i][j], 0, 0, 0);
        }
    }

    // ---- conv2 scores (CPW=4, col0=0) ----
    {
        for (int t = tid; t < 512; t += 256) ((float*)sSD)[t] = 0.0f;
        __syncthreads();
        float avs[4], avd[4];
        #pragma unroll
        for (int j = 0; j < 4; j++) {
            int c = wave * 64 + j * 16 + l16;
            avs[j] = att_s[c];
            avd[j] = att_d[c];
        }
        #pragma unroll
        for (int i = 0; i < 4; i++) {
            float ps[4] = {0,0,0,0}, pd[4] = {0,0,0,0};
            #pragma unroll
            for (int j = 0; j < 4; j++)
                #pragma unroll
                for (int r = 0; r < 4; r++) {
                    ps[r] += acc2[i][j][r] * avs[j];
                    pd[r] += acc2[i][j][r] * avd[j];
                }
            #pragma unroll
            for (int off = 1; off < 16; off <<= 1)
                #pragma unroll
                for (int r = 0; r < 4; r++) {
                    ps[r] += __shfl_xor(ps[r], off);
                    pd[r] += __shfl_xor(pd[r], off);
                }
            if (l16 == 0) {
                #pragma unroll
                for (int r = 0; r < 4; r++) {
                    atomicAdd(&sSD[i * 16 + quad * 4 + r][wave][0], ps[r]);
                    atomicAdd(&sSD[i * 16 + quad * 4 + r][wave][1], pd[r]);
                }
            }
        }
        __syncthreads();
        {
            int row = tid & 63, hb = tid >> 6;
            int r = row0 + row;
            if (r < Nrows) {
                a_s[r * 4 + hb] = sSD[row][hb][0] * LOG2E;
                a_d[r * 4 + hb] = sSD[row][hb][1] * LOG2E;
            }
        }
    }
    // ---- C write ----
    #pragma unroll
    for (int i = 0; i < 4; i++) {
        #pragma unroll
        for (int j = 0; j < 4; j++) {
            int col = wave * 64 + j * 16 + l16;
            #pragma unroll
            for (int r = 0; r < 4; r++) {
                int row = row0 + i * 16 + quad * 4 + r;
                if (row < Nrows) C16[(size_t)row * 256 + col] = f2b(acc2[i][j][r]);
            }
        }
    }
}

// ------------- CSR build -------------
__global__ void edge_hist_kernel(const int* __restrict__ ei, int* __restrict__ counts,
                                 int E, int Et) {
    int e = blockIdx.x * 256 + threadIdx.x;
    if (e >= Et) return;
    int d = (e < E) ? ei[E + e] : e - E;
    atomicAdd(&counts[d], 1);
}

__global__ __launch_bounds__(1024) void scan_blocks(int* __restrict__ counts,
                                                    int* __restrict__ blockSums, int N) {
    __shared__ int wsum[16];
    const int tid = threadIdx.x;
    const int lane = tid & 63;
    const int wave = tid >> 6;
    int i = blockIdx.x * 1024 + tid;
    int v = (i < N) ? counts[i] : 0;
    int s = v;
    #pragma unroll
    for (int off = 1; off < 64; off <<= 1) {
        int t = __shfl_up(s, off);
        if (lane >= off) s += t;
    }
    if (lane == 63) wsum[wave] = s;
    __syncthreads();
    if (wave == 0 && lane < 16) {
        int ws = wsum[lane];
        #pragma unroll
        for (int off = 1; off < 16; off <<= 1) {
            int t = __shfl_up(ws, off);
            if (lane >= off) ws += t;
        }
        wsum[lane] = ws;
    }
    __syncthreads();
    int waveOff = (wave > 0) ? wsum[wave - 1] : 0;
    int incl = s + waveOff;
    if (i < N) counts[i] = incl - v;
    if (tid == 1023) blockSums[blockIdx.x] = incl;
}

__global__ void scan_add2(const int* __restrict__ excl, const int* __restrict__ blockSums,
                          int nb, int* __restrict__ offsets, int* __restrict__ cursor,
                          int N, int Et) {
    __shared__ int sbs[64];
    if (threadIdx.x < 64) {
        int lane = threadIdx.x;
        int v = (lane < nb) ? blockSums[lane] : 0;
        int s = v;
        #pragma unroll
        for (int off = 1; off < 64; off <<= 1) {
            int t = __shfl_up(s, off);
            if (lane >= off) s += t;
        }
        sbs[lane] = s - v;                 // exclusive
    }
    __syncthreads();
    int i = blockIdx.x * 256 + threadIdx.x;
    if (i < N) {
        int o = excl[i] + sbs[i >> 10];
        offsets[i] = o;
        cursor[i] = o;
    }
    if (i == N) offsets[N] = Et;
}

__global__ void edge_sort_kernel(const int* __restrict__ ei, int* __restrict__ cursor,
                                 int* __restrict__ srcS, int E, int Et) {
    int e = blockIdx.x * 256 + threadIdx.x;
    if (e >= Et) return;
    int s, d;
    if (e < E) { s = ei[e]; d = ei[E + e]; } else { s = d = e - E; }
    int pos = atomicAdd(&cursor[d], 1);
    srcS[pos] = s;
}

// ------------- conv1 aggregate of RAW x (32-dim bf16, 64 B/row, 3.2 MB table) -------------
__global__ __launch_bounds__(256) void gat_agg_x32(
        const int* __restrict__ offsets, const int* __restrict__ srcS,
        const float4* __restrict__ a_s4, const float4* __restrict__ a_d4,
        const unsigned short* __restrict__ x16,    // [N,32]
        unsigned short* __restrict__ aggX,         // [N,128]
        int N) {
    __shared__ float4 wlds[4][64];
    __shared__ int slds[4][64];
    const int wid = threadIdx.x >> 6;
    const int n = blockIdx.x * 4 + wid;
    if (n >= N) return;
    const int lane = threadIdx.x & 63;
    const int q = lane >> 4;
    const int l16 = lane & 15;
    const int start = offsets[n], end = offsets[n + 1];
    const float4 ad = a_d4[n];
    float2 acc0 = {0,0}, acc1 = {0,0}, acc2 = {0,0}, acc3 = {0,0};
    float4 den = {0,0,0,0};
    const int loff = l16 << 1;     // 2 channels of 32

    for (int e0 = start; e0 < end; e0 += 64) {
        const int cnt = min(64, end - e0);
        if (lane < cnt) {
            int sB = srcS[e0 + lane];
            slds[wid][lane] = sB;
            const float4 as = a_s4[sB];
            float x0 = as.x + ad.x; x0 = fmaxf(x0, NEG_SLOPE * x0);
            float x1 = as.y + ad.y; x1 = fmaxf(x1, NEG_SLOPE * x1);
            float x2 = as.z + ad.z; x2 = fmaxf(x2, NEG_SLOPE * x2);
            float x3 = as.w + ad.w; x3 = fmaxf(x3, NEG_SLOPE * x3);
            wlds[wid][lane] = (float4){exp2f(x0), exp2f(x1), exp2f(x2), exp2f(x3)};
        }
        int j = q;
        for (; j + 12 < cnt; j += 16) {
            int ss[4]; float4 ww[4]; unsigned int gg[4];
            #pragma unroll
            for (int u = 0; u < 4; u++) {
                ss[u] = slds[wid][j + 4 * u];
                ww[u] = wlds[wid][j + 4 * u];
            }
            #pragma unroll
            for (int u = 0; u < 4; u++)
                gg[u] = *(const unsigned int*)&x16[((size_t)ss[u] << 5) + loff];
            #pragma unroll
            for (int u = 0; u < 4; u++) {
                const float vl = b2f_lo(gg[u]), vh = b2f_hi(gg[u]);
                acc0.x += ww[u].x * vl; acc0.y += ww[u].x * vh;
                acc1.x += ww[u].y * vl; acc1.y += ww[u].y * vh;
                acc2.x += ww[u].z * vl; acc2.y += ww[u].z * vh;
                acc3.x += ww[u].w * vl; acc3.y += ww[u].w * vh;
                den.x += ww[u].x; den.y += ww[u].y; den.z += ww[u].z; den.w += ww[u].w;
            }
        }
        for (; j + 4 < cnt; j += 8) {
            const int s0 = slds[wid][j], s1 = slds[wid][j + 4];
            const float4 w0 = wlds[wid][j], w1 = wlds[wid][j + 4];
            const unsigned int g0 = *(const unsigned int*)&x16[((size_t)s0 << 5) + loff];
            const unsigned int g1 = *(const unsigned int*)&x16[((size_t)s1 << 5) + loff];
            const float vl0 = b2f_lo(g0), vh0 = b2f_hi(g0);
            const float vl1 = b2f_lo(g1), vh1 = b2f_hi(g1);
            acc0.x += w0.x * vl0 + w1.x * vl1; acc0.y += w0.x * vh0 + w1.x * vh1;
            acc1.x += w0.y * vl0 + w1.y * vl1; acc1.y += w0.y * vh0 + w1.y * vh1;
            acc2.x += w0.z * vl0 + w1.z * vl1; acc2.y += w0.z * vh0 + w1.z * vh1;
            acc3.x += w0.w * vl0 + w1.w * vl1; acc3.y += w0.w * vh0 + w1.w * vh1;
            den.x += w0.x + w1.x; den.y += w0.y + w1.y;
            den.z += w0.z + w1.z; den.w += w0.w + w1.w;
        }
        for (; j < cnt; j += 4) {
            const int s = slds[wid][j];
            const float4 w = wlds[wid][j];
            const unsigned int g = *(const unsigned int*)&x16[((size_t)s << 5) + loff];
            const float vl = b2f_lo(g), vh = b2f_hi(g);
            acc0.x += w.x * vl; acc0.y += w.x * vh;
            acc1.x += w.y * vl; acc1.y += w.y * vh;
            acc2.x += w.z * vl; acc2.y += w.z * vh;
            acc3.x += w.w * vl; acc3.y += w.w * vh;
            den.x += w.x; den.y += w.y; den.z += w.z; den.w += w.w;
        }
    }
    #pragma unroll
    for (int off = 16; off < 64; off <<= 1) {
        acc0.x += __shfl_xor(acc0.x, off); acc0.y += __shfl_xor(acc0.y, off);
        acc1.x += __shfl_xor(acc1.x, off); acc1.y += __shfl_xor(acc1.y, off);
        acc2.x += __shfl_xor(acc2.x, off); acc2.y += __shfl_xor(acc2.y, off);
        acc3.x += __shfl_xor(acc3.x, off); acc3.y += __shfl_xor(acc3.y, off);
        den.x += __shfl_xor(den.x, off); den.y += __shfl_xor(den.y, off);
        den.z += __shfl_xor(den.z, off); den.w += __shfl_xor(den.w, off);
    }
    if (q == 0) {
        const float i0 = 1.0f / (den.x + 1e-16f);
        const float i1 = 1.0f / (den.y + 1e-16f);
        const float i2 = 1.0f / (den.z + 1e-16f);
        const float i3 = 1.0f / (den.w + 1e-16f);
        unsigned int o0 = (unsigned int)f2b(acc0.x * i0) | ((unsigned int)f2b(acc0.y * i0) << 16);
        unsigned int o1 = (unsigned int)f2b(acc1.x * i1) | ((unsigned int)f2b(acc1.y * i1) << 16);
        unsigned int o2 = (unsigned int)f2b(acc2.x * i2) | ((unsigned int)f2b(acc2.y * i2) << 16);
        unsigned int o3 = (unsigned int)f2b(acc3.x * i3) | ((unsigned int)f2b(acc3.y * i3) << 16);
        *(unsigned int*)&aggX[((size_t)n << 7) + 0 * 32 + loff] = o0;
        *(unsigned int*)&aggX[((size_t)n << 7) + 1 * 32 + loff] = o1;
        *(unsigned int*)&aggX[((size_t)n << 7) + 2 * 32 + loff] = o2;
        *(unsigned int*)&aggX[((size_t)n << 7) + 3 * 32 + loff] = o3;
    }
}

// ------------- conv2 aggregate (256-dim) + bias + ELU + CONV3 SCORES (a3 = h3 . u3) -------------
__global__ __launch_bounds__(256) void gat_fused4(
        const int* __restrict__ offsets, const int* __restrict__ srcS,
        const float4* __restrict__ a_s4, const float4* __restrict__ a_d4,
        const unsigned short* __restrict__ hW16, const float* __restrict__ bias,
        const float* __restrict__ u3s, const float* __restrict__ u3d,
        float* __restrict__ a_s3, float* __restrict__ a_d3,
        unsigned short* __restrict__ out16, int N) {
    __shared__ float wlds[4][64][4];
    __shared__ int slds[4][64];
    const int wid = threadIdx.x >> 6;
    const int n = blockIdx.x * 4 + wid;
    if (n >= N) return;
    const int lane = threadIdx.x & 63;
    const int quad = lane >> 4;
    const int start = offsets[n], end = offsets[n + 1];
    const float4 ad = a_d4[n];
    float4 acc = {0, 0, 0, 0};
    float den = 0.0f;
    const int loff = lane << 2;

    for (int e0 = start; e0 < end; e0 += 64) {
        const int cnt = min(64, end - e0);
        if (lane < cnt) {
            int sB = srcS[e0 + lane];
            slds[wid][lane] = sB;
            const float4 as = a_s4[sB];
            float x0 = as.x + ad.x; x0 = fmaxf(x0, NEG_SLOPE * x0);
            float x1 = as.y + ad.y; x1 = fmaxf(x1, NEG_SLOPE * x1);
            float x2 = as.z + ad.z; x2 = fmaxf(x2, NEG_SLOPE * x2);
            float x3 = as.w + ad.w; x3 = fmaxf(x3, NEG_SLOPE * x3);
            wlds[wid][lane][0] = exp2f(x0);
            wlds[wid][lane][1] = exp2f(x1);
            wlds[wid][lane][2] = exp2f(x2);
            wlds[wid][lane][3] = exp2f(x3);
        }
        int j = 0;
        for (; j + 4 <= cnt; j += 4) {
            const int s0 = __builtin_amdgcn_readfirstlane(slds[wid][j + 0]);
            const int s1 = __builtin_amdgcn_readfirstlane(slds[wid][j + 1]);
            const int s2 = __builtin_amdgcn_readfirstlane(slds[wid][j + 2]);
            const int s3 = __builtin_amdgcn_readfirstlane(slds[wid][j + 3]);
            const float w0 = wlds[wid][j + 0][quad];
            const float w1 = wlds[wid][j + 1][quad];
            const float w2 = wlds[wid][j + 2][quad];
            const float w3 = wlds[wid][j + 3][quad];
            const uint2 h0 = *(const uint2*)&hW16[((size_t)s0 << 8) + loff];
            const uint2 h1 = *(const uint2*)&hW16[((size_t)s1 << 8) + loff];
            const uint2 h2 = *(const uint2*)&hW16[((size_t)s2 << 8) + loff];
            const uint2 h3 = *(const uint2*)&hW16[((size_t)s3 << 8) + loff];
            acc.x += w0 * b2f_lo(h0.x); acc.y += w0 * b2f_hi(h0.x);
            acc.z += w0 * b2f_lo(h0.y); acc.w += w0 * b2f_hi(h0.y);
            acc.x += w1 * b2f_lo(h1.x); acc.y += w1 * b2f_hi(h1.x);
            acc.z += w1 * b2f_lo(h1.y); acc.w += w1 * b2f_hi(h1.y);
            acc.x += w2 * b2f_lo(h2.x); acc.y += w2 * b2f_hi(h2.x);
            acc.z += w2 * b2f_lo(h2.y); acc.w += w2 * b2f_hi(h2.y);
            acc.x += w3 * b2f_lo(h3.x); acc.y += w3 * b2f_hi(h3.x);
            acc.z += w3 * b2f_lo(h3.y); acc.w += w3 * b2f_hi(h3.y);
            den += (w0 + w1) + (w2 + w3);
        }
        for (; j < cnt; j++) {
            const int s = __builtin_amdgcn_readfirstlane(slds[wid][j]);
            const float w = wlds[wid][j][quad];
            const uint2 hv = *(const uint2*)&hW16[((size_t)s << 8) + loff];
            acc.x += w * b2f_lo(hv.x); acc.y += w * b2f_hi(hv.x);
            acc.z += w * b2f_lo(hv.y); acc.w += w * b2f_hi(hv.y);
            den += w;
        }
    }

    const float inv = 1.0f / (den + 1e-16f);
    const float4 bb = *(const float4*)&bias[loff];
    float v0 = acc.x * inv + bb.x; v0 = (v0 > 0.0f) ? v0 : expm1f(v0);
    float v1 = acc.y * inv + bb.y; v1 = (v1 > 0.0f) ? v1 : expm1f(v1);
    float v2 = acc.z * inv + bb.z; v2 = (v2 > 0.0f) ? v2 : expm1f(v2);
    float v3 = acc.w * inv + bb.w; v3 = (v3 > 0.0f) ? v3 : expm1f(v3);
    // conv3 scores from the fp32 h3 row (each lane owns 4 channels)
    {
        const float4 us = *(const float4*)&u3s[loff];
        const float4 ud = *(const float4*)&u3d[loff];
        float ps = v0 * us.x + v1 * us.y + v2 * us.z + v3 * us.w;
        float pd = v0 * ud.x + v1 * ud.y + v2 * ud.z + v3 * ud.w;
        #pragma unroll
        for (int off = 1; off < 64; off <<= 1) {
            ps += __shfl_xor(ps, off);
            pd += __shfl_xor(pd, off);
        }
        if (lane == 0) {
            a_s3[n] = ps * LOG2E;
            a_d3[n] = pd * LOG2E;
        }
    }
    uint2 o;
    o.x = (unsigned int)f2b(v0) | ((unsigned int)f2b(v1) << 16);
    o.y = (unsigned int)f2b(v2) | ((unsigned int)f2b(v3) << 16);
    *(uint2*)&out16[(size_t)n * 256 + loff] = o;
}

// ------------- H=1 fused (conv3): wave/node gather + PARTITIONED fused mean-pool -------------
__global__ __launch_bounds__(256) void gat_fused1(
        const int* __restrict__ offsets, const int* __restrict__ srcS,
        const float* __restrict__ a_s, const float* __restrict__ a_d,
        const unsigned short* __restrict__ hW16, const float* __restrict__ bias,
        const int* __restrict__ batch,
        float* __restrict__ pooledP, float* __restrict__ cntP, int N, int G) {
    __shared__ float wlds[4][64];
    __shared__ int slds[4][64];
    __shared__ float2 sOut[4][32];
    __shared__ int sG[4];
    const int wid = threadIdx.x >> 6;
    const int n = blockIdx.x * 4 + wid;
    const bool valid = n < N;                  // no early return: all waves reach the barrier
    const int lane = threadIdx.x & 63;
    const int half = lane >> 5;
    const int l32 = lane & 31;
    const int start = valid ? offsets[n] : 0;
    const int end   = valid ? offsets[n + 1] : 0;
    const float ad  = valid ? a_d[n] : 0.0f;
    float accx = 0.0f, accy = 0.0f, den = 0.0f;
    const int loff = l32 << 1;

    for (int e0 = start; e0 < end; e0 += 64) {
        const int cnt_ = min(64, end - e0);
        if (lane < cnt_) {
            int sB = srcS[e0 + lane];
            slds[wid][lane] = sB;
            float ev = a_s[sB] + ad;
            ev = fmaxf(ev, NEG_SLOPE * ev);
            wlds[wid][lane] = exp2f(ev);
        }
        int j = half;
        for (; j + 8 <= cnt_ + half; j += 8) {
            const int s0 = slds[wid][j + 0];
            const int s1 = slds[wid][j + 2];
            const int s2 = slds[wid][j + 4];
            const int s3 = slds[wid][j + 6];
            const float w0 = wlds[wid][j + 0];
            const float w1 = wlds[wid][j + 2];
            const float w2 = wlds[wid][j + 4];
            const float w3 = wlds[wid][j + 6];
            const unsigned int h0 = *(const unsigned int*)&hW16[((size_t)s0 << 6) + loff];
            const unsigned int h1 = *(const unsigned int*)&hW16[((size_t)s1 << 6) + loff];
            const unsigned int h2 = *(const unsigned int*)&hW16[((size_t)s2 << 6) + loff];
            const unsigned int h3 = *(const unsigned int*)&hW16[((size_t)s3 << 6) + loff];
            accx += w0 * b2f_lo(h0); accy += w0 * b2f_hi(h0);
            accx += w1 * b2f_lo(h1); accy += w1 * b2f_hi(h1);
            accx += w2 * b2f_lo(h2); accy += w2 * b2f_hi(h2);
            accx += w3 * b2f_lo(h3); accy += w3 * b2f_hi(h3);
            den += (w0 + w1) + (w2 + w3);
        }
        for (; j < cnt_; j += 2) {
            const int s = slds[wid][j];
            const float w = wlds[wid][j];
            const unsigned int hv = *(const unsigned int*)&hW16[((size_t)s << 6) + loff];
            accx += w * b2f_lo(hv);
            accy += w * b2f_hi(hv);
            den += w;
        }
    }
    accx += __shfl_xor(accx, 32);
    accy += __shfl_xor(accy, 32);
    den  += __shfl_xor(den, 32);
    if (half == 0) {
        if (valid) {
            const float inv = 1.0f / (den + 1e-16f);
            sOut[wid][l32] = (float2){accx * inv + bias[loff], accy * inv + bias[loff + 1]};
        } else {
            sOut[wid][l32] = (float2){0.0f, 0.0f};
        }
        if (l32 == 0) sG[wid] = valid ? batch[n] : -1;
    }
    __syncthreads();
    const int p = blockIdx.x & 63;
    if (wid == 0 && half == 0) {
        const int g0 = sG[0], g1 = sG[1], g2 = sG[2], g3 = sG[3];
        if (g0 >= 0 && g1 == g0 && g2 == g0 && g3 == g0) {
            const float2 s0 = sOut[0][l32], s1 = sOut[1][l32];
            const float2 s2 = sOut[2][l32], s3 = sOut[3][l32];
            float* base = pooledP + ((size_t)p * G + g0) * 64;
            atomicAdd(&base[loff],     (s0.x + s1.x) + (s2.x + s3.x));
            atomicAdd(&base[loff + 1], (s0.y + s1.y) + (s2.y + s3.y));
            if (l32 == 0) atomicAdd(&cntP[p * G + g0], 4.0f);
        } else {
            #pragma unroll
            for (int w = 0; w < 4; w++) {
                const int g = sG[w];
                if (g >= 0) {
                    const float2 s = sOut[w][l32];
                    float* base = pooledP + ((size_t)p * G + g) * 64;
                    atomicAdd(&base[loff], s.x);
                    atomicAdd(&base[loff + 1], s.y);
                    if (l32 == 0) atomicAdd(&cntP[p * G + g], 1.0f);
                }
            }
        }
    }
}

// ------------- decoder head: one block per graph (reduces 64 pool partitions first) -------------
__global__ __launch_bounds__(256) void final_kernel(
        const float* __restrict__ pooledP, const float* __restrict__ cntP,
        const float* __restrict__ gf, const float* __restrict__ Wg,
        const float* __restrict__ bg, const float* __restrict__ Wd1,
        const float* __restrict__ bd1, const float* __restrict__ gamma,
        const float* __restrict__ beta, const float* __restrict__ Wd2,
        const float* __restrict__ bd2, float* __restrict__ out, int G) {
    const int g = blockIdx.x;
    const int tid = threadIdx.x;
    const int lane = tid & 63;
    const int wave = tid >> 6;
    __shared__ float sPart[4][64];
    __shared__ float sCntTot;
    __shared__ float spg[128];
    __shared__ float sz[64];
    __shared__ float wred[8];

    {   // partition reduce: wave pg sums partitions [pg*16, pg*16+16)
        const int c = lane;
        const int pg = wave;
        float a = 0.0f;
        #pragma unroll
        for (int p = 0; p < 16; p++)
            a += pooledP[((size_t)(pg * 16 + p) * G + g) * 64 + c];
        sPart[pg][c] = a;
        if (pg == 1) {
            float cv = cntP[c * G + g];
            #pragma unroll
            for (int off = 32; off > 0; off >>= 1) cv += __shfl_xor(cv, off);
            if (c == 0) sCntTot = cv;
        }
    }
    __syncthreads();
    if (tid < 64) {
        spg[tid] = (sPart[0][tid] + sPart[1][tid] + sPart[2][tid] + sPart[3][tid])
                   / fmaxf(sCntTot, 1.0f);
    } else if (tid < 128) {
        int c = tid - 64;
        float v = bg[c];
        #pragma unroll
        for (int k = 0; k < 4; k++) v += gf[g * 4 + k] * Wg[k * 64 + c];
        spg[64 + c] = fmaxf(v, 0.0f);
    }
    __syncthreads();
    if (tid < 64) {
        float v = bd1[tid];
        #pragma unroll 8
        for (int k = 0; k < 128; k++) v += spg[k] * Wd1[k * 64 + tid];
        v = v * gamma[tid] + beta[tid];
        sz[tid] = fmaxf(v, 0.0f);
    }
    __syncthreads();
    float v = bd2[tid];
    #pragma unroll 8
    for (int k = 0; k < 64; k++) v += sz[k] * Wd2[k * 256 + tid];
    float m = v;
    #pragma unroll
    for (int off = 32; off > 0; off >>= 1) m = fmaxf(m, __shfl_xor(m, off));
    if (lane == 0) wred[wave] = m;
    __syncthreads();
    float M = fmaxf(fmaxf(wred[0], wred[1]), fmaxf(wred[2], wred[3]));
    float e = expf(v - M);
    float s = e;
    #pragma unroll
    for (int off = 32; off > 0; off >>= 1) s += __shfl_xor(s, off);
    if (lane == 0) wred[4 + wave] = s;
    __syncthreads();
    float S = (wred[4] + wred[5]) + (wred[6] + wred[7]);
    out[g * 256 + tid] = e / S;
}

extern "C" void kernel_launch(void* const* d_in, const int* in_sizes, int n_in,
                              void* d_out, int out_size, void* d_ws, size_t ws_size,
                              hipStream_t stream) {
    const float* x     = (const float*)d_in[0];
    const int*   ei    = (const int*)  d_in[1];
    const int*   batch = (const int*)  d_in[2];
    const float* gf    = (const float*)d_in[3];
    const float* W_enc = (const float*)d_in[4];
    const float* b_enc = (const float*)d_in[5];
    const float* W1  = (const float*)d_in[6];
    const float* as1 = (const float*)d_in[7];
    const float* ad1 = (const float*)d_in[8];
    const float* b1  = (const float*)d_in[9];
    const float* W2  = (const float*)d_in[10];
    const float* as2 = (const float*)d_in[11];
    const float* ad2 = (const float*)d_in[12];
    const float* b2  = (const float*)d_in[13];
    const float* W3  = (const float*)d_in[14];
    const float* as3 = (const float*)d_in[15];
    const float* ad3 = (const float*)d_in[16];
    const float* b3  = (const float*)d_in[17];
    const float* Wg  = (const float*)d_in[18];
    const float* bg  = (const float*)d_in[19];
    const float* Wd1 = (const float*)d_in[20];
    const float* bd1 = (const float*)d_in[21];
    const float* gm  = (const float*)d_in[22];
    const float* bt  = (const float*)d_in[23];
    const float* Wd2 = (const float*)d_in[24];
    const float* bd2 = (const float*)d_in[25];

    const int N  = in_sizes[2];
    const int E  = in_sizes[1] / 2;
    const int G  = in_sizes[3] / 4;
    const int Et = E + N;

    unsigned short* h16a = (unsigned short*)d_ws;                // [N,256] conv2 gather table
    unsigned short* h16b = h16a + (size_t)N * 256;               // [N,256]: aggX[N,128] early, then conv2 agg out
    unsigned short* h1_16 = h16b + (size_t)N * 256;              // [N,64] conv3 gather table
    unsigned short* x16  = h1_16 + (size_t)N * 64;               // [N,32] bf16
    unsigned short* Wc1t = x16 + (size_t)N * 32;                 // [4][64][32]
    unsigned short* Wt2  = Wc1t + 4 * 64 * 32;                   // [256,256]
    unsigned short* Wt3  = Wt2 + 256 * 256;                      // [64,256]
    float* bc1    = (float*)(Wt3 + 64 * 256);                    // [256]
    float* a_s    = bc1 + 256;                                   // [N,4]
    float* a_d    = a_s + (size_t)N * 4;                         // [N,4]
    float* a_s3   = a_d + (size_t)N * 4;                         // [N]
    float* a_d3   = a_s3 + N;                                    // [N]
    float* u1s    = a_d3 + N;                                    // [64,4]
    float* u1d    = u1s + 256;                                   // [64,4]
    float* u3s    = u1d + 256;                                   // [256]
    float* u3d    = u3s + 256;                                   // [256]
    float* pooledP = u3d + 256;                                  // [64][G][64]
    float* cntP   = pooledP + (size_t)64 * G * 64;               // [64][G]
    int*   offsets = (int*)(cntP + 64 * G);                      // [N+1]
    int*   srcS    = offsets + (N + 1);                          // [Et]
    int*   counts  = srcS + Et;                                  // [N]
    int*   cursor  = counts + N;                                 // [N]
    int*   blockSums = cursor + N;                               // [cdiv(N,1024)]

    dim3 blk(256);
    auto cdiv = [](int a, int b) { return (a + b - 1) / b; };
    const int eBlocks = cdiv(Et, 256);
    const int rowBlocks = cdiv(N, 64);
    const int nScanBlocks = cdiv(N, 1024);
    const int zc = cdiv(N, 256);
    const int z2 = cdiv(64 * G * 64, 256);

    // ---------------- prep (folded weights + u-vectors + zero-init) + CSR build ----------------
    prep_kernel<<<355 + zc + z2, blk, 0, stream>>>(W_enc, b_enc, W1, W2, W3, as1, ad1, b1,
                                                   as3, ad3, Wc1t, bc1, Wt2, Wt3,
                                                   u1s, u1d, u3s, u3d,
                                                   counts, pooledP, cntP, N, G, zc);
    edge_hist_kernel<<<eBlocks, blk, 0, stream>>>(ei, counts, E, Et);
    scan_blocks<<<nScanBlocks, 1024, 0, stream>>>(counts, blockSums, N);
    scan_add2<<<cdiv(N + 1, 256), blk, 0, stream>>>(counts, blockSums, nScanBlocks,
                                                    offsets, cursor, N, Et);
    edge_sort_kernel<<<eBlocks, blk, 0, stream>>>(ei, cursor, srcS, E, Et);

    // conv1 scores from raw x + x->bf16
    score_x<<<cdiv(N, 32), blk, 0, stream>>>(x, W_enc, b_enc, u1s, u1d, x16, a_s, a_d, N);

    // ---------------- conv1 aggregate (raw x) -> fused conv1+conv2 GEMM ----------------
    gat_agg_x32<<<cdiv(N, 4), blk, 0, stream>>>(offsets, srcS, (const float4*)a_s,
                                                (const float4*)a_d, x16, h16b, N);
    gemm_c12<<<rowBlocks, blk, 0, stream>>>(h16b, Wc1t, bc1, Wt2, as2, ad2,
                                            a_s, a_d, h16a, N);

    // ---------------- conv2 aggregate (+conv3 scores fused) ----------------
    gat_fused4<<<cdiv(N, 4), blk, 0, stream>>>(offsets, srcS, (const float4*)a_s,
                                               (const float4*)a_d, h16a, b2,
                                               u3s, u3d, a_s3, a_d3, h16b, N);

    // ---------------- conv3: GEMM (no scores) -> aggregate + partitioned pool ----------------
    gemm_mfma<1, 0><<<dim3(rowBlocks, 1), blk, 0, stream>>>(h16b, Wt3, h1_16,
                                                            nullptr, nullptr, nullptr, nullptr,
                                                            N, 256, 64, 1);
    gat_fused1<<<cdiv(N, 4), blk, 0, stream>>>(offsets, srcS, a_s3, a_d3, h1_16, b3,
                                               batch, pooledP, cntP, N, G);

    // ---------------- decoder head ----------------
    final_kernel<<<G, blk, 0, stream>>>(pooledP, cntP, gf, Wg, bg, Wd1, bd1, gm, bt, Wd2, bd2,
                                        (float*)d_out, G);
}

// Round 7
// 384.440 us; speedup vs baseline: 1.2011x; 1.0524x over previous
//
#include <hip/hip_runtime.h>
#include <math.h>

#define NEG_SLOPE 0.2f
#define LOG2E 1.4426950408889634f

typedef __attribute__((ext_vector_type(8))) short short8;   // 8 bf16 = 4 VGPRs
typedef __attribute__((ext_vector_type(4))) float f32x4;    // MFMA acc

#if __has_builtin(__builtin_amdgcn_cvt_pk_f32_fp8) && __has_builtin(__builtin_amdgcn_cvt_pk_fp8_f32)
#define FP8_HW 1
#else
#define FP8_HW 0
#endif

__device__ inline float b2f_lo(unsigned int u) {
    union { unsigned int i; float f; } x; x.i = u << 16; return x.f;
}
__device__ inline float b2f_hi(unsigned int u) {
    union { unsigned int i; float f; } x; x.i = u & 0xFFFF0000u; return x.f;
}
__device__ inline unsigned short f2b(float f) {
    union { float f; unsigned int i; } u; u.f = f;
    unsigned int r = u.i + 0x7FFF + ((u.i >> 16) & 1);   // round-to-nearest-even
    return (unsigned short)(r >> 16);
}

// ---- OCP e4m3 helpers (HW cvt on gfx950; exact manual fallback) ----
__device__ inline float fp8_decode1(unsigned int b) {
    unsigned int e = (b >> 3) & 15, m = b & 7;
    union { unsigned int i; float f; } u;
    if (e == 0) u.f = (float)m * 0.001953125f;          // subnormal: m * 2^-9
    else u.i = ((e + 120) << 23) | (m << 20);            // (1+m/8) * 2^(e-7)
    if (b & 0x80) u.f = -u.f;
    return u.f;
}
__device__ inline void fp8x4_to_f32(unsigned int g, float& v0, float& v1,
                                    float& v2, float& v3) {
#if FP8_HW
    auto lo = __builtin_amdgcn_cvt_pk_f32_fp8((int)g, false);   // bytes 0,1
    auto hi = __builtin_amdgcn_cvt_pk_f32_fp8((int)g, true);    // bytes 2,3
    v0 = lo[0]; v1 = lo[1]; v2 = hi[0]; v3 = hi[1];
#else
    v0 = fp8_decode1(g & 255);         v1 = fp8_decode1((g >> 8) & 255);
    v2 = fp8_decode1((g >> 16) & 255); v3 = fp8_decode1((g >> 24) & 255);
#endif
}
__device__ inline unsigned char f32_to_fp8(float f) {
#if FP8_HW
    return (unsigned char)(__builtin_amdgcn_cvt_pk_fp8_f32(f, f, 0, false) & 0xFF);
#else
    union { float f; unsigned int i; } u; u.f = f;
    unsigned int s = (u.i >> 24) & 0x80;
    float a = fabsf(f);
    if (a < 0.015625f) {                                 // subnormal band
        int m = (int)rintf(a * 512.0f);
        if (m > 7) return (unsigned char)(s | 0x08);
        return (unsigned char)(s | m);
    }
    if (a >= 448.0f) return (unsigned char)(s | 0x7E);
    int e = (int)((u.i >> 23) & 0xFF) - 127;
    union { unsigned int i; float f; } sc; sc.i = (unsigned int)(127 + 3 - e) << 23;
    int q = (int)rintf(a * sc.f);                        // in [8,16]
    if (q >= 16) { q = 8; e += 1; }
    return (unsigned char)(s | ((unsigned int)(e + 7) << 3) | (unsigned int)(q - 8));
#endif
}

// ---------------- prep: folded conv1 weights (Wc1 = W_enc@W1, bc1), u1/u3 vectors,
// Wt2/Wt3 transposes, and ALL zero-init ----------------
__global__ void prep_kernel(const float* __restrict__ W_enc, const float* __restrict__ b_enc,
                            const float* __restrict__ W1, const float* __restrict__ W2,
                            const float* __restrict__ W3, const float* __restrict__ as1,
                            const float* __restrict__ ad1, const float* __restrict__ b1,
                            const float* __restrict__ as3, const float* __restrict__ ad3,
                            unsigned short* __restrict__ Wc1t, float* __restrict__ bc1,
                            unsigned short* __restrict__ Wt2, unsigned short* __restrict__ Wt3,
                            float* __restrict__ u1s, float* __restrict__ u1d,
                            float* __restrict__ u3s, float* __restrict__ u3d,
                            int* __restrict__ counts, float* __restrict__ pooledP,
                            float* __restrict__ cntP, int N, int G, int zc) {
    const int b = blockIdx.x;
    const int t = threadIdx.x;
    if (b < 32) {
        // Wc1t[h][o][j] = sum_k W_enc[j][k] * W1[k][h*64+o]   (bf16, B^T layout)
        int i = b * 256 + t;                       // 8192 values
        int h = i >> 11, rem = i & 2047, o = rem >> 5, j = rem & 31;
        float s = 0.0f;
        for (int k = 0; k < 64; k++)
            s += W_enc[j * 64 + k] * W1[k * 256 + h * 64 + o];
        Wc1t[i] = f2b(s);
    } else if (b == 32) {
        // bc1[c] = b1[c] + sum_k b_enc[k] * W1[k][c]   (uses sum(alpha)=1)
        float s = b1[t];
        for (int k = 0; k < 64; k++) s += b_enc[k] * W1[k * 256 + t];
        bc1[t] = s;
    } else if (b == 33) {
        // u1 score projections in h1-space (consumed by score_x)
        int k = t >> 2, h = t & 3;
        float s = 0.0f, d = 0.0f;
        for (int c = 0; c < 64; c++) {
            float w = W1[k * 256 + h * 64 + c];
            s += w * as1[h * 64 + c];
            d += w * ad1[h * 64 + c];
        }
        u1s[k * 4 + h] = s;
        u1d[k * 4 + h] = d;
    } else if (b == 34) {
        // u3 = W3 @ as3 (conv3 scores computed from h3 directly: a3 = h3 . u3)
        float s = 0.0f, d = 0.0f;
        for (int o = 0; o < 64; o++) {
            float w = W3[t * 64 + o];
            s += w * as3[o];
            d += w * ad3[o];
        }
        u3s[t] = s; u3d[t] = d;
    } else if (b < 35 + 256) {
        int i = (b - 35) * 256 + t;                // K=256, M=256
        int k = i >> 8, m = i & 255;
        Wt2[(size_t)m * 256 + k] = f2b(W2[i]);
    } else if (b < 35 + 256 + 64) {
        int i = (b - 291) * 256 + t;               // K=256, M=64
        int k = i >> 6, m = i & 63;
        Wt3[(size_t)m * 256 + k] = f2b(W3[i]);
    } else if (b < 355 + zc) {
        int i = (b - 355) * 256 + t;
        if (i < N) counts[i] = 0;
    } else {
        int i = (b - 355 - zc) * 256 + t;
        if (i < 64 * G * 64) pooledP[i] = 0.0f;    // [64 partitions][G][64]
        if (i < 64 * G) cntP[i] = 0.0f;            // [64 partitions][G]
    }
}

// ---------------- score_x: conv1 scores directly from x (a = x*(W_enc@u1) + b_enc@u1),
// plus x -> bf16 conversion. ----------------
__global__ __launch_bounds__(256) void score_x(
        const float* __restrict__ x, const float* __restrict__ W_enc,
        const float* __restrict__ b_enc,
        const float* __restrict__ u1s, const float* __restrict__ u1d,
        unsigned short* __restrict__ x16, float* __restrict__ a_s,
        float* __restrict__ a_d, int N) {
    __shared__ float sUs[32][4], sUd[32][4], sC[8];
    __shared__ float sX[32][33];
    const int t = threadIdx.x;
    if (t < 128) {
        int j = t >> 2, h = t & 3;
        float s = 0.0f, d = 0.0f;
        for (int k = 0; k < 64; k++) {
            float w = W_enc[j * 64 + k];
            s += w * u1s[k * 4 + h];
            d += w * u1d[k * 4 + h];
        }
        sUs[j][h] = s; sUd[j][h] = d;
    } else if (t < 136) {
        int hh = t - 128;                           // 0..3 -> s, 4..7 -> d
        const float* u = (hh < 4) ? u1s : u1d;
        int h = hh & 3;
        float c = 0.0f;
        for (int k = 0; k < 64; k++) c += b_enc[k] * u[k * 4 + h];
        sC[hh] = c;
    }
    const int n0 = blockIdx.x * 32;
    const int row = t >> 3, col = (t & 7) << 2;
    float4 xv = {0, 0, 0, 0};
    if (n0 + row < N) xv = *(const float4*)&x[(size_t)(n0 + row) * 32 + col];
    sX[row][col + 0] = xv.x; sX[row][col + 1] = xv.y;
    sX[row][col + 2] = xv.z; sX[row][col + 3] = xv.w;
    __syncthreads();
    const int ni = t >> 3, oi = t & 7, h = oi & 3;
    const bool isS = oi < 4;
    float acc = sC[oi];
    #pragma unroll 8
    for (int j = 0; j < 32; j++) acc += sX[ni][j] * (isS ? sUs[j][h] : sUd[j][h]);
    if (n0 + ni < N) {
        float* out = isS ? a_s : a_d;
        out[(size_t)(n0 + ni) * 4 + h] = acc * LOG2E;
    }
    if (n0 + row < N) {
        ushort4 o = {f2b(xv.x), f2b(xv.y), f2b(xv.z), f2b(xv.w)};
        *(ushort4*)&x16[(size_t)(n0 + row) * 32 + col] = o;
    }
}

// ---------------- MFMA GEMM: C16[N,M] = A16[N,K] @ Wt16^T; optional fused scores ----------------
template<int CPW, int SCORES>
__global__ __launch_bounds__(256) void gemm_mfma(const unsigned short* __restrict__ A16,
                                                 const unsigned short* __restrict__ Bt16,
                                                 unsigned short* __restrict__ C16,
                                                 const float* __restrict__ att_s,
                                                 const float* __restrict__ att_d,
                                                 float* __restrict__ a_s,
                                                 float* __restrict__ a_d,
                                                 int Nrows, int K, int M, int H) {
    constexpr int BN = CPW * 64;
    __shared__ unsigned short sA[64][40];
    __shared__ unsigned short sB[BN][40];
    const int tid = threadIdx.x;
    const int wave = tid >> 6;
    const int lane = tid & 63;
    const int quad = lane >> 4;
    const int l16 = lane & 15;
    const int row0 = blockIdx.x * 64;
    const int col0 = blockIdx.y * BN;
    const int sr = tid >> 2;
    const int sk = (tid & 3) << 3;

    f32x4 acc[4][CPW];
    #pragma unroll
    for (int i = 0; i < 4; i++)
        #pragma unroll
        for (int j = 0; j < CPW; j++) acc[i][j] = (f32x4){0,0,0,0};

    for (int kt = 0; kt < K; kt += 32) {
        __syncthreads();
        {
            int r = row0 + sr;
            uint4 z = {0,0,0,0};
            *(uint4*)&sA[sr][sk] = (r < Nrows) ? *(const uint4*)&A16[(size_t)r * K + kt + sk] : z;
        }
        #pragma unroll
        for (int i = 0; i < CPW; i++) {
            int c = col0 + sr + i * 64;
            *(uint4*)&sB[sr + i * 64][sk] = *(const uint4*)&Bt16[(size_t)c * K + kt + sk];
        }
        __syncthreads();
        short8 bf[CPW];
        #pragma unroll
        for (int j = 0; j < CPW; j++)
            bf[j] = *(const short8*)&sB[wave * (CPW * 16) + j * 16 + l16][quad * 8];
        #pragma unroll
        for (int i = 0; i < 4; i++) {
            short8 af = *(const short8*)&sA[i * 16 + l16][quad * 8];
            #pragma unroll
            for (int j = 0; j < CPW; j++)
                acc[i][j] = __builtin_amdgcn_mfma_f32_16x16x32_bf16(af, bf[j], acc[i][j], 0, 0, 0);
        }
    }
    if (SCORES) {
        __shared__ float sSD[64][CPW][2];
        for (int t = tid; t < 64 * CPW * 2; t += 256) ((float*)sSD)[t] = 0.0f;
        __syncthreads();
        const int hib = (wave * (CPW * 16)) >> 6;
        float avs[CPW], avd[CPW];
        #pragma unroll
        for (int j = 0; j < CPW; j++) {
            int c = col0 + wave * (CPW * 16) + j * 16 + l16;
            avs[j] = att_s[c];
            avd[j] = att_d[c];
        }
        #pragma unroll
        for (int i = 0; i < 4; i++) {
            float ps[4] = {0,0,0,0}, pd[4] = {0,0,0,0};
            #pragma unroll
            for (int j = 0; j < CPW; j++)
                #pragma unroll
                for (int r = 0; r < 4; r++) {
                    ps[r] += acc[i][j][r] * avs[j];
                    pd[r] += acc[i][j][r] * avd[j];
                }
            #pragma unroll
            for (int off = 1; off < 16; off <<= 1)
                #pragma unroll
                for (int r = 0; r < 4; r++) {
                    ps[r] += __shfl_xor(ps[r], off);
                    pd[r] += __shfl_xor(pd[r], off);
                }
            if (l16 == 0) {
                #pragma unroll
                for (int r = 0; r < 4; r++) {
                    atomicAdd(&sSD[i * 16 + quad * 4 + r][hib][0], ps[r]);
                    atomicAdd(&sSD[i * 16 + quad * 4 + r][hib][1], pd[r]);
                }
            }
        }
        __syncthreads();
        for (int t = tid; t < 64 * CPW; t += 256) {
            int row = t & 63, hb = t >> 6;
            int r = row0 + row;
            if (r < Nrows) {
                int hg = (col0 >> 6) + hb;
                a_s[r * H + hg] = sSD[row][hb][0] * LOG2E;
                a_d[r * H + hg] = sSD[row][hb][1] * LOG2E;
            }
        }
    }
    #pragma unroll
    for (int i = 0; i < 4; i++) {
        #pragma unroll
        for (int j = 0; j < CPW; j++) {
            int col = col0 + wave * (CPW * 16) + j * 16 + l16;
            #pragma unroll
            for (int r = 0; r < 4; r++) {
                int row = row0 + i * 16 + quad * 4 + r;
                if (row < Nrows) C16[(size_t)row * M + col] = f2b(acc[i][j][r]);
            }
        }
    }
}

// ---------------- FUSED conv1-GEMM + conv2-GEMM. h2 never hits HBM in bf16: the conv2
// gather table is written as fp8-e4m3 (halves gat_fused4's fetch). Scores fp32. ----------------
__global__ __launch_bounds__(256) void gemm_c12(
        const unsigned short* __restrict__ aggX,   // [N,128]
        const unsigned short* __restrict__ Wc1t,   // [(h*64+o)*32 + j]
        const float* __restrict__ bc1,             // [256]
        const unsigned short* __restrict__ Wt2,    // [256][256] B^T
        const float* __restrict__ att_s,           // as2 [256]
        const float* __restrict__ att_d,
        float* __restrict__ a_s, float* __restrict__ a_d,   // [N,4] conv2 scores
        unsigned char* __restrict__ C8,            // [N,256] fp8 conv2 gather table
        int Nrows) {
    __shared__ unsigned short sH[64][264];   // h2 tile (row stride 528B)
    __shared__ unsigned short sB[256][40];
    __shared__ float sSD[64][4][2];
    const int tid = threadIdx.x;
    const int wave = tid >> 6;
    const int lane = tid & 63;
    const int quad = lane >> 4;
    const int l16 = lane & 15;
    const int row0 = blockIdx.x * 64;
    const int sr = tid >> 2;
    const int sk = (tid & 3) << 3;

    // ---- phase 1: conv1 (folded, K=32) per head -> sH ----
    #pragma unroll
    for (int h = 0; h < 4; h++) {
        __syncthreads();
        {
            int r = row0 + sr;
            uint4 z = {0,0,0,0};
            *(uint4*)&sB[sr][sk] = (r < Nrows)
                ? *(const uint4*)&aggX[(size_t)r * 128 + h * 32 + sk] : z;
            *(uint4*)&sB[64 + sr][sk] = *(const uint4*)&Wc1t[(size_t)(h * 64 + sr) * 32 + sk];
        }
        __syncthreads();
        short8 bf = *(const short8*)&sB[64 + wave * 16 + l16][quad * 8];
        const int col = h * 64 + wave * 16 + l16;
        const float bb = bc1[col];
        #pragma unroll
        for (int i = 0; i < 4; i++) {
            short8 af = *(const short8*)&sB[i * 16 + l16][quad * 8];
            f32x4 acc = __builtin_amdgcn_mfma_f32_16x16x32_bf16(af, bf, (f32x4){0,0,0,0}, 0, 0, 0);
            #pragma unroll
            for (int r = 0; r < 4; r++) {
                float v = acc[r] + bb;
                v = (v > 0.0f) ? v : expm1f(v);        // ELU
                sH[i * 16 + quad * 4 + r][col] = f2b(v);
            }
        }
    }

    // ---- phase 2: conv2 GEMM, A from sH, BN=256 ----
    f32x4 acc2[4][4];
    #pragma unroll
    for (int i = 0; i < 4; i++)
        #pragma unroll
        for (int j = 0; j < 4; j++) acc2[i][j] = (f32x4){0,0,0,0};

    for (int kt = 0; kt < 256; kt += 32) {
        __syncthreads();
        #pragma unroll
        for (int i = 0; i < 4; i++) {
            int c = sr + i * 64;
            *(uint4*)&sB[c][sk] = *(const uint4*)&Wt2[(size_t)c * 256 + kt + sk];
        }
        __syncthreads();
        short8 bf2[4];
        #pragma unroll
        for (int j = 0; j < 4; j++)
            bf2[j] = *(const short8*)&sB[wave * 64 + j * 16 + l16][quad * 8];
        #pragma unroll
        for (int i = 0; i < 4; i++) {
            short8 af = *(const short8*)&sH[i * 16 + l16][kt + quad * 8];
            #pragma unroll
            for (int j = 0; j < 4; j++)
                acc2[i][j] = __builtin_amdgcn_mfma_f32_16x16x32_bf16(af, bf2[j], acc2[i][j], 0, 0, 0);
        }
    }

    // ---- conv2 scores (fp32, before fp8 encode) ----
    {
        for (int t = tid; t < 512; t += 256) ((float*)sSD)[t] = 0.0f;
        __syncthreads();
        float avs[4], avd[4];
        #pragma unroll
        for (int j = 0; j < 4; j++) {
            int c = wave * 64 + j * 16 + l16;
            avs[j] = att_s[c];
            avd[j] = att_d[c];
        }
        #pragma unroll
        for (int i = 0; i < 4; i++) {
            float ps[4] = {0,0,0,0}, pd[4] = {0,0,0,0};
            #pragma unroll
            for (int j = 0; j < 4; j++)
                #pragma unroll
                for (int r = 0; r < 4; r++) {
                    ps[r] += acc2[i][j][r] * avs[j];
                    pd[r] += acc2[i][j][r] * avd[j];
                }
            #pragma unroll
            for (int off = 1; off < 16; off <<= 1)
                #pragma unroll
                for (int r = 0; r < 4; r++) {
                    ps[r] += __shfl_xor(ps[r], off);
                    pd[r] += __shfl_xor(pd[r], off);
                }
            if (l16 == 0) {
                #pragma unroll
                for (int r = 0; r < 4; r++) {
                    atomicAdd(&sSD[i * 16 + quad * 4 + r][wave][0], ps[r]);
                    atomicAdd(&sSD[i * 16 + quad * 4 + r][wave][1], pd[r]);
                }
            }
        }
        __syncthreads();
        {
            int row = tid & 63, hb = tid >> 6;
            int r = row0 + row;
            if (r < Nrows) {
                a_s[r * 4 + hb] = sSD[row][hb][0] * LOG2E;
                a_d[r * 4 + hb] = sSD[row][hb][1] * LOG2E;
            }
        }
    }
    // ---- C write (fp8 e4m3) ----
    #pragma unroll
    for (int i = 0; i < 4; i++) {
        #pragma unroll
        for (int j = 0; j < 4; j++) {
            int col = wave * 64 + j * 16 + l16;
            #pragma unroll
            for (int r = 0; r < 4; r++) {
                int row = row0 + i * 16 + quad * 4 + r;
                if (row < Nrows) C8[(size_t)row * 256 + col] = f32_to_fp8(acc2[i][j][r]);
            }
        }
    }
}

// ------------- CSR build -------------
__global__ void edge_hist_kernel(const int* __restrict__ ei, int* __restrict__ counts,
                                 int E, int Et) {
    int e = blockIdx.x * 256 + threadIdx.x;
    if (e >= Et) return;
    int d = (e < E) ? ei[E + e] : e - E;
    atomicAdd(&counts[d], 1);
}

__global__ __launch_bounds__(1024) void scan_blocks(int* __restrict__ counts,
                                                    int* __restrict__ blockSums, int N) {
    __shared__ int wsum[16];
    const int tid = threadIdx.x;
    const int lane = tid & 63;
    const int wave = tid >> 6;
    int i = blockIdx.x * 1024 + tid;
    int v = (i < N) ? counts[i] : 0;
    int s = v;
    #pragma unroll
    for (int off = 1; off < 64; off <<= 1) {
        int t = __shfl_up(s, off);
        if (lane >= off) s += t;
    }
    if (lane == 63) wsum[wave] = s;
    __syncthreads();
    if (wave == 0 && lane < 16) {
        int ws = wsum[lane];
        #pragma unroll
        for (int off = 1; off < 16; off <<= 1) {
            int t = __shfl_up(ws, off);
            if (lane >= off) ws += t;
        }
        wsum[lane] = ws;
    }
    __syncthreads();
    int waveOff = (wave > 0) ? wsum[wave - 1] : 0;
    int incl = s + waveOff;
    if (i < N) counts[i] = incl - v;
    if (tid == 1023) blockSums[blockIdx.x] = incl;
}

__global__ void scan_add2(const int* __restrict__ excl, const int* __restrict__ blockSums,
                          int nb, int* __restrict__ offsets, int* __restrict__ cursor,
                          int N, int Et) {
    __shared__ int sbs[64];
    if (threadIdx.x < 64) {
        int lane = threadIdx.x;
        int v = (lane < nb) ? blockSums[lane] : 0;
        int s = v;
        #pragma unroll
        for (int off = 1; off < 64; off <<= 1) {
            int t = __shfl_up(s, off);
            if (lane >= off) s += t;
        }
        sbs[lane] = s - v;                 // exclusive
    }
    __syncthreads();
    int i = blockIdx.x * 256 + threadIdx.x;
    if (i < N) {
        int o = excl[i] + sbs[i >> 10];
        offsets[i] = o;
        cursor[i] = o;
    }
    if (i == N) offsets[N] = Et;
}

__global__ void edge_sort_kernel(const int* __restrict__ ei, int* __restrict__ cursor,
                                 int* __restrict__ srcS, int E, int Et) {
    int e = blockIdx.x * 256 + threadIdx.x;
    if (e >= Et) return;
    int s, d;
    if (e < E) { s = ei[e]; d = ei[E + e]; } else { s = d = e - E; }
    int pos = atomicAdd(&cursor[d], 1);
    srcS[pos] = s;
}

// ------------- conv1 aggregate of RAW x (32-dim bf16, 64 B/row, 3.2 MB table) -------------
__global__ __launch_bounds__(256) void gat_agg_x32(
        const int* __restrict__ offsets, const int* __restrict__ srcS,
        const float4* __restrict__ a_s4, const float4* __restrict__ a_d4,
        const unsigned short* __restrict__ x16,    // [N,32]
        unsigned short* __restrict__ aggX,         // [N,128]
        int N) {
    __shared__ float4 wlds[4][64];
    __shared__ int slds[4][64];
    const int wid = threadIdx.x >> 6;
    const int n = blockIdx.x * 4 + wid;
    if (n >= N) return;
    const int lane = threadIdx.x & 63;
    const int q = lane >> 4;
    const int l16 = lane & 15;
    const int start = offsets[n], end = offsets[n + 1];
    const float4 ad = a_d4[n];
    float2 acc0 = {0,0}, acc1 = {0,0}, acc2 = {0,0}, acc3 = {0,0};
    float4 den = {0,0,0,0};
    const int loff = l16 << 1;     // 2 channels of 32

    for (int e0 = start; e0 < end; e0 += 64) {
        const int cnt = min(64, end - e0);
        if (lane < cnt) {
            int sB = srcS[e0 + lane];
            slds[wid][lane] = sB;
            const float4 as = a_s4[sB];
            float x0 = as.x + ad.x; x0 = fmaxf(x0, NEG_SLOPE * x0);
            float x1 = as.y + ad.y; x1 = fmaxf(x1, NEG_SLOPE * x1);
            float x2 = as.z + ad.z; x2 = fmaxf(x2, NEG_SLOPE * x2);
            float x3 = as.w + ad.w; x3 = fmaxf(x3, NEG_SLOPE * x3);
            wlds[wid][lane] = (float4){exp2f(x0), exp2f(x1), exp2f(x2), exp2f(x3)};
        }
        int j = q;
        for (; j + 12 < cnt; j += 16) {
            int ss[4]; float4 ww[4]; unsigned int gg[4];
            #pragma unroll
            for (int u = 0; u < 4; u++) {
                ss[u] = slds[wid][j + 4 * u];
                ww[u] = wlds[wid][j + 4 * u];
            }
            #pragma unroll
            for (int u = 0; u < 4; u++)
                gg[u] = *(const unsigned int*)&x16[((size_t)ss[u] << 5) + loff];
            #pragma unroll
            for (int u = 0; u < 4; u++) {
                const float vl = b2f_lo(gg[u]), vh = b2f_hi(gg[u]);
                acc0.x += ww[u].x * vl; acc0.y += ww[u].x * vh;
                acc1.x += ww[u].y * vl; acc1.y += ww[u].y * vh;
                acc2.x += ww[u].z * vl; acc2.y += ww[u].z * vh;
                acc3.x += ww[u].w * vl; acc3.y += ww[u].w * vh;
                den.x += ww[u].x; den.y += ww[u].y; den.z += ww[u].z; den.w += ww[u].w;
            }
        }
        for (; j + 4 < cnt; j += 8) {
            const int s0 = slds[wid][j], s1 = slds[wid][j + 4];
            const float4 w0 = wlds[wid][j], w1 = wlds[wid][j + 4];
            const unsigned int g0 = *(const unsigned int*)&x16[((size_t)s0 << 5) + loff];
            const unsigned int g1 = *(const unsigned int*)&x16[((size_t)s1 << 5) + loff];
            const float vl0 = b2f_lo(g0), vh0 = b2f_hi(g0);
            const float vl1 = b2f_lo(g1), vh1 = b2f_hi(g1);
            acc0.x += w0.x * vl0 + w1.x * vl1; acc0.y += w0.x * vh0 + w1.x * vh1;
            acc1.x += w0.y * vl0 + w1.y * vl1; acc1.y += w0.y * vh0 + w1.y * vh1;
            acc2.x += w0.z * vl0 + w1.z * vl1; acc2.y += w0.z * vh0 + w1.z * vh1;
            acc3.x += w0.w * vl0 + w1.w * vl1; acc3.y += w0.w * vh0 + w1.w * vh1;
            den.x += w0.x + w1.x; den.y += w0.y + w1.y;
            den.z += w0.z + w1.z; den.w += w0.w + w1.w;
        }
        for (; j < cnt; j += 4) {
            const int s = slds[wid][j];
            const float4 w = wlds[wid][j];
            const unsigned int g = *(const unsigned int*)&x16[((size_t)s << 5) + loff];
            const float vl = b2f_lo(g), vh = b2f_hi(g);
            acc0.x += w.x * vl; acc0.y += w.x * vh;
            acc1.x += w.y * vl; acc1.y += w.y * vh;
            acc2.x += w.z * vl; acc2.y += w.z * vh;
            acc3.x += w.w * vl; acc3.y += w.w * vh;
            den.x += w.x; den.y += w.y; den.z += w.z; den.w += w.w;
        }
    }
    #pragma unroll
    for (int off = 16; off < 64; off <<= 1) {
        acc0.x += __shfl_xor(acc0.x, off); acc0.y += __shfl_xor(acc0.y, off);
        acc1.x += __shfl_xor(acc1.x, off); acc1.y += __shfl_xor(acc1.y, off);
        acc2.x += __shfl_xor(acc2.x, off); acc2.y += __shfl_xor(acc2.y, off);
        acc3.x += __shfl_xor(acc3.x, off); acc3.y += __shfl_xor(acc3.y, off);
        den.x += __shfl_xor(den.x, off); den.y += __shfl_xor(den.y, off);
        den.z += __shfl_xor(den.z, off); den.w += __shfl_xor(den.w, off);
    }
    if (q == 0) {
        const float i0 = 1.0f / (den.x + 1e-16f);
        const float i1 = 1.0f / (den.y + 1e-16f);
        const float i2 = 1.0f / (den.z + 1e-16f);
        const float i3 = 1.0f / (den.w + 1e-16f);
        unsigned int o0 = (unsigned int)f2b(acc0.x * i0) | ((unsigned int)f2b(acc0.y * i0) << 16);
        unsigned int o1 = (unsigned int)f2b(acc1.x * i1) | ((unsigned int)f2b(acc1.y * i1) << 16);
        unsigned int o2 = (unsigned int)f2b(acc2.x * i2) | ((unsigned int)f2b(acc2.y * i2) << 16);
        unsigned int o3 = (unsigned int)f2b(acc3.x * i3) | ((unsigned int)f2b(acc3.y * i3) << 16);
        *(unsigned int*)&aggX[((size_t)n << 7) + 0 * 32 + loff] = o0;
        *(unsigned int*)&aggX[((size_t)n << 7) + 1 * 32 + loff] = o1;
        *(unsigned int*)&aggX[((size_t)n << 7) + 2 * 32 + loff] = o2;
        *(unsigned int*)&aggX[((size_t)n << 7) + 3 * 32 + loff] = o3;
    }
}

// ------------- conv2 aggregate over FP8 table (4B/lane gather) + bias + ELU + conv3 scores -------------
__global__ __launch_bounds__(256) void gat_fused4(
        const int* __restrict__ offsets, const int* __restrict__ srcS,
        const float4* __restrict__ a_s4, const float4* __restrict__ a_d4,
        const unsigned char* __restrict__ h8, const float* __restrict__ bias,
        const float* __restrict__ u3s, const float* __restrict__ u3d,
        float* __restrict__ a_s3, float* __restrict__ a_d3,
        unsigned short* __restrict__ out16, int N) {
    __shared__ float wlds[4][64][4];
    __shared__ int slds[4][64];
    const int wid = threadIdx.x >> 6;
    const int n = blockIdx.x * 4 + wid;
    if (n >= N) return;
    const int lane = threadIdx.x & 63;
    const int quad = lane >> 4;
    const int start = offsets[n], end = offsets[n + 1];
    const float4 ad = a_d4[n];
    float4 acc = {0, 0, 0, 0};
    float den = 0.0f;
    const int loff = lane << 2;                  // channel index == byte offset (fp8)

    for (int e0 = start; e0 < end; e0 += 64) {
        const int cnt = min(64, end - e0);
        if (lane < cnt) {
            int sB = srcS[e0 + lane];
            slds[wid][lane] = sB;
            const float4 as = a_s4[sB];
            float x0 = as.x + ad.x; x0 = fmaxf(x0, NEG_SLOPE * x0);
            float x1 = as.y + ad.y; x1 = fmaxf(x1, NEG_SLOPE * x1);
            float x2 = as.z + ad.z; x2 = fmaxf(x2, NEG_SLOPE * x2);
            float x3 = as.w + ad.w; x3 = fmaxf(x3, NEG_SLOPE * x3);
            wlds[wid][lane][0] = exp2f(x0);
            wlds[wid][lane][1] = exp2f(x1);
            wlds[wid][lane][2] = exp2f(x2);
            wlds[wid][lane][3] = exp2f(x3);
        }
        int j = 0;
        for (; j + 4 <= cnt; j += 4) {
            const int s0 = __builtin_amdgcn_readfirstlane(slds[wid][j + 0]);
            const int s1 = __builtin_amdgcn_readfirstlane(slds[wid][j + 1]);
            const int s2 = __builtin_amdgcn_readfirstlane(slds[wid][j + 2]);
            const int s3 = __builtin_amdgcn_readfirstlane(slds[wid][j + 3]);
            const float w0 = wlds[wid][j + 0][quad];
            const float w1 = wlds[wid][j + 1][quad];
            const float w2 = wlds[wid][j + 2][quad];
            const float w3 = wlds[wid][j + 3][quad];
            const unsigned int g0 = *(const unsigned int*)&h8[((size_t)s0 << 8) + loff];
            const unsigned int g1 = *(const unsigned int*)&h8[((size_t)s1 << 8) + loff];
            const unsigned int g2 = *(const unsigned int*)&h8[((size_t)s2 << 8) + loff];
            const unsigned int g3 = *(const unsigned int*)&h8[((size_t)s3 << 8) + loff];
            float v0, v1, v2, v3;
            fp8x4_to_f32(g0, v0, v1, v2, v3);
            acc.x += w0 * v0; acc.y += w0 * v1; acc.z += w0 * v2; acc.w += w0 * v3;
            fp8x4_to_f32(g1, v0, v1, v2, v3);
            acc.x += w1 * v0; acc.y += w1 * v1; acc.z += w1 * v2; acc.w += w1 * v3;
            fp8x4_to_f32(g2, v0, v1, v2, v3);
            acc.x += w2 * v0; acc.y += w2 * v1; acc.z += w2 * v2; acc.w += w2 * v3;
            fp8x4_to_f32(g3, v0, v1, v2, v3);
            acc.x += w3 * v0; acc.y += w3 * v1; acc.z += w3 * v2; acc.w += w3 * v3;
            den += (w0 + w1) + (w2 + w3);
        }
        for (; j < cnt; j++) {
            const int s = __builtin_amdgcn_readfirstlane(slds[wid][j]);
            const float w = wlds[wid][j][quad];
            const unsigned int g = *(const unsigned int*)&h8[((size_t)s << 8) + loff];
            float v0, v1, v2, v3;
            fp8x4_to_f32(g, v0, v1, v2, v3);
            acc.x += w * v0; acc.y += w * v1; acc.z += w * v2; acc.w += w * v3;
            den += w;
        }
    }

    const float inv = 1.0f / (den + 1e-16f);
    const float4 bb = *(const float4*)&bias[loff];
    float v0 = acc.x * inv + bb.x; v0 = (v0 > 0.0f) ? v0 : expm1f(v0);
    float v1 = acc.y * inv + bb.y; v1 = (v1 > 0.0f) ? v1 : expm1f(v1);
    float v2 = acc.z * inv + bb.z; v2 = (v2 > 0.0f) ? v2 : expm1f(v2);
    float v3 = acc.w * inv + bb.w; v3 = (v3 > 0.0f) ? v3 : expm1f(v3);
    // conv3 scores from the fp32 h3 row (each lane owns 4 channels)
    {
        const float4 us = *(const float4*)&u3s[loff];
        const float4 ud = *(const float4*)&u3d[loff];
        float ps = v0 * us.x + v1 * us.y + v2 * us.z + v3 * us.w;
        float pd = v0 * ud.x + v1 * ud.y + v2 * ud.z + v3 * ud.w;
        #pragma unroll
        for (int off = 1; off < 64; off <<= 1) {
            ps += __shfl_xor(ps, off);
            pd += __shfl_xor(pd, off);
        }
        if (lane == 0) {
            a_s3[n] = ps * LOG2E;
            a_d3[n] = pd * LOG2E;
        }
    }
    uint2 o;
    o.x = (unsigned int)f2b(v0) | ((unsigned int)f2b(v1) << 16);
    o.y = (unsigned int)f2b(v2) | ((unsigned int)f2b(v3) << 16);
    *(uint2*)&out16[(size_t)n * 256 + loff] = o;
}

// ------------- H=1 fused (conv3): wave/node gather + PARTITIONED fused mean-pool -------------
__global__ __launch_bounds__(256) void gat_fused1(
        const int* __restrict__ offsets, const int* __restrict__ srcS,
        const float* __restrict__ a_s, const float* __restrict__ a_d,
        const unsigned short* __restrict__ hW16, const float* __restrict__ bias,
        const int* __restrict__ batch,
        float* __restrict__ pooledP, float* __restrict__ cntP, int N, int G) {
    __shared__ float wlds[4][64];
    __shared__ int slds[4][64];
    __shared__ float2 sOut[4][32];
    __shared__ int sG[4];
    const int wid = threadIdx.x >> 6;
    const int n = blockIdx.x * 4 + wid;
    const bool valid = n < N;                  // no early return: all waves reach the barrier
    const int lane = threadIdx.x & 63;
    const int half = lane >> 5;
    const int l32 = lane & 31;
    const int start = valid ? offsets[n] : 0;
    const int end   = valid ? offsets[n + 1] : 0;
    const float ad  = valid ? a_d[n] : 0.0f;
    float accx = 0.0f, accy = 0.0f, den = 0.0f;
    const int loff = l32 << 1;

    for (int e0 = start; e0 < end; e0 += 64) {
        const int cnt_ = min(64, end - e0);
        if (lane < cnt_) {
            int sB = srcS[e0 + lane];
            slds[wid][lane] = sB;
            float ev = a_s[sB] + ad;
            ev = fmaxf(ev, NEG_SLOPE * ev);
            wlds[wid][lane] = exp2f(ev);
        }
        int j = half;
        for (; j + 8 <= cnt_ + half; j += 8) {
            const int s0 = slds[wid][j + 0];
            const int s1 = slds[wid][j + 2];
            const int s2 = slds[wid][j + 4];
            const int s3 = slds[wid][j + 6];
            const float w0 = wlds[wid][j + 0];
            const float w1 = wlds[wid][j + 2];
            const float w2 = wlds[wid][j + 4];
            const float w3 = wlds[wid][j + 6];
            const unsigned int h0 = *(const unsigned int*)&hW16[((size_t)s0 << 6) + loff];
            const unsigned int h1 = *(const unsigned int*)&hW16[((size_t)s1 << 6) + loff];
            const unsigned int h2 = *(const unsigned int*)&hW16[((size_t)s2 << 6) + loff];
            const unsigned int h3 = *(const unsigned int*)&hW16[((size_t)s3 << 6) + loff];
            accx += w0 * b2f_lo(h0); accy += w0 * b2f_hi(h0);
            accx += w1 * b2f_lo(h1); accy += w1 * b2f_hi(h1);
            accx += w2 * b2f_lo(h2); accy += w2 * b2f_hi(h2);
            accx += w3 * b2f_lo(h3); accy += w3 * b2f_hi(h3);
            den += (w0 + w1) + (w2 + w3);
        }
        for (; j < cnt_; j += 2) {
            const int s = slds[wid][j];
            const float w = wlds[wid][j];
            const unsigned int hv = *(const unsigned int*)&hW16[((size_t)s << 6) + loff];
            accx += w * b2f_lo(hv);
            accy += w * b2f_hi(hv);
            den += w;
        }
    }
    accx += __shfl_xor(accx, 32);
    accy += __shfl_xor(accy, 32);
    den  += __shfl_xor(den, 32);
    if (half == 0) {
        if (valid) {
            const float inv = 1.0f / (den + 1e-16f);
            sOut[wid][l32] = (float2){accx * inv + bias[loff], accy * inv + bias[loff + 1]};
        } else {
            sOut[wid][l32] = (float2){0.0f, 0.0f};
        }
        if (l32 == 0) sG[wid] = valid ? batch[n] : -1;
    }
    __syncthreads();
    const int p = blockIdx.x & 63;
    if (wid == 0 && half == 0) {
        const int g0 = sG[0], g1 = sG[1], g2 = sG[2], g3 = sG[3];
        if (g0 >= 0 && g1 == g0 && g2 == g0 && g3 == g0) {
            const float2 s0 = sOut[0][l32], s1 = sOut[1][l32];
            const float2 s2 = sOut[2][l32], s3 = sOut[3][l32];
            float* base = pooledP + ((size_t)p * G + g0) * 64;
            atomicAdd(&base[loff],     (s0.x + s1.x) + (s2.x + s3.x));
            atomicAdd(&base[loff + 1], (s0.y + s1.y) + (s2.y + s3.y));
            if (l32 == 0) atomicAdd(&cntP[p * G + g0], 4.0f);
        } else {
            #pragma unroll
            for (int w = 0; w < 4; w++) {
                const int g = sG[w];
                if (g >= 0) {
                    const float2 s = sOut[w][l32];
                    float* base = pooledP + ((size_t)p * G + g) * 64;
                    atomicAdd(&base[loff], s.x);
                    atomicAdd(&base[loff + 1], s.y);
                    if (l32 == 0) atomicAdd(&cntP[p * G + g], 1.0f);
                }
            }
        }
    }
}

// ------------- decoder head: one block per graph (reduces 64 pool partitions first) -------------
__global__ __launch_bounds__(256) void final_kernel(
        const float* __restrict__ pooledP, const float* __restrict__ cntP,
        const float* __restrict__ gf, const float* __restrict__ Wg,
        const float* __restrict__ bg, const float* __restrict__ Wd1,
        const float* __restrict__ bd1, const float* __restrict__ gamma,
        const float* __restrict__ beta, const float* __restrict__ Wd2,
        const float* __restrict__ bd2, float* __restrict__ out, int G) {
    const int g = blockIdx.x;
    const int tid = threadIdx.x;
    const int lane = tid & 63;
    const int wave = tid >> 6;
    __shared__ float sPart[4][64];
    __shared__ float sCntTot;
    __shared__ float spg[128];
    __shared__ float sz[64];
    __shared__ float wred[8];

    {   // partition reduce: wave pg sums partitions [pg*16, pg*16+16)
        const int c = lane;
        const int pg = wave;
        float a = 0.0f;
        #pragma unroll
        for (int p = 0; p < 16; p++)
            a += pooledP[((size_t)(pg * 16 + p) * G + g) * 64 + c];
        sPart[pg][c] = a;
        if (pg == 1) {
            float cv = cntP[c * G + g];
            #pragma unroll
            for (int off = 32; off > 0; off >>= 1) cv += __shfl_xor(cv, off);
            if (c == 0) sCntTot = cv;
        }
    }
    __syncthreads();
    if (tid < 64) {
        spg[tid] = (sPart[0][tid] + sPart[1][tid] + sPart[2][tid] + sPart[3][tid])
                   / fmaxf(sCntTot, 1.0f);
    } else if (tid < 128) {
        int c = tid - 64;
        float v = bg[c];
        #pragma unroll
        for (int k = 0; k < 4; k++) v += gf[g * 4 + k] * Wg[k * 64 + c];
        spg[64 + c] = fmaxf(v, 0.0f);
    }
    __syncthreads();
    if (tid < 64) {
        float v = bd1[tid];
        #pragma unroll 8
        for (int k = 0; k < 128; k++) v += spg[k] * Wd1[k * 64 + tid];
        v = v * gamma[tid] + beta[tid];
        sz[tid] = fmaxf(v, 0.0f);
    }
    __syncthreads();
    float v = bd2[tid];
    #pragma unroll 8
    for (int k = 0; k < 64; k++) v += sz[k] * Wd2[k * 256 + tid];
    float m = v;
    #pragma unroll
    for (int off = 32; off > 0; off >>= 1) m = fmaxf(m, __shfl_xor(m, off));
    if (lane == 0) wred[wave] = m;
    __syncthreads();
    float M = fmaxf(fmaxf(wred[0], wred[1]), fmaxf(wred[2], wred[3]));
    float e = expf(v - M);
    float s = e;
    #pragma unroll
    for (int off = 32; off > 0; off >>= 1) s += __shfl_xor(s, off);
    if (lane == 0) wred[4 + wave] = s;
    __syncthreads();
    float S = (wred[4] + wred[5]) + (wred[6] + wred[7]);
    out[g * 256 + tid] = e / S;
}

extern "C" void kernel_launch(void* const* d_in, const int* in_sizes, int n_in,
                              void* d_out, int out_size, void* d_ws, size_t ws_size,
                              hipStream_t stream) {
    const float* x     = (const float*)d_in[0];
    const int*   ei    = (const int*)  d_in[1];
    const int*   batch = (const int*)  d_in[2];
    const float* gf    = (const float*)d_in[3];
    const float* W_enc = (const float*)d_in[4];
    const float* b_enc = (const float*)d_in[5];
    const float* W1  = (const float*)d_in[6];
    const float* as1 = (const float*)d_in[7];
    const float* ad1 = (const float*)d_in[8];
    const float* b1  = (const float*)d_in[9];
    const float* W2  = (const float*)d_in[10];
    const float* as2 = (const float*)d_in[11];
    const float* ad2 = (const float*)d_in[12];
    const float* b2  = (const float*)d_in[13];
    const float* W3  = (const float*)d_in[14];
    const float* as3 = (const float*)d_in[15];
    const float* ad3 = (const float*)d_in[16];
    const float* b3  = (const float*)d_in[17];
    const float* Wg  = (const float*)d_in[18];
    const float* bg  = (const float*)d_in[19];
    const float* Wd1 = (const float*)d_in[20];
    const float* bd1 = (const float*)d_in[21];
    const float* gm  = (const float*)d_in[22];
    const float* bt  = (const float*)d_in[23];
    const float* Wd2 = (const float*)d_in[24];
    const float* bd2 = (const float*)d_in[25];

    const int N  = in_sizes[2];
    const int E  = in_sizes[1] / 2;
    const int G  = in_sizes[3] / 4;
    const int Et = E + N;

    unsigned short* h16a = (unsigned short*)d_ws;                // slot reused: conv2 fp8 table [N,256]B
    unsigned short* h16b = h16a + (size_t)N * 256;               // [N,256]: aggX[N,128] early, then conv2 agg out
    unsigned short* h1_16 = h16b + (size_t)N * 256;              // [N,64] conv3 gather table
    unsigned short* x16  = h1_16 + (size_t)N * 64;               // [N,32] bf16
    unsigned short* Wc1t = x16 + (size_t)N * 32;                 // [4][64][32]
    unsigned short* Wt2  = Wc1t + 4 * 64 * 32;                   // [256,256]
    unsigned short* Wt3  = Wt2 + 256 * 256;                      // [64,256]
    float* bc1    = (float*)(Wt3 + 64 * 256);                    // [256]
    float* a_s    = bc1 + 256;                                   // [N,4]
    float* a_d    = a_s + (size_t)N * 4;                         // [N,4]
    float* a_s3   = a_d + (size_t)N * 4;                         // [N]
    float* a_d3   = a_s3 + N;                                    // [N]
    float* u1s    = a_d3 + N;                                    // [64,4]
    float* u1d    = u1s + 256;                                   // [64,4]
    float* u3s    = u1d + 256;                                   // [256]
    float* u3d    = u3s + 256;                                   // [256]
    float* pooledP = u3d + 256;                                  // [64][G][64]
    float* cntP   = pooledP + (size_t)64 * G * 64;               // [64][G]
    int*   offsets = (int*)(cntP + 64 * G);                      // [N+1]
    int*   srcS    = offsets + (N + 1);                          // [Et]
    int*   counts  = srcS + Et;                                  // [N]
    int*   cursor  = counts + N;                                 // [N]
    int*   blockSums = cursor + N;                               // [cdiv(N,1024)]

    unsigned char* h8a = (unsigned char*)h16a;                   // fp8 conv2 gather table view

    dim3 blk(256);
    auto cdiv = [](int a, int b) { return (a + b - 1) / b; };
    const int eBlocks = cdiv(Et, 256);
    const int rowBlocks = cdiv(N, 64);
    const int nScanBlocks = cdiv(N, 1024);
    const int zc = cdiv(N, 256);
    const int z2 = cdiv(64 * G * 64, 256);

    // ---------------- prep (folded weights + u-vectors + zero-init) + CSR build ----------------
    prep_kernel<<<355 + zc + z2, blk, 0, stream>>>(W_enc, b_enc, W1, W2, W3, as1, ad1, b1,
                                                   as3, ad3, Wc1t, bc1, Wt2, Wt3,
                                                   u1s, u1d, u3s, u3d,
                                                   counts, pooledP, cntP, N, G, zc);
    edge_hist_kernel<<<eBlocks, blk, 0, stream>>>(ei, counts, E, Et);
    scan_blocks<<<nScanBlocks, 1024, 0, stream>>>(counts, blockSums, N);
    scan_add2<<<cdiv(N + 1, 256), blk, 0, stream>>>(counts, blockSums, nScanBlocks,
                                                    offsets, cursor, N, Et);
    edge_sort_kernel<<<eBlocks, blk, 0, stream>>>(ei, cursor, srcS, E, Et);

    // conv1 scores from raw x + x->bf16
    score_x<<<cdiv(N, 32), blk, 0, stream>>>(x, W_enc, b_enc, u1s, u1d, x16, a_s, a_d, N);

    // ---------------- conv1 aggregate (raw x) -> fused conv1+conv2 GEMM (fp8 table out) ----------------
    gat_agg_x32<<<cdiv(N, 4), blk, 0, stream>>>(offsets, srcS, (const float4*)a_s,
                                                (const float4*)a_d, x16, h16b, N);
    gemm_c12<<<rowBlocks, blk, 0, stream>>>(h16b, Wc1t, bc1, Wt2, as2, ad2,
                                            a_s, a_d, h8a, N);

    // ---------------- conv2 aggregate over fp8 table (+conv3 scores fused) ----------------
    gat_fused4<<<cdiv(N, 4), blk, 0, stream>>>(offsets, srcS, (const float4*)a_s,
                                               (const float4*)a_d, h8a, b2,
                                               u3s, u3d, a_s3, a_d3, h16b, N);

    // ---------------- conv3: GEMM (no scores) -> aggregate + partitioned pool ----------------
    gemm_mfma<1, 0><<<dim3(rowBlocks, 1), blk, 0, stream>>>(h16b, Wt3, h1_16,
                                                            nullptr, nullptr, nullptr, nullptr,
                                                            N, 256, 64, 1);
    gat_fused1<<<cdiv(N, 4), blk, 0, stream>>>(offsets, srcS, a_s3, a_d3, h1_16, b3,
                                               batch, pooledP, cntP, N, G);

    // ---------------- decoder head ----------------
    final_kernel<<<G, blk, 0, stream>>>(pooledP, cntP, gf, Wg, bg, Wd1, bd1, gm, bt, Wd2, bd2,
                                        (float*)d_out, G);
}

// Round 9
// 378.829 us; speedup vs baseline: 1.2189x; 1.0148x over previous
//
#include <hip/hip_runtime.h>
#include <math.h>

#define NEG_SLOPE 0.2f
#define LOG2E 1.4426950408889634f

typedef __attribute__((ext_vector_type(8))) short short8;   // 8 bf16 = 4 VGPRs
typedef __attribute__((ext_vector_type(4))) float f32x4;    // MFMA acc
typedef __attribute__((ext_vector_type(2))) float f32x2;

#if __has_builtin(__builtin_amdgcn_cvt_pk_f32_fp8) && __has_builtin(__builtin_amdgcn_cvt_pk_fp8_f32)
#define FP8_HW 1
#else
#define FP8_HW 0
#endif

__device__ inline float b2f_lo(unsigned int u) {
    union { unsigned int i; float f; } x; x.i = u << 16; return x.f;
}
__device__ inline float b2f_hi(unsigned int u) {
    union { unsigned int i; float f; } x; x.i = u & 0xFFFF0000u; return x.f;
}
__device__ inline unsigned short f2b(float f) {
    union { float f; unsigned int i; } u; u.f = f;
    unsigned int r = u.i + 0x7FFF + ((u.i >> 16) & 1);   // round-to-nearest-even
    return (unsigned short)(r >> 16);
}

// ---- OCP e4m3 helpers (HW cvt on gfx950; exact manual fallback) ----
__device__ inline float fp8_decode1(unsigned int b) {
    unsigned int e = (b >> 3) & 15, m = b & 7;
    union { unsigned int i; float f; } u;
    if (e == 0) u.f = (float)m * 0.001953125f;          // subnormal: m * 2^-9
    else u.i = ((e + 120) << 23) | (m << 20);            // (1+m/8) * 2^(e-7)
    if (b & 0x80) u.f = -u.f;
    return u.f;
}
__device__ inline void fp8x4_to_f32(unsigned int g, float& v0, float& v1,
                                    float& v2, float& v3) {
#if FP8_HW
    f32x2 lo = __builtin_amdgcn_cvt_pk_f32_fp8((int)g, false);   // bytes 0,1
    f32x2 hi = __builtin_amdgcn_cvt_pk_f32_fp8((int)g, true);    // bytes 2,3
    v0 = lo[0]; v1 = lo[1]; v2 = hi[0]; v3 = hi[1];
#else
    v0 = fp8_decode1(g & 255);         v1 = fp8_decode1((g >> 8) & 255);
    v2 = fp8_decode1((g >> 16) & 255); v3 = fp8_decode1((g >> 24) & 255);
#endif
}
__device__ inline void fp8x2_to_f32(unsigned int g2, float& v0, float& v1) {
#if FP8_HW
    f32x2 lo = __builtin_amdgcn_cvt_pk_f32_fp8((int)(g2 & 0xFFFF), false);
    v0 = lo[0]; v1 = lo[1];
#else
    v0 = fp8_decode1(g2 & 255);
    v1 = fp8_decode1((g2 >> 8) & 255);
#endif
}
__device__ inline unsigned char f32_to_fp8(float f) {
#if FP8_HW
    return (unsigned char)(__builtin_amdgcn_cvt_pk_fp8_f32(f, f, 0, false) & 0xFF);
#else
    union { float f; unsigned int i; } u; u.f = f;
    unsigned int s = (u.i >> 24) & 0x80;
    float a = fabsf(f);
    if (a < 0.015625f) {                                 // subnormal band
        int m = (int)rintf(a * 512.0f);
        if (m > 7) return (unsigned char)(s | 0x08);
        return (unsigned char)(s | m);
    }
    if (a >= 448.0f) return (unsigned char)(s | 0x7E);
    int e = (int)((u.i >> 23) & 0xFF) - 127;
    union { unsigned int i; float f; } sc; sc.i = (unsigned int)(127 + 3 - e) << 23;
    int q = (int)rintf(a * sc.f);                        // in [8,16]
    if (q >= 16) { q = 8; e += 1; }
    return (unsigned char)(s | ((unsigned int)(e + 7) << 3) | (unsigned int)(q - 8));
#endif
}

// ---------------- prep: folded conv1 weights (Wc1 = W_enc@W1, bc1), u1/u3 vectors,
// Wt2/Wt3 transposes, and ALL zero-init ----------------
__global__ void prep_kernel(const float* __restrict__ W_enc, const float* __restrict__ b_enc,
                            const float* __restrict__ W1, const float* __restrict__ W2,
                            const float* __restrict__ W3, const float* __restrict__ as1,
                            const float* __restrict__ ad1, const float* __restrict__ b1,
                            const float* __restrict__ as3, const float* __restrict__ ad3,
                            unsigned short* __restrict__ Wc1t, float* __restrict__ bc1,
                            unsigned short* __restrict__ Wt2, unsigned short* __restrict__ Wt3,
                            float* __restrict__ u1s, float* __restrict__ u1d,
                            float* __restrict__ u3s, float* __restrict__ u3d,
                            int* __restrict__ counts, float* __restrict__ pooledP,
                            float* __restrict__ cntP, int N, int G, int zc) {
    const int b = blockIdx.x;
    const int t = threadIdx.x;
    if (b < 32) {
        // Wc1t[h][o][j] = sum_k W_enc[j][k] * W1[k][h*64+o]   (bf16, B^T layout)
        int i = b * 256 + t;                       // 8192 values
        int h = i >> 11, rem = i & 2047, o = rem >> 5, j = rem & 31;
        float s = 0.0f;
        for (int k = 0; k < 64; k++)
            s += W_enc[j * 64 + k] * W1[k * 256 + h * 64 + o];
        Wc1t[i] = f2b(s);
    } else if (b == 32) {
        // bc1[c] = b1[c] + sum_k b_enc[k] * W1[k][c]   (uses sum(alpha)=1)
        float s = b1[t];
        for (int k = 0; k < 64; k++) s += b_enc[k] * W1[k * 256 + t];
        bc1[t] = s;
    } else if (b == 33) {
        // u1 score projections in h1-space (consumed by score_x)
        int k = t >> 2, h = t & 3;
        float s = 0.0f, d = 0.0f;
        for (int c = 0; c < 64; c++) {
            float w = W1[k * 256 + h * 64 + c];
            s += w * as1[h * 64 + c];
            d += w * ad1[h * 64 + c];
        }
        u1s[k * 4 + h] = s;
        u1d[k * 4 + h] = d;
    } else if (b == 34) {
        // u3 = W3 @ as3 (conv3 scores computed from h3 directly: a3 = h3 . u3)
        float s = 0.0f, d = 0.0f;
        for (int o = 0; o < 64; o++) {
            float w = W3[t * 64 + o];
            s += w * as3[o];
            d += w * ad3[o];
        }
        u3s[t] = s; u3d[t] = d;
    } else if (b < 35 + 256) {
        int i = (b - 35) * 256 + t;                // K=256, M=256
        int k = i >> 8, m = i & 255;
        Wt2[(size_t)m * 256 + k] = f2b(W2[i]);
    } else if (b < 35 + 256 + 64) {
        int i = (b - 291) * 256 + t;               // K=256, M=64
        int k = i >> 6, m = i & 63;
        Wt3[(size_t)m * 256 + k] = f2b(W3[i]);
    } else if (b < 355 + zc) {
        int i = (b - 355) * 256 + t;
        if (i < N) counts[i] = 0;
    } else {
        int i = (b - 355 - zc) * 256 + t;
        if (i < 64 * G * 64) pooledP[i] = 0.0f;    // [64 partitions][G][64]
        if (i < 64 * G) cntP[i] = 0.0f;            // [64 partitions][G]
    }
}

// ---------------- score_x: conv1 scores directly from fp32 x (a = x*(W_enc@u1) + b_enc@u1),
// plus x -> fp8 conversion for the conv1 gather table. ----------------
__global__ __launch_bounds__(256) void score_x(
        const float* __restrict__ x, const float* __restrict__ W_enc,
        const float* __restrict__ b_enc,
        const float* __restrict__ u1s, const float* __restrict__ u1d,
        unsigned char* __restrict__ x8, float* __restrict__ a_s,
        float* __restrict__ a_d, int N) {
    __shared__ float sUs[32][4], sUd[32][4], sC[8];
    __shared__ float sX[32][33];
    const int t = threadIdx.x;
    if (t < 128) {
        int j = t >> 2, h = t & 3;
        float s = 0.0f, d = 0.0f;
        for (int k = 0; k < 64; k++) {
            float w = W_enc[j * 64 + k];
            s += w * u1s[k * 4 + h];
            d += w * u1d[k * 4 + h];
        }
        sUs[j][h] = s; sUd[j][h] = d;
    } else if (t < 136) {
        int hh = t - 128;                           // 0..3 -> s, 4..7 -> d
        const float* u = (hh < 4) ? u1s : u1d;
        int h = hh & 3;
        float c = 0.0f;
        for (int k = 0; k < 64; k++) c += b_enc[k] * u[k * 4 + h];
        sC[hh] = c;
    }
    const int n0 = blockIdx.x * 32;
    const int row = t >> 3, col = (t & 7) << 2;
    float4 xv = {0, 0, 0, 0};
    if (n0 + row < N) xv = *(const float4*)&x[(size_t)(n0 + row) * 32 + col];
    sX[row][col + 0] = xv.x; sX[row][col + 1] = xv.y;
    sX[row][col + 2] = xv.z; sX[row][col + 3] = xv.w;
    __syncthreads();
    const int ni = t >> 3, oi = t & 7, h = oi & 3;
    const bool isS = oi < 4;
    float acc = sC[oi];
    #pragma unroll 8
    for (int j = 0; j < 32; j++) acc += sX[ni][j] * (isS ? sUs[j][h] : sUd[j][h]);
    if (n0 + ni < N) {
        float* out = isS ? a_s : a_d;
        out[(size_t)(n0 + ni) * 4 + h] = acc * LOG2E;
    }
    if (n0 + row < N) {
        unsigned int o = (unsigned int)f32_to_fp8(xv.x)
                       | ((unsigned int)f32_to_fp8(xv.y) << 8)
                       | ((unsigned int)f32_to_fp8(xv.z) << 16)
                       | ((unsigned int)f32_to_fp8(xv.w) << 24);
        *(unsigned int*)&x8[(size_t)(n0 + row) * 32 + col] = o;
    }
}

// ---------------- FUSED conv1-GEMM + conv2-GEMM. h2 never hits HBM in bf16: the conv2
// gather table is written as fp8-e4m3 (halves gat_fused4's fetch). Scores fp32. ----------------
__global__ __launch_bounds__(256) void gemm_c12(
        const unsigned short* __restrict__ aggX,   // [N,128]
        const unsigned short* __restrict__ Wc1t,   // [(h*64+o)*32 + j]
        const float* __restrict__ bc1,             // [256]
        const unsigned short* __restrict__ Wt2,    // [256][256] B^T
        const float* __restrict__ att_s,           // as2 [256]
        const float* __restrict__ att_d,
        float* __restrict__ a_s, float* __restrict__ a_d,   // [N,4] conv2 scores
        unsigned char* __restrict__ C8,            // [N,256] fp8 conv2 gather table
        int Nrows) {
    __shared__ unsigned short sH[64][264];   // h2 tile (row stride 528B)
    __shared__ unsigned short sB[256][40];
    __shared__ float sSD[64][4][2];
    const int tid = threadIdx.x;
    const int wave = tid >> 6;
    const int lane = tid & 63;
    const int quad = lane >> 4;
    const int l16 = lane & 15;
    const int row0 = blockIdx.x * 64;
    const int sr = tid >> 2;
    const int sk = (tid & 3) << 3;

    // ---- phase 1: conv1 (folded, K=32) per head -> sH ----
    #pragma unroll
    for (int h = 0; h < 4; h++) {
        __syncthreads();
        {
            int r = row0 + sr;
            uint4 z = {0,0,0,0};
            *(uint4*)&sB[sr][sk] = (r < Nrows)
                ? *(const uint4*)&aggX[(size_t)r * 128 + h * 32 + sk] : z;
            *(uint4*)&sB[64 + sr][sk] = *(const uint4*)&Wc1t[(size_t)(h * 64 + sr) * 32 + sk];
        }
        __syncthreads();
        short8 bf = *(const short8*)&sB[64 + wave * 16 + l16][quad * 8];
        const int col = h * 64 + wave * 16 + l16;
        const float bb = bc1[col];
        #pragma unroll
        for (int i = 0; i < 4; i++) {
            short8 af = *(const short8*)&sB[i * 16 + l16][quad * 8];
            f32x4 acc = __builtin_amdgcn_mfma_f32_16x16x32_bf16(af, bf, (f32x4){0,0,0,0}, 0, 0, 0);
            #pragma unroll
            for (int r = 0; r < 4; r++) {
                float v = acc[r] + bb;
                v = (v > 0.0f) ? v : expm1f(v);        // ELU
                sH[i * 16 + quad * 4 + r][col] = f2b(v);
            }
        }
    }

    // ---- phase 2: conv2 GEMM, A from sH, BN=256 ----
    f32x4 acc2[4][4];
    #pragma unroll
    for (int i = 0; i < 4; i++)
        #pragma unroll
        for (int j = 0; j < 4; j++) acc2[i][j] = (f32x4){0,0,0,0};

    for (int kt = 0; kt < 256; kt += 32) {
        __syncthreads();
        #pragma unroll
        for (int i = 0; i < 4; i++) {
            int c = sr + i * 64;
            *(uint4*)&sB[c][sk] = *(const uint4*)&Wt2[(size_t)c * 256 + kt + sk];
        }
        __syncthreads();
        short8 bf2[4];
        #pragma unroll
        for (int j = 0; j < 4; j++)
            bf2[j] = *(const short8*)&sB[wave * 64 + j * 16 + l16][quad * 8];
        #pragma unroll
        for (int i = 0; i < 4; i++) {
            short8 af = *(const short8*)&sH[i * 16 + l16][kt + quad * 8];
            #pragma unroll
            for (int j = 0; j < 4; j++)
                acc2[i][j] = __builtin_amdgcn_mfma_f32_16x16x32_bf16(af, bf2[j], acc2[i][j], 0, 0, 0);
        }
    }

    // ---- conv2 scores (fp32, before fp8 encode) ----
    {
        for (int t = tid; t < 512; t += 256) ((float*)sSD)[t] = 0.0f;
        __syncthreads();
        float avs[4], avd[4];
        #pragma unroll
        for (int j = 0; j < 4; j++) {
            int c = wave * 64 + j * 16 + l16;
            avs[j] = att_s[c];
            avd[j] = att_d[c];
        }
        #pragma unroll
        for (int i = 0; i < 4; i++) {
            float ps[4] = {0,0,0,0}, pd[4] = {0,0,0,0};
            #pragma unroll
            for (int j = 0; j < 4; j++)
                #pragma unroll
                for (int r = 0; r < 4; r++) {
                    ps[r] += acc2[i][j][r] * avs[j];
                    pd[r] += acc2[i][j][r] * avd[j];
                }
            #pragma unroll
            for (int off = 1; off < 16; off <<= 1)
                #pragma unroll
                for (int r = 0; r < 4; r++) {
                    ps[r] += __shfl_xor(ps[r], off);
                    pd[r] += __shfl_xor(pd[r], off);
                }
            if (l16 == 0) {
                #pragma unroll
                for (int r = 0; r < 4; r++) {
                    atomicAdd(&sSD[i * 16 + quad * 4 + r][wave][0], ps[r]);
                    atomicAdd(&sSD[i * 16 + quad * 4 + r][wave][1], pd[r]);
                }
            }
        }
        __syncthreads();
        {
            int row = tid & 63, hb = tid >> 6;
            int r = row0 + row;
            if (r < Nrows) {
                a_s[r * 4 + hb] = sSD[row][hb][0] * LOG2E;
                a_d[r * 4 + hb] = sSD[row][hb][1] * LOG2E;
            }
        }
    }
    // ---- C write (fp8 e4m3) ----
    #pragma unroll
    for (int i = 0; i < 4; i++) {
        #pragma unroll
        for (int j = 0; j < 4; j++) {
            int col = wave * 64 + j * 16 + l16;
            #pragma unroll
            for (int r = 0; r < 4; r++) {
                int row = row0 + i * 16 + quad * 4 + r;
                if (row < Nrows) C8[(size_t)row * 256 + col] = f32_to_fp8(acc2[i][j][r]);
            }
        }
    }
}

// ---------------- conv3 GEMM: C8[N,64] fp8 = bf16 A[N,256] @ Wt3^T (no scores) ----------------
__global__ __launch_bounds__(256) void gemm_c3(const unsigned short* __restrict__ A16,
                                               const unsigned short* __restrict__ Bt16,
                                               unsigned char* __restrict__ C8,
                                               int Nrows) {
    __shared__ unsigned short sA[64][40];
    __shared__ unsigned short sB[64][40];
    const int tid = threadIdx.x;
    const int wave = tid >> 6;
    const int lane = tid & 63;
    const int quad = lane >> 4;
    const int l16 = lane & 15;
    const int row0 = blockIdx.x * 64;
    const int sr = tid >> 2;
    const int sk = (tid & 3) << 3;

    f32x4 acc[4];
    #pragma unroll
    for (int i = 0; i < 4; i++) acc[i] = (f32x4){0,0,0,0};

    for (int kt = 0; kt < 256; kt += 32) {
        __syncthreads();
        {
            int r = row0 + sr;
            uint4 z = {0,0,0,0};
            *(uint4*)&sA[sr][sk] = (r < Nrows) ? *(const uint4*)&A16[(size_t)r * 256 + kt + sk] : z;
            *(uint4*)&sB[sr][sk] = *(const uint4*)&Bt16[(size_t)sr * 256 + kt + sk];
        }
        __syncthreads();
        short8 bf = *(const short8*)&sB[wave * 16 + l16][quad * 8];
        #pragma unroll
        for (int i = 0; i < 4; i++) {
            short8 af = *(const short8*)&sA[i * 16 + l16][quad * 8];
            acc[i] = __builtin_amdgcn_mfma_f32_16x16x32_bf16(af, bf, acc[i], 0, 0, 0);
        }
    }
    const int col = wave * 16 + l16;
    #pragma unroll
    for (int i = 0; i < 4; i++) {
        #pragma unroll
        for (int r = 0; r < 4; r++) {
            int row = row0 + i * 16 + quad * 4 + r;
            if (row < Nrows) C8[(size_t)row * 64 + col] = f32_to_fp8(acc[i][r]);
        }
    }
}

// ------------- CSR build -------------
__global__ void edge_hist_kernel(const int* __restrict__ ei, int* __restrict__ counts,
                                 int E, int Et) {
    int e = blockIdx.x * 256 + threadIdx.x;
    if (e >= Et) return;
    int d = (e < E) ? ei[E + e] : e - E;
    atomicAdd(&counts[d], 1);
}

__global__ __launch_bounds__(1024) void scan_blocks(int* __restrict__ counts,
                                                    int* __restrict__ blockSums, int N) {
    __shared__ int wsum[16];
    const int tid = threadIdx.x;
    const int lane = tid & 63;
    const int wave = tid >> 6;
    int i = blockIdx.x * 1024 + tid;
    int v = (i < N) ? counts[i] : 0;
    int s = v;
    #pragma unroll
    for (int off = 1; off < 64; off <<= 1) {
        int t = __shfl_up(s, off);
        if (lane >= off) s += t;
    }
    if (lane == 63) wsum[wave] = s;
    __syncthreads();
    if (wave == 0 && lane < 16) {
        int ws = wsum[lane];
        #pragma unroll
        for (int off = 1; off < 16; off <<= 1) {
            int t = __shfl_up(ws, off);
            if (lane >= off) ws += t;
        }
        wsum[lane] = ws;
    }
    __syncthreads();
    int waveOff = (wave > 0) ? wsum[wave - 1] : 0;
    int incl = s + waveOff;
    if (i < N) counts[i] = incl - v;
    if (tid == 1023) blockSums[blockIdx.x] = incl;
}

__global__ void scan_add2(const int* __restrict__ excl, const int* __restrict__ blockSums,
                          int nb, int* __restrict__ offsets, int* __restrict__ cursor,
                          int N, int Et) {
    __shared__ int sbs[64];
    if (threadIdx.x < 64) {
        int lane = threadIdx.x;
        int v = (lane < nb) ? blockSums[lane] : 0;
        int s = v;
        #pragma unroll
        for (int off = 1; off < 64; off <<= 1) {
            int t = __shfl_up(s, off);
            if (lane >= off) s += t;
        }
        sbs[lane] = s - v;                 // exclusive
    }
    __syncthreads();
    int i = blockIdx.x * 256 + threadIdx.x;
    if (i < N) {
        int o = excl[i] + sbs[i >> 10];
        offsets[i] = o;
        cursor[i] = o;
    }
    if (i == N) offsets[N] = Et;
}

__global__ void edge_sort_kernel(const int* __restrict__ ei, int* __restrict__ cursor,
                                 int* __restrict__ srcS, int E, int Et) {
    int e = blockIdx.x * 256 + threadIdx.x;
    if (e >= Et) return;
    int s, d;
    if (e < E) { s = ei[e]; d = ei[E + e]; } else { s = d = e - E; }
    int pos = atomicAdd(&cursor[d], 1);
    srcS[pos] = s;
}

// ------------- conv1 aggregate of RAW x (32-dim fp8, 32 B/row, 1.6 MB table) -------------
__global__ __launch_bounds__(256) void gat_agg_x32(
        const int* __restrict__ offsets, const int* __restrict__ srcS,
        const float4* __restrict__ a_s4, const float4* __restrict__ a_d4,
        const unsigned char* __restrict__ x8,      // [N,32] fp8
        unsigned short* __restrict__ aggX,         // [N,128]
        int N) {
    __shared__ float4 wlds[4][64];
    __shared__ int slds[4][64];
    const int wid = threadIdx.x >> 6;
    const int n = blockIdx.x * 4 + wid;
    if (n >= N) return;
    const int lane = threadIdx.x & 63;
    const int q = lane >> 4;
    const int l16 = lane & 15;
    const int start = offsets[n], end = offsets[n + 1];
    const float4 ad = a_d4[n];
    float2 acc0 = {0,0}, acc1 = {0,0}, acc2 = {0,0}, acc3 = {0,0};
    float4 den = {0,0,0,0};
    const int loff = l16 << 1;     // 2 channels of 32 (bytes in fp8)

    for (int e0 = start; e0 < end; e0 += 64) {
        const int cnt = min(64, end - e0);
        if (lane < cnt) {
            int sB = srcS[e0 + lane];
            slds[wid][lane] = sB;
            const float4 as = a_s4[sB];
            float x0 = as.x + ad.x; x0 = fmaxf(x0, NEG_SLOPE * x0);
            float x1 = as.y + ad.y; x1 = fmaxf(x1, NEG_SLOPE * x1);
            float x2 = as.z + ad.z; x2 = fmaxf(x2, NEG_SLOPE * x2);
            float x3 = as.w + ad.w; x3 = fmaxf(x3, NEG_SLOPE * x3);
            wlds[wid][lane] = (float4){exp2f(x0), exp2f(x1), exp2f(x2), exp2f(x3)};
        }
        int j = q;
        for (; j + 12 < cnt; j += 16) {
            int ss[4]; float4 ww[4]; unsigned int gg[4];
            #pragma unroll
            for (int u = 0; u < 4; u++) {
                ss[u] = slds[wid][j + 4 * u];
                ww[u] = wlds[wid][j + 4 * u];
            }
            #pragma unroll
            for (int u = 0; u < 4; u++)
                gg[u] = *(const unsigned short*)&x8[((size_t)ss[u] << 5) + loff];
            #pragma unroll
            for (int u = 0; u < 4; u++) {
                float vl, vh;
                fp8x2_to_f32(gg[u], vl, vh);
                acc0.x += ww[u].x * vl; acc0.y += ww[u].x * vh;
                acc1.x += ww[u].y * vl; acc1.y += ww[u].y * vh;
                acc2.x += ww[u].z * vl; acc2.y += ww[u].z * vh;
                acc3.x += ww[u].w * vl; acc3.y += ww[u].w * vh;
                den.x += ww[u].x; den.y += ww[u].y; den.z += ww[u].z; den.w += ww[u].w;
            }
        }
        for (; j + 4 < cnt; j += 8) {
            const int s0 = slds[wid][j], s1 = slds[wid][j + 4];
            const float4 w0 = wlds[wid][j], w1 = wlds[wid][j + 4];
            const unsigned int g0 = *(const unsigned short*)&x8[((size_t)s0 << 5) + loff];
            const unsigned int g1 = *(const unsigned short*)&x8[((size_t)s1 << 5) + loff];
            float vl0, vh0, vl1, vh1;
            fp8x2_to_f32(g0, vl0, vh0);
            fp8x2_to_f32(g1, vl1, vh1);
            acc0.x += w0.x * vl0 + w1.x * vl1; acc0.y += w0.x * vh0 + w1.x * vh1;
            acc1.x += w0.y * vl0 + w1.y * vl1; acc1.y += w0.y * vh0 + w1.y * vh1;
            acc2.x += w0.z * vl0 + w1.z * vl1; acc2.y += w0.z * vh0 + w1.z * vh1;
            acc3.x += w0.w * vl0 + w1.w * vl1; acc3.y += w0.w * vh0 + w1.w * vh1;
            den.x += w0.x + w1.x; den.y += w0.y + w1.y;
            den.z += w0.z + w1.z; den.w += w0.w + w1.w;
        }
        for (; j < cnt; j += 4) {
            const int s = slds[wid][j];
            const float4 w = wlds[wid][j];
            const unsigned int g = *(const unsigned short*)&x8[((size_t)s << 5) + loff];
            float vl, vh;
            fp8x2_to_f32(g, vl, vh);
            acc0.x += w.x * vl; acc0.y += w.x * vh;
            acc1.x += w.y * vl; acc1.y += w.y * vh;
            acc2.x += w.z * vl; acc2.y += w.z * vh;
            acc3.x += w.w * vl; acc3.y += w.w * vh;
            den.x += w.x; den.y += w.y; den.z += w.z; den.w += w.w;
        }
    }
    #pragma unroll
    for (int off = 16; off < 64; off <<= 1) {
        acc0.x += __shfl_xor(acc0.x, off); acc0.y += __shfl_xor(acc0.y, off);
        acc1.x += __shfl_xor(acc1.x, off); acc1.y += __shfl_xor(acc1.y, off);
        acc2.x += __shfl_xor(acc2.x, off); acc2.y += __shfl_xor(acc2.y, off);
        acc3.x += __shfl_xor(acc3.x, off); acc3.y += __shfl_xor(acc3.y, off);
        den.x += __shfl_xor(den.x, off); den.y += __shfl_xor(den.y, off);
        den.z += __shfl_xor(den.z, off); den.w += __shfl_xor(den.w, off);
    }
    if (q == 0) {
        const float i0 = 1.0f / (den.x + 1e-16f);
        const float i1 = 1.0f / (den.y + 1e-16f);
        const float i2 = 1.0f / (den.z + 1e-16f);
        const float i3 = 1.0f / (den.w + 1e-16f);
        unsigned int o0 = (unsigned int)f2b(acc0.x * i0) | ((unsigned int)f2b(acc0.y * i0) << 16);
        unsigned int o1 = (unsigned int)f2b(acc1.x * i1) | ((unsigned int)f2b(acc1.y * i1) << 16);
        unsigned int o2 = (unsigned int)f2b(acc2.x * i2) | ((unsigned int)f2b(acc2.y * i2) << 16);
        unsigned int o3 = (unsigned int)f2b(acc3.x * i3) | ((unsigned int)f2b(acc3.y * i3) << 16);
        *(unsigned int*)&aggX[((size_t)n << 7) + 0 * 32 + loff] = o0;
        *(unsigned int*)&aggX[((size_t)n << 7) + 1 * 32 + loff] = o1;
        *(unsigned int*)&aggX[((size_t)n << 7) + 2 * 32 + loff] = o2;
        *(unsigned int*)&aggX[((size_t)n << 7) + 3 * 32 + loff] = o3;
    }
}

// ------------- conv2 aggregate over FP8 table (4B/lane gather) + bias + ELU + conv3 scores -------------
__global__ __launch_bounds__(256) void gat_fused4(
        const int* __restrict__ offsets, const int* __restrict__ srcS,
        const float4* __restrict__ a_s4, const float4* __restrict__ a_d4,
        const unsigned char* __restrict__ h8, const float* __restrict__ bias,
        const float* __restrict__ u3s, const float* __restrict__ u3d,
        float* __restrict__ a_s3, float* __restrict__ a_d3,
        unsigned short* __restrict__ out16, int N) {
    __shared__ float wlds[4][64][4];
    __shared__ int slds[4][64];
    const int wid = threadIdx.x >> 6;
    const int n = blockIdx.x * 4 + wid;
    if (n >= N) return;
    const int lane = threadIdx.x & 63;
    const int quad = lane >> 4;
    const int start = offsets[n], end = offsets[n + 1];
    const float4 ad = a_d4[n];
    float4 acc = {0, 0, 0, 0};
    float den = 0.0f;
    const int loff = lane << 2;                  // channel index == byte offset (fp8)

    for (int e0 = start; e0 < end; e0 += 64) {
        const int cnt = min(64, end - e0);
        if (lane < cnt) {
            int sB = srcS[e0 + lane];
            slds[wid][lane] = sB;
            const float4 as = a_s4[sB];
            float x0 = as.x + ad.x; x0 = fmaxf(x0, NEG_SLOPE * x0);
            float x1 = as.y + ad.y; x1 = fmaxf(x1, NEG_SLOPE * x1);
            float x2 = as.z + ad.z; x2 = fmaxf(x2, NEG_SLOPE * x2);
            float x3 = as.w + ad.w; x3 = fmaxf(x3, NEG_SLOPE * x3);
            wlds[wid][lane][0] = exp2f(x0);
            wlds[wid][lane][1] = exp2f(x1);
            wlds[wid][lane][2] = exp2f(x2);
            wlds[wid][lane][3] = exp2f(x3);
        }
        int j = 0;
        for (; j + 4 <= cnt; j += 4) {
            const int s0 = __builtin_amdgcn_readfirstlane(slds[wid][j + 0]);
            const int s1 = __builtin_amdgcn_readfirstlane(slds[wid][j + 1]);
            const int s2 = __builtin_amdgcn_readfirstlane(slds[wid][j + 2]);
            const int s3 = __builtin_amdgcn_readfirstlane(slds[wid][j + 3]);
            const float w0 = wlds[wid][j + 0][quad];
            const float w1 = wlds[wid][j + 1][quad];
            const float w2 = wlds[wid][j + 2][quad];
            const float w3 = wlds[wid][j + 3][quad];
            const unsigned int g0 = *(const unsigned int*)&h8[((size_t)s0 << 8) + loff];
            const unsigned int g1 = *(const unsigned int*)&h8[((size_t)s1 << 8) + loff];
            const unsigned int g2 = *(const unsigned int*)&h8[((size_t)s2 << 8) + loff];
            const unsigned int g3 = *(const unsigned int*)&h8[((size_t)s3 << 8) + loff];
            float v0, v1, v2, v3;
            fp8x4_to_f32(g0, v0, v1, v2, v3);
            acc.x += w0 * v0; acc.y += w0 * v1; acc.z += w0 * v2; acc.w += w0 * v3;
            fp8x4_to_f32(g1, v0, v1, v2, v3);
            acc.x += w1 * v0; acc.y += w1 * v1; acc.z += w1 * v2; acc.w += w1 * v3;
            fp8x4_to_f32(g2, v0, v1, v2, v3);
            acc.x += w2 * v0; acc.y += w2 * v1; acc.z += w2 * v2; acc.w += w2 * v3;
            fp8x4_to_f32(g3, v0, v1, v2, v3);
            acc.x += w3 * v0; acc.y += w3 * v1; acc.z += w3 * v2; acc.w += w3 * v3;
            den += (w0 + w1) + (w2 + w3);
        }
        for (; j < cnt; j++) {
            const int s = __builtin_amdgcn_readfirstlane(slds[wid][j]);
            const float w = wlds[wid][j][quad];
            const unsigned int g = *(const unsigned int*)&h8[((size_t)s << 8) + loff];
            float v0, v1, v2, v3;
            fp8x4_to_f32(g, v0, v1, v2, v3);
            acc.x += w * v0; acc.y += w * v1; acc.z += w * v2; acc.w += w * v3;
            den += w;
        }
    }

    const float inv = 1.0f / (den + 1e-16f);
    const float4 bb = *(const float4*)&bias[loff];
    float v0 = acc.x * inv + bb.x; v0 = (v0 > 0.0f) ? v0 : expm1f(v0);
    float v1 = acc.y * inv + bb.y; v1 = (v1 > 0.0f) ? v1 : expm1f(v1);
    float v2 = acc.z * inv + bb.z; v2 = (v2 > 0.0f) ? v2 : expm1f(v2);
    float v3 = acc.w * inv + bb.w; v3 = (v3 > 0.0f) ? v3 : expm1f(v3);
    // conv3 scores from the fp32 h3 row (each lane owns 4 channels)
    {
        const float4 us = *(const float4*)&u3s[loff];
        const float4 ud = *(const float4*)&u3d[loff];
        float ps = v0 * us.x + v1 * us.y + v2 * us.z + v3 * us.w;
        float pd = v0 * ud.x + v1 * ud.y + v2 * ud.z + v3 * ud.w;
        #pragma unroll
        for (int off = 1; off < 64; off <<= 1) {
            ps += __shfl_xor(ps, off);
            pd += __shfl_xor(pd, off);
        }
        if (lane == 0) {
            a_s3[n] = ps * LOG2E;
            a_d3[n] = pd * LOG2E;
        }
    }
    uint2 o;
    o.x = (unsigned int)f2b(v0) | ((unsigned int)f2b(v1) << 16);
    o.y = (unsigned int)f2b(v2) | ((unsigned int)f2b(v3) << 16);
    *(uint2*)&out16[(size_t)n * 256 + loff] = o;
}

// ------------- H=1 fused (conv3): wave/node gather over FP8 table + PARTITIONED fused mean-pool -------------
__global__ __launch_bounds__(256) void gat_fused1(
        const int* __restrict__ offsets, const int* __restrict__ srcS,
        const float* __restrict__ a_s, const float* __restrict__ a_d,
        const unsigned char* __restrict__ h8, const float* __restrict__ bias,
        const int* __restrict__ batch,
        float* __restrict__ pooledP, float* __restrict__ cntP, int N, int G) {
    __shared__ float wlds[4][64];
    __shared__ int slds[4][64];
    __shared__ float2 sOut[4][32];
    __shared__ int sG[4];
    const int wid = threadIdx.x >> 6;
    const int n = blockIdx.x * 4 + wid;
    const bool valid = n < N;                  // no early return: all waves reach the barrier
    const int lane = threadIdx.x & 63;
    const int half = lane >> 5;
    const int l32 = lane & 31;
    const int start = valid ? offsets[n] : 0;
    const int end   = valid ? offsets[n + 1] : 0;
    const float ad  = valid ? a_d[n] : 0.0f;
    float accx = 0.0f, accy = 0.0f, den = 0.0f;
    const int loff = l32 << 1;                 // 2 channels (bytes in fp8)

    for (int e0 = start; e0 < end; e0 += 64) {
        const int cnt_ = min(64, end - e0);
        if (lane < cnt_) {
            int sB = srcS[e0 + lane];
            slds[wid][lane] = sB;
            float ev = a_s[sB] + ad;
            ev = fmaxf(ev, NEG_SLOPE * ev);
            wlds[wid][lane] = exp2f(ev);
        }
        int j = half;
        for (; j + 8 <= cnt_ + half; j += 8) {
            const int s0 = slds[wid][j + 0];
            const int s1 = slds[wid][j + 2];
            const int s2 = slds[wid][j + 4];
            const int s3 = slds[wid][j + 6];
            const float w0 = wlds[wid][j + 0];
            const float w1 = wlds[wid][j + 2];
            const float w2 = wlds[wid][j + 4];
            const float w3 = wlds[wid][j + 6];
            const unsigned int g0 = *(const unsigned short*)&h8[((size_t)s0 << 6) + loff];
            const unsigned int g1 = *(const unsigned short*)&h8[((size_t)s1 << 6) + loff];
            const unsigned int g2 = *(const unsigned short*)&h8[((size_t)s2 << 6) + loff];
            const unsigned int g3 = *(const unsigned short*)&h8[((size_t)s3 << 6) + loff];
            float vl, vh;
            fp8x2_to_f32(g0, vl, vh); accx += w0 * vl; accy += w0 * vh;
            fp8x2_to_f32(g1, vl, vh); accx += w1 * vl; accy += w1 * vh;
            fp8x2_to_f32(g2, vl, vh); accx += w2 * vl; accy += w2 * vh;
            fp8x2_to_f32(g3, vl, vh); accx += w3 * vl; accy += w3 * vh;
            den += (w0 + w1) + (w2 + w3);
        }
        for (; j < cnt_; j += 2) {
            const int s = slds[wid][j];
            const float w = wlds[wid][j];
            const unsigned int g = *(const unsigned short*)&h8[((size_t)s << 6) + loff];
            float vl, vh;
            fp8x2_to_f32(g, vl, vh);
            accx += w * vl;
            accy += w * vh;
            den += w;
        }
    }
    accx += __shfl_xor(accx, 32);
    accy += __shfl_xor(accy, 32);
    den  += __shfl_xor(den, 32);
    if (half == 0) {
        if (valid) {
            const float inv = 1.0f / (den + 1e-16f);
            sOut[wid][l32] = (float2){accx * inv + bias[loff], accy * inv + bias[loff + 1]};
        } else {
            sOut[wid][l32] = (float2){0.0f, 0.0f};
        }
        if (l32 == 0) sG[wid] = valid ? batch[n] : -1;
    }
    __syncthreads();
    const int p = blockIdx.x & 63;
    if (wid == 0 && half == 0) {
        const int g0 = sG[0], g1 = sG[1], g2 = sG[2], g3 = sG[3];
        if (g0 >= 0 && g1 == g0 && g2 == g0 && g3 == g0) {
            const float2 s0 = sOut[0][l32], s1 = sOut[1][l32];
            const float2 s2 = sOut[2][l32], s3 = sOut[3][l32];
            float* base = pooledP + ((size_t)p * G + g0) * 64;
            atomicAdd(&base[loff],     (s0.x + s1.x) + (s2.x + s3.x));
            atomicAdd(&base[loff + 1], (s0.y + s1.y) + (s2.y + s3.y));
            if (l32 == 0) atomicAdd(&cntP[p * G + g0], 4.0f);
        } else {
            #pragma unroll
            for (int w = 0; w < 4; w++) {
                const int g = sG[w];
                if (g >= 0) {
                    const float2 s = sOut[w][l32];
                    float* base = pooledP + ((size_t)p * G + g) * 64;
                    atomicAdd(&base[loff], s.x);
                    atomicAdd(&base[loff + 1], s.y);
                    if (l32 == 0) atomicAdd(&cntP[p * G + g], 1.0f);
                }
            }
        }
    }
}

// ------------- decoder head: one block per graph (reduces 64 pool partitions first) -------------
__global__ __launch_bounds__(256) void final_kernel(
        const float* __restrict__ pooledP, const float* __restrict__ cntP,
        const float* __restrict__ gf, const float* __restrict__ Wg,
        const float* __restrict__ bg, const float* __restrict__ Wd1,
        const float* __restrict__ bd1, const float* __restrict__ gamma,
        const float* __restrict__ beta, const float* __restrict__ Wd2,
        const float* __restrict__ bd2, float* __restrict__ out, int G) {
    const int g = blockIdx.x;
    const int tid = threadIdx.x;
    const int lane = tid & 63;
    const int wave = tid >> 6;
    __shared__ float sPart[4][64];
    __shared__ float sCntTot;
    __shared__ float spg[128];
    __shared__ float sz[64];
    __shared__ float wred[8];

    {   // partition reduce: wave pg sums partitions [pg*16, pg*16+16)
        const int c = lane;
        const int pg = wave;
        float a = 0.0f;
        #pragma unroll
        for (int p = 0; p < 16; p++)
            a += pooledP[((size_t)(pg * 16 + p) * G + g) * 64 + c];
        sPart[pg][c] = a;
        if (pg == 1) {
            float cv = cntP[c * G + g];
            #pragma unroll
            for (int off = 32; off > 0; off >>= 1) cv += __shfl_xor(cv, off);
            if (c == 0) sCntTot = cv;
        }
    }
    __syncthreads();
    if (tid < 64) {
        spg[tid] = (sPart[0][tid] + sPart[1][tid] + sPart[2][tid] + sPart[3][tid])
                   / fmaxf(sCntTot, 1.0f);
    } else if (tid < 128) {
        int c = tid - 64;
        float v = bg[c];
        #pragma unroll
        for (int k = 0; k < 4; k++) v += gf[g * 4 + k] * Wg[k * 64 + c];
        spg[64 + c] = fmaxf(v, 0.0f);
    }
    __syncthreads();
    if (tid < 64) {
        float v = bd1[tid];
        #pragma unroll 8
        for (int k = 0; k < 128; k++) v += spg[k] * Wd1[k * 64 + tid];
        v = v * gamma[tid] + beta[tid];
        sz[tid] = fmaxf(v, 0.0f);
    }
    __syncthreads();
    float v = bd2[tid];
    #pragma unroll 8
    for (int k = 0; k < 64; k++) v += sz[k] * Wd2[k * 256 + tid];
    float m = v;
    #pragma unroll
    for (int off = 32; off > 0; off >>= 1) m = fmaxf(m, __shfl_xor(m, off));
    if (lane == 0) wred[wave] = m;
    __syncthreads();
    float M = fmaxf(fmaxf(wred[0], wred[1]), fmaxf(wred[2], wred[3]));
    float e = expf(v - M);
    float s = e;
    #pragma unroll
    for (int off = 32; off > 0; off >>= 1) s += __shfl_xor(s, off);
    if (lane == 0) wred[4 + wave] = s;
    __syncthreads();
    float S = (wred[4] + wred[5]) + (wred[6] + wred[7]);
    out[g * 256 + tid] = e / S;
}

extern "C" void kernel_launch(void* const* d_in, const int* in_sizes, int n_in,
                              void* d_out, int out_size, void* d_ws, size_t ws_size,
                              hipStream_t stream) {
    const float* x     = (const float*)d_in[0];
    const int*   ei    = (const int*)  d_in[1];
    const int*   batch = (const int*)  d_in[2];
    const float* gf    = (const float*)d_in[3];
    const float* W_enc = (const float*)d_in[4];
    const float* b_enc = (const float*)d_in[5];
    const float* W1  = (const float*)d_in[6];
    const float* as1 = (const float*)d_in[7];
    const float* ad1 = (const float*)d_in[8];
    const float* b1  = (const float*)d_in[9];
    const float* W2  = (const float*)d_in[10];
    const float* as2 = (const float*)d_in[11];
    const float* ad2 = (const float*)d_in[12];
    const float* b2  = (const float*)d_in[13];
    const float* W3  = (const float*)d_in[14];
    const float* as3 = (const float*)d_in[15];
    const float* ad3 = (const float*)d_in[16];
    const float* b3  = (const float*)d_in[17];
    const float* Wg  = (const float*)d_in[18];
    const float* bg  = (const float*)d_in[19];
    const float* Wd1 = (const float*)d_in[20];
    const float* bd1 = (const float*)d_in[21];
    const float* gm  = (const float*)d_in[22];
    const float* bt  = (const float*)d_in[23];
    const float* Wd2 = (const float*)d_in[24];
    const float* bd2 = (const float*)d_in[25];

    const int N  = in_sizes[2];
    const int E  = in_sizes[1] / 2;
    const int G  = in_sizes[3] / 4;
    const int Et = E + N;

    unsigned short* h16a = (unsigned short*)d_ws;                // slot: conv2 fp8 table [N,256]B
    unsigned short* h16b = h16a + (size_t)N * 256;               // [N,256]: aggX [N,128] early, then conv2 agg out
    unsigned short* h1_16 = h16b + (size_t)N * 256;              // slot: conv3 fp8 table [N,64]B
    unsigned short* x16  = h1_16 + (size_t)N * 64;               // slot: x fp8 table [N,32]B
    unsigned short* Wc1t = x16 + (size_t)N * 32;                 // [4][64][32]
    unsigned short* Wt2  = Wc1t + 4 * 64 * 32;                   // [256,256]
    unsigned short* Wt3  = Wt2 + 256 * 256;                      // [64,256]
    float* bc1    = (float*)(Wt3 + 64 * 256);                    // [256]
    float* a_s    = bc1 + 256;                                   // [N,4]
    float* a_d    = a_s + (size_t)N * 4;                         // [N,4]
    float* a_s3   = a_d + (size_t)N * 4;                         // [N]
    float* a_d3   = a_s3 + N;                                    // [N]
    float* u1s    = a_d3 + N;                                    // [64,4]
    float* u1d    = u1s + 256;                                   // [64,4]
    float* u3s    = u1d + 256;                                   // [256]
    float* u3d    = u3s + 256;                                   // [256]
    float* pooledP = u3d + 256;                                  // [64][G][64]
    float* cntP   = pooledP + (size_t)64 * G * 64;               // [64][G]
    int*   offsets = (int*)(cntP + 64 * G);                      // [N+1]
    int*   srcS    = offsets + (N + 1);                          // [Et]
    int*   counts  = srcS + Et;                                  // [N]
    int*   cursor  = counts + N;                                 // [N]
    int*   blockSums = cursor + N;                               // [cdiv(N,1024)]

    unsigned char* h8a  = (unsigned char*)h16a;                  // fp8 conv2 gather table view
    unsigned char* h1_8 = (unsigned char*)h1_16;                 // fp8 conv3 gather table view
    unsigned char* x8   = (unsigned char*)x16;                   // fp8 x gather table view

    dim3 blk(256);
    auto cdiv = [](int a, int b) { return (a + b - 1) / b; };
    const int eBlocks = cdiv(Et, 256);
    const int rowBlocks = cdiv(N, 64);
    const int nScanBlocks = cdiv(N, 1024);
    const int zc = cdiv(N, 256);
    const int z2 = cdiv(64 * G * 64, 256);

    // ---------------- prep (folded weights + u-vectors + zero-init) + CSR build ----------------
    prep_kernel<<<355 + zc + z2, blk, 0, stream>>>(W_enc, b_enc, W1, W2, W3, as1, ad1, b1,
                                                   as3, ad3, Wc1t, bc1, Wt2, Wt3,
                                                   u1s, u1d, u3s, u3d,
                                                   counts, pooledP, cntP, N, G, zc);
    edge_hist_kernel<<<eBlocks, blk, 0, stream>>>(ei, counts, E, Et);
    scan_blocks<<<nScanBlocks, 1024, 0, stream>>>(counts, blockSums, N);
    scan_add2<<<cdiv(N + 1, 256), blk, 0, stream>>>(counts, blockSums, nScanBlocks,
                                                    offsets, cursor, N, Et);
    edge_sort_kernel<<<eBlocks, blk, 0, stream>>>(ei, cursor, srcS, E, Et);

    // conv1 scores from fp32 x + x->fp8 gather table
    score_x<<<cdiv(N, 32), blk, 0, stream>>>(x, W_enc, b_enc, u1s, u1d, x8, a_s, a_d, N);

    // ---------------- conv1 aggregate (fp8 x) -> fused conv1+conv2 GEMM (fp8 table out) ----------------
    gat_agg_x32<<<cdiv(N, 4), blk, 0, stream>>>(offsets, srcS, (const float4*)a_s,
                                                (const float4*)a_d, x8, h16b, N);
    gemm_c12<<<rowBlocks, blk, 0, stream>>>(h16b, Wc1t, bc1, Wt2, as2, ad2,
                                            a_s, a_d, h8a, N);

    // ---------------- conv2 aggregate over fp8 table (+conv3 scores fused) ----------------
    gat_fused4<<<cdiv(N, 4), blk, 0, stream>>>(offsets, srcS, (const float4*)a_s,
                                               (const float4*)a_d, h8a, b2,
                                               u3s, u3d, a_s3, a_d3, h16b, N);

    // ---------------- conv3: GEMM (fp8 table out) -> aggregate + partitioned pool ----------------
    gemm_c3<<<rowBlocks, blk, 0, stream>>>(h16b, Wt3, h1_8, N);
    gat_fused1<<<cdiv(N, 4), blk, 0, stream>>>(offsets, srcS, a_s3, a_d3, h1_8, b3,
                                               batch, pooledP, cntP, N, G);

    // ---------------- decoder head ----------------
    final_kernel<<<G, blk, 0, stream>>>(pooledP, cntP, gf, Wg, bg, Wd1, bd1, gm, bt, Wd2, bd2,
                                        (float*)d_out, G);
}

// Round 10
// 354.086 us; speedup vs baseline: 1.3041x; 1.0699x over previous
//
#include <hip/hip_runtime.h>
#include <math.h>

#define NEG_SLOPE 0.2f
#define LOG2E 1.4426950408889634f
#define BSH 7                      // 128 nodes per dst-bucket

typedef __attribute__((ext_vector_type(8))) short short8;   // 8 bf16 = 4 VGPRs
typedef __attribute__((ext_vector_type(4))) float f32x4;    // MFMA acc
typedef __attribute__((ext_vector_type(2))) float f32x2;

#if __has_builtin(__builtin_amdgcn_cvt_pk_f32_fp8) && __has_builtin(__builtin_amdgcn_cvt_pk_fp8_f32)
#define FP8_HW 1
#else
#define FP8_HW 0
#endif

__device__ inline float b2f_lo(unsigned int u) {
    union { unsigned int i; float f; } x; x.i = u << 16; return x.f;
}
__device__ inline float b2f_hi(unsigned int u) {
    union { unsigned int i; float f; } x; x.i = u & 0xFFFF0000u; return x.f;
}
__device__ inline unsigned short f2b(float f) {
    union { float f; unsigned int i; } u; u.f = f;
    unsigned int r = u.i + 0x7FFF + ((u.i >> 16) & 1);   // round-to-nearest-even
    return (unsigned short)(r >> 16);
}

// ---- OCP e4m3 helpers (HW cvt on gfx950; exact manual fallback) ----
__device__ inline float fp8_decode1(unsigned int b) {
    unsigned int e = (b >> 3) & 15, m = b & 7;
    union { unsigned int i; float f; } u;
    if (e == 0) u.f = (float)m * 0.001953125f;          // subnormal: m * 2^-9
    else u.i = ((e + 120) << 23) | (m << 20);            // (1+m/8) * 2^(e-7)
    if (b & 0x80) u.f = -u.f;
    return u.f;
}
__device__ inline void fp8x4_to_f32(unsigned int g, float& v0, float& v1,
                                    float& v2, float& v3) {
#if FP8_HW
    f32x2 lo = __builtin_amdgcn_cvt_pk_f32_fp8((int)g, false);   // bytes 0,1
    f32x2 hi = __builtin_amdgcn_cvt_pk_f32_fp8((int)g, true);    // bytes 2,3
    v0 = lo[0]; v1 = lo[1]; v2 = hi[0]; v3 = hi[1];
#else
    v0 = fp8_decode1(g & 255);         v1 = fp8_decode1((g >> 8) & 255);
    v2 = fp8_decode1((g >> 16) & 255); v3 = fp8_decode1((g >> 24) & 255);
#endif
}
__device__ inline void fp8x2_to_f32(unsigned int g2, float& v0, float& v1) {
#if FP8_HW
    f32x2 lo = __builtin_amdgcn_cvt_pk_f32_fp8((int)(g2 & 0xFFFF), false);
    v0 = lo[0]; v1 = lo[1];
#else
    v0 = fp8_decode1(g2 & 255);
    v1 = fp8_decode1((g2 >> 8) & 255);
#endif
}
__device__ inline unsigned char f32_to_fp8(float f) {
#if FP8_HW
    return (unsigned char)(__builtin_amdgcn_cvt_pk_fp8_f32(f, f, 0, false) & 0xFF);
#else
    union { float f; unsigned int i; } u; u.f = f;
    unsigned int s = (u.i >> 24) & 0x80;
    float a = fabsf(f);
    if (a < 0.015625f) {                                 // subnormal band
        int m = (int)rintf(a * 512.0f);
        if (m > 7) return (unsigned char)(s | 0x08);
        return (unsigned char)(s | m);
    }
    if (a >= 448.0f) return (unsigned char)(s | 0x7E);
    int e = (int)((u.i >> 23) & 0xFF) - 127;
    union { unsigned int i; float f; } sc; sc.i = (unsigned int)(127 + 3 - e) << 23;
    int q = (int)rintf(a * sc.f);                        // in [8,16]
    if (q >= 16) { q = 8; e += 1; }
    return (unsigned char)(s | ((unsigned int)(e + 7) << 3) | (unsigned int)(q - 8));
#endif
}

// ---------------- prep: folded conv1 weights, u1/u3 vectors, Wt2/Wt3, ALL zero-init ----------------
__global__ void prep_kernel(const float* __restrict__ W_enc, const float* __restrict__ b_enc,
                            const float* __restrict__ W1, const float* __restrict__ W2,
                            const float* __restrict__ W3, const float* __restrict__ as1,
                            const float* __restrict__ ad1, const float* __restrict__ b1,
                            const float* __restrict__ as3, const float* __restrict__ ad3,
                            unsigned short* __restrict__ Wc1t, float* __restrict__ bc1,
                            unsigned short* __restrict__ Wt2, unsigned short* __restrict__ Wt3,
                            float* __restrict__ u1s, float* __restrict__ u1d,
                            float* __restrict__ u3s, float* __restrict__ u3d,
                            int* __restrict__ counts, float* __restrict__ pooledP,
                            float* __restrict__ cntP, int* __restrict__ bucketCnt,
                            int N, int G, int zc, int NB) {
    const int b = blockIdx.x;
    const int t = threadIdx.x;
    if (b < 32) {
        int i = b * 256 + t;                       // 8192 values
        int h = i >> 11, rem = i & 2047, o = rem >> 5, j = rem & 31;
        float s = 0.0f;
        for (int k = 0; k < 64; k++)
            s += W_enc[j * 64 + k] * W1[k * 256 + h * 64 + o];
        Wc1t[i] = f2b(s);
    } else if (b == 32) {
        float s = b1[t];
        for (int k = 0; k < 64; k++) s += b_enc[k] * W1[k * 256 + t];
        bc1[t] = s;
    } else if (b == 33) {
        int k = t >> 2, h = t & 3;
        float s = 0.0f, d = 0.0f;
        for (int c = 0; c < 64; c++) {
            float w = W1[k * 256 + h * 64 + c];
            s += w * as1[h * 64 + c];
            d += w * ad1[h * 64 + c];
        }
        u1s[k * 4 + h] = s;
        u1d[k * 4 + h] = d;
    } else if (b == 34) {
        float s = 0.0f, d = 0.0f;
        for (int o = 0; o < 64; o++) {
            float w = W3[t * 64 + o];
            s += w * as3[o];
            d += w * ad3[o];
        }
        u3s[t] = s; u3d[t] = d;
    } else if (b < 35 + 256) {
        int i = (b - 35) * 256 + t;                // K=256, M=256
        int k = i >> 8, m = i & 255;
        Wt2[(size_t)m * 256 + k] = f2b(W2[i]);
    } else if (b < 35 + 256 + 64) {
        int i = (b - 291) * 256 + t;               // K=256, M=64
        int k = i >> 6, m = i & 63;
        Wt3[(size_t)m * 256 + k] = f2b(W3[i]);
    } else if (b < 355 + zc) {
        int i = (b - 355) * 256 + t;
        if (i < N) counts[i] = 0;
    } else {
        int i = (b - 355 - zc) * 256 + t;
        if (i < 64 * G * 64) pooledP[i] = 0.0f;    // [64 partitions][G][64]
        if (i < 64 * G) cntP[i] = 0.0f;            // [64 partitions][G]
        if (i <= NB) bucketCnt[i] = 0;
    }
}

// ---------------- score_x: conv1 scores from fp32 x + x -> fp8 table ----------------
__global__ __launch_bounds__(256) void score_x(
        const float* __restrict__ x, const float* __restrict__ W_enc,
        const float* __restrict__ b_enc,
        const float* __restrict__ u1s, const float* __restrict__ u1d,
        unsigned char* __restrict__ x8, float* __restrict__ a_s,
        float* __restrict__ a_d, int N) {
    __shared__ float sUs[32][4], sUd[32][4], sC[8];
    __shared__ float sX[32][33];
    const int t = threadIdx.x;
    if (t < 128) {
        int j = t >> 2, h = t & 3;
        float s = 0.0f, d = 0.0f;
        for (int k = 0; k < 64; k++) {
            float w = W_enc[j * 64 + k];
            s += w * u1s[k * 4 + h];
            d += w * u1d[k * 4 + h];
        }
        sUs[j][h] = s; sUd[j][h] = d;
    } else if (t < 136) {
        int hh = t - 128;                           // 0..3 -> s, 4..7 -> d
        const float* u = (hh < 4) ? u1s : u1d;
        int h = hh & 3;
        float c = 0.0f;
        for (int k = 0; k < 64; k++) c += b_enc[k] * u[k * 4 + h];
        sC[hh] = c;
    }
    const int n0 = blockIdx.x * 32;
    const int row = t >> 3, col = (t & 7) << 2;
    float4 xv = {0, 0, 0, 0};
    if (n0 + row < N) xv = *(const float4*)&x[(size_t)(n0 + row) * 32 + col];
    sX[row][col + 0] = xv.x; sX[row][col + 1] = xv.y;
    sX[row][col + 2] = xv.z; sX[row][col + 3] = xv.w;
    __syncthreads();
    const int ni = t >> 3, oi = t & 7, h = oi & 3;
    const bool isS = oi < 4;
    float acc = sC[oi];
    #pragma unroll 8
    for (int j = 0; j < 32; j++) acc += sX[ni][j] * (isS ? sUs[j][h] : sUd[j][h]);
    if (n0 + ni < N) {
        float* out = isS ? a_s : a_d;
        out[(size_t)(n0 + ni) * 4 + h] = acc * LOG2E;
    }
    if (n0 + row < N) {
        unsigned int o = (unsigned int)f32_to_fp8(xv.x)
                       | ((unsigned int)f32_to_fp8(xv.y) << 8)
                       | ((unsigned int)f32_to_fp8(xv.z) << 16)
                       | ((unsigned int)f32_to_fp8(xv.w) << 24);
        *(unsigned int*)&x8[(size_t)(n0 + row) * 32 + col] = o;
    }
}

// ---------------- FUSED conv1+conv2 GEMM (fp8 table out) ----------------
__global__ __launch_bounds__(256) void gemm_c12(
        const unsigned short* __restrict__ aggX,   // [N,128]
        const unsigned short* __restrict__ Wc1t,
        const float* __restrict__ bc1,
        const unsigned short* __restrict__ Wt2,
        const float* __restrict__ att_s,
        const float* __restrict__ att_d,
        float* __restrict__ a_s, float* __restrict__ a_d,
        unsigned char* __restrict__ C8,
        int Nrows) {
    __shared__ unsigned short sH[64][264];
    __shared__ unsigned short sB[256][40];
    __shared__ float sSD[64][4][2];
    const int tid = threadIdx.x;
    const int wave = tid >> 6;
    const int lane = tid & 63;
    const int quad = lane >> 4;
    const int l16 = lane & 15;
    const int row0 = blockIdx.x * 64;
    const int sr = tid >> 2;
    const int sk = (tid & 3) << 3;

    #pragma unroll
    for (int h = 0; h < 4; h++) {
        __syncthreads();
        {
            int r = row0 + sr;
            uint4 z = {0,0,0,0};
            *(uint4*)&sB[sr][sk] = (r < Nrows)
                ? *(const uint4*)&aggX[(size_t)r * 128 + h * 32 + sk] : z;
            *(uint4*)&sB[64 + sr][sk] = *(const uint4*)&Wc1t[(size_t)(h * 64 + sr) * 32 + sk];
        }
        __syncthreads();
        short8 bf = *(const short8*)&sB[64 + wave * 16 + l16][quad * 8];
        const int col = h * 64 + wave * 16 + l16;
        const float bb = bc1[col];
        #pragma unroll
        for (int i = 0; i < 4; i++) {
            short8 af = *(const short8*)&sB[i * 16 + l16][quad * 8];
            f32x4 acc = __builtin_amdgcn_mfma_f32_16x16x32_bf16(af, bf, (f32x4){0,0,0,0}, 0, 0, 0);
            #pragma unroll
            for (int r = 0; r < 4; r++) {
                float v = acc[r] + bb;
                v = (v > 0.0f) ? v : expm1f(v);        // ELU
                sH[i * 16 + quad * 4 + r][col] = f2b(v);
            }
        }
    }

    f32x4 acc2[4][4];
    #pragma unroll
    for (int i = 0; i < 4; i++)
        #pragma unroll
        for (int j = 0; j < 4; j++) acc2[i][j] = (f32x4){0,0,0,0};

    for (int kt = 0; kt < 256; kt += 32) {
        __syncthreads();
        #pragma unroll
        for (int i = 0; i < 4; i++) {
            int c = sr + i * 64;
            *(uint4*)&sB[c][sk] = *(const uint4*)&Wt2[(size_t)c * 256 + kt + sk];
        }
        __syncthreads();
        short8 bf2[4];
        #pragma unroll
        for (int j = 0; j < 4; j++)
            bf2[j] = *(const short8*)&sB[wave * 64 + j * 16 + l16][quad * 8];
        #pragma unroll
        for (int i = 0; i < 4; i++) {
            short8 af = *(const short8*)&sH[i * 16 + l16][kt + quad * 8];
            #pragma unroll
            for (int j = 0; j < 4; j++)
                acc2[i][j] = __builtin_amdgcn_mfma_f32_16x16x32_bf16(af, bf2[j], acc2[i][j], 0, 0, 0);
        }
    }

    {
        for (int t = tid; t < 512; t += 256) ((float*)sSD)[t] = 0.0f;
        __syncthreads();
        float avs[4], avd[4];
        #pragma unroll
        for (int j = 0; j < 4; j++) {
            int c = wave * 64 + j * 16 + l16;
            avs[j] = att_s[c];
            avd[j] = att_d[c];
        }
        #pragma unroll
        for (int i = 0; i < 4; i++) {
            float ps[4] = {0,0,0,0}, pd[4] = {0,0,0,0};
            #pragma unroll
            for (int j = 0; j < 4; j++)
                #pragma unroll
                for (int r = 0; r < 4; r++) {
                    ps[r] += acc2[i][j][r] * avs[j];
                    pd[r] += acc2[i][j][r] * avd[j];
                }
            #pragma unroll
            for (int off = 1; off < 16; off <<= 1)
                #pragma unroll
                for (int r = 0; r < 4; r++) {
                    ps[r] += __shfl_xor(ps[r], off);
                    pd[r] += __shfl_xor(pd[r], off);
                }
            if (l16 == 0) {
                #pragma unroll
                for (int r = 0; r < 4; r++) {
                    atomicAdd(&sSD[i * 16 + quad * 4 + r][wave][0], ps[r]);
                    atomicAdd(&sSD[i * 16 + quad * 4 + r][wave][1], pd[r]);
                }
            }
        }
        __syncthreads();
        {
            int row = tid & 63, hb = tid >> 6;
            int r = row0 + row;
            if (r < Nrows) {
                a_s[r * 4 + hb] = sSD[row][hb][0] * LOG2E;
                a_d[r * 4 + hb] = sSD[row][hb][1] * LOG2E;
            }
        }
    }
    #pragma unroll
    for (int i = 0; i < 4; i++) {
        #pragma unroll
        for (int j = 0; j < 4; j++) {
            int col = wave * 64 + j * 16 + l16;
            #pragma unroll
            for (int r = 0; r < 4; r++) {
                int row = row0 + i * 16 + quad * 4 + r;
                if (row < Nrows) C8[(size_t)row * 256 + col] = f32_to_fp8(acc2[i][j][r]);
            }
        }
    }
}

// ---------------- conv3 GEMM: C8[N,64] fp8 = bf16 A[N,256] @ Wt3^T ----------------
__global__ __launch_bounds__(256) void gemm_c3(const unsigned short* __restrict__ A16,
                                               const unsigned short* __restrict__ Bt16,
                                               unsigned char* __restrict__ C8,
                                               int Nrows) {
    __shared__ unsigned short sA[64][40];
    __shared__ unsigned short sB[64][40];
    const int tid = threadIdx.x;
    const int wave = tid >> 6;
    const int lane = tid & 63;
    const int quad = lane >> 4;
    const int l16 = lane & 15;
    const int row0 = blockIdx.x * 64;
    const int sr = tid >> 2;
    const int sk = (tid & 3) << 3;

    f32x4 acc[4];
    #pragma unroll
    for (int i = 0; i < 4; i++) acc[i] = (f32x4){0,0,0,0};

    for (int kt = 0; kt < 256; kt += 32) {
        __syncthreads();
        {
            int r = row0 + sr;
            uint4 z = {0,0,0,0};
            *(uint4*)&sA[sr][sk] = (r < Nrows) ? *(const uint4*)&A16[(size_t)r * 256 + kt + sk] : z;
            *(uint4*)&sB[sr][sk] = *(const uint4*)&Bt16[(size_t)sr * 256 + kt + sk];
        }
        __syncthreads();
        short8 bf = *(const short8*)&sB[wave * 16 + l16][quad * 8];
        #pragma unroll
        for (int i = 0; i < 4; i++) {
            short8 af = *(const short8*)&sA[i * 16 + l16][quad * 8];
            acc[i] = __builtin_amdgcn_mfma_f32_16x16x32_bf16(af, bf, acc[i], 0, 0, 0);
        }
    }
    const int col = wave * 16 + l16;
    #pragma unroll
    for (int i = 0; i < 4; i++) {
        #pragma unroll
        for (int r = 0; r < 4; r++) {
            int row = row0 + i * 16 + quad * 4 + r;
            if (row < Nrows) C8[(size_t)row * 64 + col] = f32_to_fp8(acc[i][r]);
        }
    }
}

// ------------- CSR build: node hist + dst-bucket hist (fused, LDS-aggregated buckets) -------------
__global__ __launch_bounds__(256) void edge_hist_kernel(const int* __restrict__ ei,
                                                        int* __restrict__ counts,
                                                        int* __restrict__ bucketCnt,
                                                        int E, int Et, int NB) {
    __shared__ int lhist[1024];
    const int tid = threadIdx.x;
    for (int b = tid; b < NB; b += 256) lhist[b] = 0;
    __syncthreads();
    const int base = blockIdx.x * 4096;
    #pragma unroll
    for (int k = 0; k < 16; k++) {
        int e = base + k * 256 + tid;
        if (e < Et) {
            int d = (e < E) ? ei[E + e] : e - E;
            atomicAdd(&counts[d], 1);
            atomicAdd(&lhist[d >> BSH], 1);
        }
    }
    __syncthreads();
    for (int b = tid; b < NB; b += 256) {
        int h = lhist[b];
        if (h > 0) atomicAdd(&bucketCnt[b], h);
    }
}

__global__ __launch_bounds__(1024) void scan_blocks(int* __restrict__ counts,
                                                    int* __restrict__ blockSums, int N) {
    __shared__ int wsum[16];
    const int tid = threadIdx.x;
    const int lane = tid & 63;
    const int wave = tid >> 6;
    int i = blockIdx.x * 1024 + tid;
    int v = (i < N) ? counts[i] : 0;
    int s = v;
    #pragma unroll
    for (int off = 1; off < 64; off <<= 1) {
        int t = __shfl_up(s, off);
        if (lane >= off) s += t;
    }
    if (lane == 63) wsum[wave] = s;
    __syncthreads();
    if (wave == 0 && lane < 16) {
        int ws = wsum[lane];
        #pragma unroll
        for (int off = 1; off < 16; off <<= 1) {
            int t = __shfl_up(ws, off);
            if (lane >= off) ws += t;
        }
        wsum[lane] = ws;
    }
    __syncthreads();
    int waveOff = (wave > 0) ? wsum[wave - 1] : 0;
    int incl = s + waveOff;
    if (i < N) counts[i] = incl - v;
    if (tid == 1023) blockSums[blockIdx.x] = incl;
}

__global__ void scan_add2(const int* __restrict__ excl, const int* __restrict__ blockSums,
                          int nb, int* __restrict__ offsets, int N, int Et) {
    __shared__ int sbs[64];
    if (threadIdx.x < 64) {
        int lane = threadIdx.x;
        int v = (lane < nb) ? blockSums[lane] : 0;
        int s = v;
        #pragma unroll
        for (int off = 1; off < 64; off <<= 1) {
            int t = __shfl_up(s, off);
            if (lane >= off) s += t;
        }
        sbs[lane] = s - v;                 // exclusive
    }
    __syncthreads();
    int i = blockIdx.x * 256 + threadIdx.x;
    if (i < N) offsets[i] = excl[i] + sbs[i >> 10];
    if (i == N) offsets[N] = Et;
}

// ------------- bucket scan: exclusive prefix over NB buckets (single block) -------------
__global__ __launch_bounds__(1024) void bucket_scan(const int* __restrict__ bucketCnt,
                                                    int* __restrict__ bucketOff,
                                                    int* __restrict__ bucketCur,
                                                    int NB, int Et) {
    __shared__ int s[1024];
    const int tid = threadIdx.x;
    int v = (tid < NB) ? bucketCnt[tid] : 0;
    s[tid] = v;
    __syncthreads();
    #pragma unroll
    for (int off = 1; off < 1024; off <<= 1) {
        int t = (tid >= off) ? s[tid - off] : 0;
        __syncthreads();
        s[tid] += t;
        __syncthreads();
    }
    if (tid < NB) {
        int ex = s[tid] - v;               // exclusive
        bucketOff[tid] = ex;
        bucketCur[tid] = ex;
    }
    if (tid == 0) bucketOff[NB] = Et;
}

// ------------- bucket scatter: edges -> bucketBuf (block-aggregated base claims) -------------
__global__ __launch_bounds__(256) void bucket_scatter(const int* __restrict__ ei,
                                                      int* __restrict__ bucketCur,
                                                      uint2* __restrict__ bucketBuf,
                                                      int E, int Et, int NB) {
    __shared__ int lhist[1024];
    __shared__ int lbase[1024];
    const int tid = threadIdx.x;
    for (int b = tid; b < NB; b += 256) lhist[b] = 0;
    __syncthreads();
    const int base = blockIdx.x * 4096;
    int sv[16], dv[16];
    #pragma unroll
    for (int k = 0; k < 16; k++) {
        int e = base + k * 256 + tid;
        if (e < Et) {
            int ss, dd;
            if (e < E) { ss = ei[e]; dd = ei[E + e]; } else { ss = dd = e - E; }
            sv[k] = ss; dv[k] = dd;
            atomicAdd(&lhist[dd >> BSH], 1);
        } else dv[k] = -1;
    }
    __syncthreads();
    for (int b = tid; b < NB; b += 256) {
        int h = lhist[b];
        lbase[b] = (h > 0) ? atomicAdd(&bucketCur[b], h) : 0;
    }
    __syncthreads();
    // reuse lhist as rank counters
    for (int b = tid; b < NB; b += 256) lhist[b] = 0;
    __syncthreads();
    #pragma unroll
    for (int k = 0; k < 16; k++) {
        if (dv[k] >= 0) {
            int b = dv[k] >> BSH;
            int r = atomicAdd(&lhist[b], 1);
            bucketBuf[lbase[b] + r] = (uint2){(unsigned int)sv[k], (unsigned int)dv[k]};
        }
    }
}

// ------------- bucket-local sort: one block per bucket; writes srcS within a ~9KB window -------------
__global__ __launch_bounds__(256) void bucket_sort(const uint2* __restrict__ bucketBuf,
                                                   const int* __restrict__ bucketOff,
                                                   const int* __restrict__ offsets,
                                                   int* __restrict__ srcS) {
    __shared__ int cnt[128];
    const int tid = threadIdx.x;
    const int b = blockIdx.x;
    if (tid < 128) cnt[tid] = 0;
    __syncthreads();
    const int node0 = b << BSH;
    const int s0 = bucketOff[b], s1 = bucketOff[b + 1];
    for (int i = s0 + tid; i < s1; i += 256) {
        uint2 e = bucketBuf[i];
        int dl = (int)e.y - node0;
        int r = atomicAdd(&cnt[dl], 1);
        srcS[offsets[e.y] + r] = (int)e.x;
    }
}

// ------------- conv1 aggregate of RAW x (32-dim fp8, 32 B/row, 1.6 MB table) -------------
__global__ __launch_bounds__(256) void gat_agg_x32(
        const int* __restrict__ offsets, const int* __restrict__ srcS,
        const float4* __restrict__ a_s4, const float4* __restrict__ a_d4,
        const unsigned char* __restrict__ x8,      // [N,32] fp8
        unsigned short* __restrict__ aggX,         // [N,128]
        int N) {
    __shared__ float4 wlds[4][64];
    __shared__ int slds[4][64];
    const int wid = threadIdx.x >> 6;
    const int n = blockIdx.x * 4 + wid;
    if (n >= N) return;
    const int lane = threadIdx.x & 63;
    const int q = lane >> 4;
    const int l16 = lane & 15;
    const int start = offsets[n], end = offsets[n + 1];
    const float4 ad = a_d4[n];
    float2 acc0 = {0,0}, acc1 = {0,0}, acc2 = {0,0}, acc3 = {0,0};
    float4 den = {0,0,0,0};
    const int loff = l16 << 1;     // 2 channels of 32 (bytes in fp8)

    for (int e0 = start; e0 < end; e0 += 64) {
        const int cnt = min(64, end - e0);
        if (lane < cnt) {
            int sB = srcS[e0 + lane];
            slds[wid][lane] = sB;
            const float4 as = a_s4[sB];
            float x0 = as.x + ad.x; x0 = fmaxf(x0, NEG_SLOPE * x0);
            float x1 = as.y + ad.y; x1 = fmaxf(x1, NEG_SLOPE * x1);
            float x2 = as.z + ad.z; x2 = fmaxf(x2, NEG_SLOPE * x2);
            float x3 = as.w + ad.w; x3 = fmaxf(x3, NEG_SLOPE * x3);
            wlds[wid][lane] = (float4){exp2f(x0), exp2f(x1), exp2f(x2), exp2f(x3)};
        }
        int j = q;
        for (; j + 12 < cnt; j += 16) {
            int ss[4]; float4 ww[4]; unsigned int gg[4];
            #pragma unroll
            for (int u = 0; u < 4; u++) {
                ss[u] = slds[wid][j + 4 * u];
                ww[u] = wlds[wid][j + 4 * u];
            }
            #pragma unroll
            for (int u = 0; u < 4; u++)
                gg[u] = *(const unsigned short*)&x8[((size_t)ss[u] << 5) + loff];
            #pragma unroll
            for (int u = 0; u < 4; u++) {
                float vl, vh;
                fp8x2_to_f32(gg[u], vl, vh);
                acc0.x += ww[u].x * vl; acc0.y += ww[u].x * vh;
                acc1.x += ww[u].y * vl; acc1.y += ww[u].y * vh;
                acc2.x += ww[u].z * vl; acc2.y += ww[u].z * vh;
                acc3.x += ww[u].w * vl; acc3.y += ww[u].w * vh;
                den.x += ww[u].x; den.y += ww[u].y; den.z += ww[u].z; den.w += ww[u].w;
            }
        }
        for (; j + 4 < cnt; j += 8) {
            const int s0 = slds[wid][j], s1 = slds[wid][j + 4];
            const float4 w0 = wlds[wid][j], w1 = wlds[wid][j + 4];
            const unsigned int g0 = *(const unsigned short*)&x8[((size_t)s0 << 5) + loff];
            const unsigned int g1 = *(const unsigned short*)&x8[((size_t)s1 << 5) + loff];
            float vl0, vh0, vl1, vh1;
            fp8x2_to_f32(g0, vl0, vh0);
            fp8x2_to_f32(g1, vl1, vh1);
            acc0.x += w0.x * vl0 + w1.x * vl1; acc0.y += w0.x * vh0 + w1.x * vh1;
            acc1.x += w0.y * vl0 + w1.y * vl1; acc1.y += w0.y * vh0 + w1.y * vh1;
            acc2.x += w0.z * vl0 + w1.z * vl1; acc2.y += w0.z * vh0 + w1.z * vh1;
            acc3.x += w0.w * vl0 + w1.w * vl1; acc3.y += w0.w * vh0 + w1.w * vh1;
            den.x += w0.x + w1.x; den.y += w0.y + w1.y;
            den.z += w0.z + w1.z; den.w += w0.w + w1.w;
        }
        for (; j < cnt; j += 4) {
            const int s = slds[wid][j];
            const float4 w = wlds[wid][j];
            const unsigned int g = *(const unsigned short*)&x8[((size_t)s << 5) + loff];
            float vl, vh;
            fp8x2_to_f32(g, vl, vh);
            acc0.x += w.x * vl; acc0.y += w.x * vh;
            acc1.x += w.y * vl; acc1.y += w.y * vh;
            acc2.x += w.z * vl; acc2.y += w.z * vh;
            acc3.x += w.w * vl; acc3.y += w.w * vh;
            den.x += w.x; den.y += w.y; den.z += w.z; den.w += w.w;
        }
    }
    #pragma unroll
    for (int off = 16; off < 64; off <<= 1) {
        acc0.x += __shfl_xor(acc0.x, off); acc0.y += __shfl_xor(acc0.y, off);
        acc1.x += __shfl_xor(acc1.x, off); acc1.y += __shfl_xor(acc1.y, off);
        acc2.x += __shfl_xor(acc2.x, off); acc2.y += __shfl_xor(acc2.y, off);
        acc3.x += __shfl_xor(acc3.x, off); acc3.y += __shfl_xor(acc3.y, off);
        den.x += __shfl_xor(den.x, off); den.y += __shfl_xor(den.y, off);
        den.z += __shfl_xor(den.z, off); den.w += __shfl_xor(den.w, off);
    }
    if (q == 0) {
        const float i0 = 1.0f / (den.x + 1e-16f);
        const float i1 = 1.0f / (den.y + 1e-16f);
        const float i2 = 1.0f / (den.z + 1e-16f);
        const float i3 = 1.0f / (den.w + 1e-16f);
        unsigned int o0 = (unsigned int)f2b(acc0.x * i0) | ((unsigned int)f2b(acc0.y * i0) << 16);
        unsigned int o1 = (unsigned int)f2b(acc1.x * i1) | ((unsigned int)f2b(acc1.y * i1) << 16);
        unsigned int o2 = (unsigned int)f2b(acc2.x * i2) | ((unsigned int)f2b(acc2.y * i2) << 16);
        unsigned int o3 = (unsigned int)f2b(acc3.x * i3) | ((unsigned int)f2b(acc3.y * i3) << 16);
        *(unsigned int*)&aggX[((size_t)n << 7) + 0 * 32 + loff] = o0;
        *(unsigned int*)&aggX[((size_t)n << 7) + 1 * 32 + loff] = o1;
        *(unsigned int*)&aggX[((size_t)n << 7) + 2 * 32 + loff] = o2;
        *(unsigned int*)&aggX[((size_t)n << 7) + 3 * 32 + loff] = o3;
    }
}

// ------------- conv2 aggregate over FP8 table (4B/lane gather) + bias + ELU + conv3 scores -------------
__global__ __launch_bounds__(256) void gat_fused4(
        const int* __restrict__ offsets, const int* __restrict__ srcS,
        const float4* __restrict__ a_s4, const float4* __restrict__ a_d4,
        const unsigned char* __restrict__ h8, const float* __restrict__ bias,
        const float* __restrict__ u3s, const float* __restrict__ u3d,
        float* __restrict__ a_s3, float* __restrict__ a_d3,
        unsigned short* __restrict__ out16, int N) {
    __shared__ float wlds[4][64][4];
    __shared__ int slds[4][64];
    const int wid = threadIdx.x >> 6;
    const int n = blockIdx.x * 4 + wid;
    if (n >= N) return;
    const int lane = threadIdx.x & 63;
    const int quad = lane >> 4;
    const int start = offsets[n], end = offsets[n + 1];
    const float4 ad = a_d4[n];
    float4 acc = {0, 0, 0, 0};
    float den = 0.0f;
    const int loff = lane << 2;                  // channel index == byte offset (fp8)

    for (int e0 = start; e0 < end; e0 += 64) {
        const int cnt = min(64, end - e0);
        if (lane < cnt) {
            int sB = srcS[e0 + lane];
            slds[wid][lane] = sB;
            const float4 as = a_s4[sB];
            float x0 = as.x + ad.x; x0 = fmaxf(x0, NEG_SLOPE * x0);
            float x1 = as.y + ad.y; x1 = fmaxf(x1, NEG_SLOPE * x1);
            float x2 = as.z + ad.z; x2 = fmaxf(x2, NEG_SLOPE * x2);
            float x3 = as.w + ad.w; x3 = fmaxf(x3, NEG_SLOPE * x3);
            wlds[wid][lane][0] = exp2f(x0);
            wlds[wid][lane][1] = exp2f(x1);
            wlds[wid][lane][2] = exp2f(x2);
            wlds[wid][lane][3] = exp2f(x3);
        }
        int j = 0;
        for (; j + 4 <= cnt; j += 4) {
            const int s0 = __builtin_amdgcn_readfirstlane(slds[wid][j + 0]);
            const int s1 = __builtin_amdgcn_readfirstlane(slds[wid][j + 1]);
            const int s2 = __builtin_amdgcn_readfirstlane(slds[wid][j + 2]);
            const int s3 = __builtin_amdgcn_readfirstlane(slds[wid][j + 3]);
            const float w0 = wlds[wid][j + 0][quad];
            const float w1 = wlds[wid][j + 1][quad];
            const float w2 = wlds[wid][j + 2][quad];
            const float w3 = wlds[wid][j + 3][quad];
            const unsigned int g0 = *(const unsigned int*)&h8[((size_t)s0 << 8) + loff];
            const unsigned int g1 = *(const unsigned int*)&h8[((size_t)s1 << 8) + loff];
            const unsigned int g2 = *(const unsigned int*)&h8[((size_t)s2 << 8) + loff];
            const unsigned int g3 = *(const unsigned int*)&h8[((size_t)s3 << 8) + loff];
            float v0, v1, v2, v3;
            fp8x4_to_f32(g0, v0, v1, v2, v3);
            acc.x += w0 * v0; acc.y += w0 * v1; acc.z += w0 * v2; acc.w += w0 * v3;
            fp8x4_to_f32(g1, v0, v1, v2, v3);
            acc.x += w1 * v0; acc.y += w1 * v1; acc.z += w1 * v2; acc.w += w1 * v3;
            fp8x4_to_f32(g2, v0, v1, v2, v3);
            acc.x += w2 * v0; acc.y += w2 * v1; acc.z += w2 * v2; acc.w += w2 * v3;
            fp8x4_to_f32(g3, v0, v1, v2, v3);
            acc.x += w3 * v0; acc.y += w3 * v1; acc.z += w3 * v2; acc.w += w3 * v3;
            den += (w0 + w1) + (w2 + w3);
        }
        for (; j < cnt; j++) {
            const int s = __builtin_amdgcn_readfirstlane(slds[wid][j]);
            const float w = wlds[wid][j][quad];
            const unsigned int g = *(const unsigned int*)&h8[((size_t)s << 8) + loff];
            float v0, v1, v2, v3;
            fp8x4_to_f32(g, v0, v1, v2, v3);
            acc.x += w * v0; acc.y += w * v1; acc.z += w * v2; acc.w += w * v3;
            den += w;
        }
    }

    const float inv = 1.0f / (den + 1e-16f);
    const float4 bb = *(const float4*)&bias[loff];
    float v0 = acc.x * inv + bb.x; v0 = (v0 > 0.0f) ? v0 : expm1f(v0);
    float v1 = acc.y * inv + bb.y; v1 = (v1 > 0.0f) ? v1 : expm1f(v1);
    float v2 = acc.z * inv + bb.z; v2 = (v2 > 0.0f) ? v2 : expm1f(v2);
    float v3 = acc.w * inv + bb.w; v3 = (v3 > 0.0f) ? v3 : expm1f(v3);
    // conv3 scores from the fp32 h3 row (each lane owns 4 channels)
    {
        const float4 us = *(const float4*)&u3s[loff];
        const float4 ud = *(const float4*)&u3d[loff];
        float ps = v0 * us.x + v1 * us.y + v2 * us.z + v3 * us.w;
        float pd = v0 * ud.x + v1 * ud.y + v2 * ud.z + v3 * ud.w;
        #pragma unroll
        for (int off = 1; off < 64; off <<= 1) {
            ps += __shfl_xor(ps, off);
            pd += __shfl_xor(pd, off);
        }
        if (lane == 0) {
            a_s3[n] = ps * LOG2E;
            a_d3[n] = pd * LOG2E;
        }
    }
    uint2 o;
    o.x = (unsigned int)f2b(v0) | ((unsigned int)f2b(v1) << 16);
    o.y = (unsigned int)f2b(v2) | ((unsigned int)f2b(v3) << 16);
    *(uint2*)&out16[(size_t)n * 256 + loff] = o;
}

// ------------- H=1 fused (conv3): wave/node gather over FP8 table + PARTITIONED fused mean-pool -------------
__global__ __launch_bounds__(256) void gat_fused1(
        const int* __restrict__ offsets, const int* __restrict__ srcS,
        const float* __restrict__ a_s, const float* __restrict__ a_d,
        const unsigned char* __restrict__ h8, const float* __restrict__ bias,
        const int* __restrict__ batch,
        float* __restrict__ pooledP, float* __restrict__ cntP, int N, int G) {
    __shared__ float wlds[4][64];
    __shared__ int slds[4][64];
    __shared__ float2 sOut[4][32];
    __shared__ int sG[4];
    const int wid = threadIdx.x >> 6;
    const int n = blockIdx.x * 4 + wid;
    const bool valid = n < N;                  // no early return: all waves reach the barrier
    const int lane = threadIdx.x & 63;
    const int half = lane >> 5;
    const int l32 = lane & 31;
    const int start = valid ? offsets[n] : 0;
    const int end   = valid ? offsets[n + 1] : 0;
    const float ad  = valid ? a_d[n] : 0.0f;
    float accx = 0.0f, accy = 0.0f, den = 0.0f;
    const int loff = l32 << 1;                 // 2 channels (bytes in fp8)

    for (int e0 = start; e0 < end; e0 += 64) {
        const int cnt_ = min(64, end - e0);
        if (lane < cnt_) {
            int sB = srcS[e0 + lane];
            slds[wid][lane] = sB;
            float ev = a_s[sB] + ad;
            ev = fmaxf(ev, NEG_SLOPE * ev);
            wlds[wid][lane] = exp2f(ev);
        }
        int j = half;
        for (; j + 8 <= cnt_ + half; j += 8) {
            const int s0 = slds[wid][j + 0];
            const int s1 = slds[wid][j + 2];
            const int s2 = slds[wid][j + 4];
            const int s3 = slds[wid][j + 6];
            const float w0 = wlds[wid][j + 0];
            const float w1 = wlds[wid][j + 2];
            const float w2 = wlds[wid][j + 4];
            const float w3 = wlds[wid][j + 6];
            const unsigned int g0 = *(const unsigned short*)&h8[((size_t)s0 << 6) + loff];
            const unsigned int g1 = *(const unsigned short*)&h8[((size_t)s1 << 6) + loff];
            const unsigned int g2 = *(const unsigned short*)&h8[((size_t)s2 << 6) + loff];
            const unsigned int g3 = *(const unsigned short*)&h8[((size_t)s3 << 6) + loff];
            float vl, vh;
            fp8x2_to_f32(g0, vl, vh); accx += w0 * vl; accy += w0 * vh;
            fp8x2_to_f32(g1, vl, vh); accx += w1 * vl; accy += w1 * vh;
            fp8x2_to_f32(g2, vl, vh); accx += w2 * vl; accy += w2 * vh;
            fp8x2_to_f32(g3, vl, vh); accx += w3 * vl; accy += w3 * vh;
            den += (w0 + w1) + (w2 + w3);
        }
        for (; j < cnt_; j += 2) {
            const int s = slds[wid][j];
            const float w = wlds[wid][j];
            const unsigned int g = *(const unsigned short*)&h8[((size_t)s << 6) + loff];
            float vl, vh;
            fp8x2_to_f32(g, vl, vh);
            accx += w * vl;
            accy += w * vh;
            den += w;
        }
    }
    accx += __shfl_xor(accx, 32);
    accy += __shfl_xor(accy, 32);
    den  += __shfl_xor(den, 32);
    if (half == 0) {
        if (valid) {
            const float inv = 1.0f / (den + 1e-16f);
            sOut[wid][l32] = (float2){accx * inv + bias[loff], accy * inv + bias[loff + 1]};
        } else {
            sOut[wid][l32] = (float2){0.0f, 0.0f};
        }
        if (l32 == 0) sG[wid] = valid ? batch[n] : -1;
    }
    __syncthreads();
    const int p = blockIdx.x & 63;
    if (wid == 0 && half == 0) {
        const int g0 = sG[0], g1 = sG[1], g2 = sG[2], g3 = sG[3];
        if (g0 >= 0 && g1 == g0 && g2 == g0 && g3 == g0) {
            const float2 s0 = sOut[0][l32], s1 = sOut[1][l32];
            const float2 s2 = sOut[2][l32], s3 = sOut[3][l32];
            float* base = pooledP + ((size_t)p * G + g0) * 64;
            atomicAdd(&base[loff],     (s0.x + s1.x) + (s2.x + s3.x));
            atomicAdd(&base[loff + 1], (s0.y + s1.y) + (s2.y + s3.y));
            if (l32 == 0) atomicAdd(&cntP[p * G + g0], 4.0f);
        } else {
            #pragma unroll
            for (int w = 0; w < 4; w++) {
                const int g = sG[w];
                if (g >= 0) {
                    const float2 s = sOut[w][l32];
                    float* base = pooledP + ((size_t)p * G + g) * 64;
                    atomicAdd(&base[loff], s.x);
                    atomicAdd(&base[loff + 1], s.y);
                    if (l32 == 0) atomicAdd(&cntP[p * G + g], 1.0f);
                }
            }
        }
    }
}

// ------------- decoder head: one block per graph (reduces 64 pool partitions first) -------------
__global__ __launch_bounds__(256) void final_kernel(
        const float* __restrict__ pooledP, const float* __restrict__ cntP,
        const float* __restrict__ gf, const float* __restrict__ Wg,
        const float* __restrict__ bg, const float* __restrict__ Wd1,
        const float* __restrict__ bd1, const float* __restrict__ gamma,
        const float* __restrict__ beta, const float* __restrict__ Wd2,
        const float* __restrict__ bd2, float* __restrict__ out, int G) {
    const int g = blockIdx.x;
    const int tid = threadIdx.x;
    const int lane = tid & 63;
    const int wave = tid >> 6;
    __shared__ float sPart[4][64];
    __shared__ float sCntTot;
    __shared__ float spg[128];
    __shared__ float sz[64];
    __shared__ float wred[8];

    {   // partition reduce: wave pg sums partitions [pg*16, pg*16+16)
        const int c = lane;
        const int pg = wave;
        float a = 0.0f;
        #pragma unroll
        for (int p = 0; p < 16; p++)
            a += pooledP[((size_t)(pg * 16 + p) * G + g) * 64 + c];
        sPart[pg][c] = a;
        if (pg == 1) {
            float cv = cntP[c * G + g];
            #pragma unroll
            for (int off = 32; off > 0; off >>= 1) cv += __shfl_xor(cv, off);
            if (c == 0) sCntTot = cv;
        }
    }
    __syncthreads();
    if (tid < 64) {
        spg[tid] = (sPart[0][tid] + sPart[1][tid] + sPart[2][tid] + sPart[3][tid])
                   / fmaxf(sCntTot, 1.0f);
    } else if (tid < 128) {
        int c = tid - 64;
        float v = bg[c];
        #pragma unroll
        for (int k = 0; k < 4; k++) v += gf[g * 4 + k] * Wg[k * 64 + c];
        spg[64 + c] = fmaxf(v, 0.0f);
    }
    __syncthreads();
    if (tid < 64) {
        float v = bd1[tid];
        #pragma unroll 8
        for (int k = 0; k < 128; k++) v += spg[k] * Wd1[k * 64 + tid];
        v = v * gamma[tid] + beta[tid];
        sz[tid] = fmaxf(v, 0.0f);
    }
    __syncthreads();
    float v = bd2[tid];
    #pragma unroll 8
    for (int k = 0; k < 64; k++) v += sz[k] * Wd2[k * 256 + tid];
    float m = v;
    #pragma unroll
    for (int off = 32; off > 0; off >>= 1) m = fmaxf(m, __shfl_xor(m, off));
    if (lane == 0) wred[wave] = m;
    __syncthreads();
    float M = fmaxf(fmaxf(wred[0], wred[1]), fmaxf(wred[2], wred[3]));
    float e = expf(v - M);
    float s = e;
    #pragma unroll
    for (int off = 32; off > 0; off >>= 1) s += __shfl_xor(s, off);
    if (lane == 0) wred[4 + wave] = s;
    __syncthreads();
    float S = (wred[4] + wred[5]) + (wred[6] + wred[7]);
    out[g * 256 + tid] = e / S;
}

extern "C" void kernel_launch(void* const* d_in, const int* in_sizes, int n_in,
                              void* d_out, int out_size, void* d_ws, size_t ws_size,
                              hipStream_t stream) {
    const float* x     = (const float*)d_in[0];
    const int*   ei    = (const int*)  d_in[1];
    const int*   batch = (const int*)  d_in[2];
    const float* gf    = (const float*)d_in[3];
    const float* W_enc = (const float*)d_in[4];
    const float* b_enc = (const float*)d_in[5];
    const float* W1  = (const float*)d_in[6];
    const float* as1 = (const float*)d_in[7];
    const float* ad1 = (const float*)d_in[8];
    const float* b1  = (const float*)d_in[9];
    const float* W2  = (const float*)d_in[10];
    const float* as2 = (const float*)d_in[11];
    const float* ad2 = (const float*)d_in[12];
    const float* b2  = (const float*)d_in[13];
    const float* W3  = (const float*)d_in[14];
    const float* as3 = (const float*)d_in[15];
    const float* ad3 = (const float*)d_in[16];
    const float* b3  = (const float*)d_in[17];
    const float* Wg  = (const float*)d_in[18];
    const float* bg  = (const float*)d_in[19];
    const float* Wd1 = (const float*)d_in[20];
    const float* bd1 = (const float*)d_in[21];
    const float* gm  = (const float*)d_in[22];
    const float* bt  = (const float*)d_in[23];
    const float* Wd2 = (const float*)d_in[24];
    const float* bd2 = (const float*)d_in[25];

    const int N  = in_sizes[2];
    const int E  = in_sizes[1] / 2;
    const int G  = in_sizes[3] / 4;
    const int Et = E + N;
    const int NB = (N + 127) >> 7;               // dst-buckets of 128 nodes (<=1024)

    unsigned short* h16a = (unsigned short*)d_ws;                // slot: conv2 fp8 table [N,256]B
    unsigned short* h16b = h16a + (size_t)N * 256;               // [N,256]: aggX [N,128] early, then conv2 agg out
    unsigned short* h1_16 = h16b + (size_t)N * 256;              // slot: conv3 fp8 table [N,64]B
    unsigned short* x16  = h1_16 + (size_t)N * 64;               // slot: x fp8 table [N,32]B
    unsigned short* Wc1t = x16 + (size_t)N * 32;                 // [4][64][32]
    unsigned short* Wt2  = Wc1t + 4 * 64 * 32;                   // [256,256]
    unsigned short* Wt3  = Wt2 + 256 * 256;                      // [64,256]
    float* bc1    = (float*)(Wt3 + 64 * 256);                    // [256]
    float* a_s    = bc1 + 256;                                   // [N,4]
    float* a_d    = a_s + (size_t)N * 4;                         // [N,4]
    float* a_s3   = a_d + (size_t)N * 4;                         // [N]
    float* a_d3   = a_s3 + N;                                    // [N]
    float* u1s    = a_d3 + N;                                    // [64,4]
    float* u1d    = u1s + 256;                                   // [64,4]
    float* u3s    = u1d + 256;                                   // [256]
    float* u3d    = u3s + 256;                                   // [256]
    float* pooledP = u3d + 256;                                  // [64][G][64]
    float* cntP   = pooledP + (size_t)64 * G * 64;               // [64][G]
    int*   offsets = (int*)(cntP + 64 * G);                      // [N+1]
    int*   srcS    = offsets + (N + 1);                          // [Et]
    int*   counts  = srcS + Et;                                  // [N]
    int*   blockSums = counts + N;                               // [cdiv(N,1024)]
    int*   bucketCnt = blockSums + ((N + 1023) / 1024);          // [NB+1]
    int*   bucketOff = bucketCnt + (NB + 1);                     // [NB+1]
    int*   bucketCur = bucketOff + (NB + 1);                     // [NB]
    uint2* bucketBuf = (uint2*)(((size_t)(bucketCur + NB) + 7) & ~(size_t)7);   // [Et]

    unsigned char* h8a  = (unsigned char*)h16a;                  // fp8 conv2 gather table view
    unsigned char* h1_8 = (unsigned char*)h1_16;                 // fp8 conv3 gather table view
    unsigned char* x8   = (unsigned char*)x16;                   // fp8 x gather table view

    dim3 blk(256);
    auto cdiv = [](int a, int b) { return (a + b - 1) / b; };
    const int ebBlocks = cdiv(Et, 4096);
    const int rowBlocks = cdiv(N, 64);
    const int nScanBlocks = cdiv(N, 1024);
    const int zc = cdiv(N, 256);
    const int z2 = cdiv(64 * G * 64, 256);

    // ---------------- prep (folded weights + u-vectors + zero-init) + CSR build ----------------
    prep_kernel<<<355 + zc + z2, blk, 0, stream>>>(W_enc, b_enc, W1, W2, W3, as1, ad1, b1,
                                                   as3, ad3, Wc1t, bc1, Wt2, Wt3,
                                                   u1s, u1d, u3s, u3d,
                                                   counts, pooledP, cntP, bucketCnt,
                                                   N, G, zc, NB);
    edge_hist_kernel<<<ebBlocks, blk, 0, stream>>>(ei, counts, bucketCnt, E, Et, NB);
    scan_blocks<<<nScanBlocks, 1024, 0, stream>>>(counts, blockSums, N);
    scan_add2<<<cdiv(N + 1, 256), blk, 0, stream>>>(counts, blockSums, nScanBlocks,
                                                    offsets, N, Et);
    bucket_scan<<<1, 1024, 0, stream>>>(bucketCnt, bucketOff, bucketCur, NB, Et);
    bucket_scatter<<<ebBlocks, blk, 0, stream>>>(ei, bucketCur, bucketBuf, E, Et, NB);
    bucket_sort<<<NB, blk, 0, stream>>>(bucketBuf, bucketOff, offsets, srcS);

    // conv1 scores from fp32 x + x->fp8 gather table
    score_x<<<cdiv(N, 32), blk, 0, stream>>>(x, W_enc, b_enc, u1s, u1d, x8, a_s, a_d, N);

    // ---------------- conv1 aggregate (fp8 x) -> fused conv1+conv2 GEMM (fp8 table out) ----------------
    gat_agg_x32<<<cdiv(N, 4), blk, 0, stream>>>(offsets, srcS, (const float4*)a_s,
                                                (const float4*)a_d, x8, h16b, N);
    gemm_c12<<<rowBlocks, blk, 0, stream>>>(h16b, Wc1t, bc1, Wt2, as2, ad2,
                                            a_s, a_d, h8a, N);

    // ---------------- conv2 aggregate over fp8 table (+conv3 scores fused) ----------------
    gat_fused4<<<cdiv(N, 4), blk, 0, stream>>>(offsets, srcS, (const float4*)a_s,
                                               (const float4*)a_d, h8a, b2,
                                               u3s, u3d, a_s3, a_d3, h16b, N);

    // ---------------- conv3: GEMM (fp8 table out) -> aggregate + partitioned pool ----------------
    gemm_c3<<<rowBlocks, blk, 0, stream>>>(h16b, Wt3, h1_8, N);
    gat_fused1<<<cdiv(N, 4), blk, 0, stream>>>(offsets, srcS, a_s3, a_d3, h1_8, b3,
                                               batch, pooledP, cntP, N, G);

    // ---------------- decoder head ----------------
    final_kernel<<<G, blk, 0, stream>>>(pooledP, cntP, gf, Wg, bg, Wd1, bd1, gm, bt, Wd2, bd2,
                                        (float*)d_out, G);
}

// Round 11
// 348.880 us; speedup vs baseline: 1.3236x; 1.0149x over previous
//
#include <hip/hip_runtime.h>
#include <math.h>

#define NEG_SLOPE 0.2f
#define LOG2E 1.4426950408889634f
#define BSH 7                      // 128 nodes per dst-bucket

typedef __attribute__((ext_vector_type(8))) short short8;   // 8 bf16 = 4 VGPRs
typedef __attribute__((ext_vector_type(4))) float f32x4;    // MFMA acc
typedef __attribute__((ext_vector_type(2))) float f32x2;
typedef long long i64;

#if __has_builtin(__builtin_amdgcn_cvt_pk_f32_fp8) && __has_builtin(__builtin_amdgcn_cvt_pk_fp8_f32)
#define FP8_HW 1
#else
#define FP8_HW 0
#endif

__device__ inline float b2f_lo(unsigned int u) {
    union { unsigned int i; float f; } x; x.i = u << 16; return x.f;
}
__device__ inline float b2f_hi(unsigned int u) {
    union { unsigned int i; float f; } x; x.i = u & 0xFFFF0000u; return x.f;
}
__device__ inline unsigned short f2b(float f) {
    union { float f; unsigned int i; } u; u.f = f;
    unsigned int r = u.i + 0x7FFF + ((u.i >> 16) & 1);   // round-to-nearest-even
    return (unsigned short)(r >> 16);
}

// ---- OCP e4m3 helpers (HW cvt on gfx950; exact manual fallback) ----
__device__ inline float fp8_decode1(unsigned int b) {
    unsigned int e = (b >> 3) & 15, m = b & 7;
    union { unsigned int i; float f; } u;
    if (e == 0) u.f = (float)m * 0.001953125f;          // subnormal: m * 2^-9
    else u.i = ((e + 120) << 23) | (m << 20);            // (1+m/8) * 2^(e-7)
    if (b & 0x80) u.f = -u.f;
    return u.f;
}
__device__ inline void fp8x4_to_f32(unsigned int g, float& v0, float& v1,
                                    float& v2, float& v3) {
#if FP8_HW
    f32x2 lo = __builtin_amdgcn_cvt_pk_f32_fp8((int)g, false);   // bytes 0,1
    f32x2 hi = __builtin_amdgcn_cvt_pk_f32_fp8((int)g, true);    // bytes 2,3
    v0 = lo[0]; v1 = lo[1]; v2 = hi[0]; v3 = hi[1];
#else
    v0 = fp8_decode1(g & 255);         v1 = fp8_decode1((g >> 8) & 255);
    v2 = fp8_decode1((g >> 16) & 255); v3 = fp8_decode1((g >> 24) & 255);
#endif
}
__device__ inline void fp8x2_to_f32(unsigned int g2, float& v0, float& v1) {
#if FP8_HW
    f32x2 lo = __builtin_amdgcn_cvt_pk_f32_fp8((int)(g2 & 0xFFFF), false);
    v0 = lo[0]; v1 = lo[1];
#else
    v0 = fp8_decode1(g2 & 255);
    v1 = fp8_decode1((g2 >> 8) & 255);
#endif
}
__device__ inline unsigned char f32_to_fp8(float f) {
#if FP8_HW
    return (unsigned char)(__builtin_amdgcn_cvt_pk_fp8_f32(f, f, 0, false) & 0xFF);
#else
    union { float f; unsigned int i; } u; u.f = f;
    unsigned int s = (u.i >> 24) & 0x80;
    float a = fabsf(f);
    if (a < 0.015625f) {                                 // subnormal band
        int m = (int)rintf(a * 512.0f);
        if (m > 7) return (unsigned char)(s | 0x08);
        return (unsigned char)(s | m);
    }
    if (a >= 448.0f) return (unsigned char)(s | 0x7E);
    int e = (int)((u.i >> 23) & 0xFF) - 127;
    union { unsigned int i; float f; } sc; sc.i = (unsigned int)(127 + 3 - e) << 23;
    int q = (int)rintf(a * sc.f);                        // in [8,16]
    if (q >= 16) { q = 8; e += 1; }
    return (unsigned char)(s | ((unsigned int)(e + 7) << 3) | (unsigned int)(q - 8));
#endif
}

// ---------------- prep: folded conv1 weights, u1/u3 vectors, Wt2/Wt3 (fp8), ALL zero-init ----------------
__global__ void prep_kernel(const float* __restrict__ W_enc, const float* __restrict__ b_enc,
                            const float* __restrict__ W1, const float* __restrict__ W2,
                            const float* __restrict__ W3, const float* __restrict__ as1,
                            const float* __restrict__ ad1, const float* __restrict__ b1,
                            const float* __restrict__ as3, const float* __restrict__ ad3,
                            unsigned short* __restrict__ Wc1t, float* __restrict__ bc1,
                            unsigned char* __restrict__ Wt2, unsigned char* __restrict__ Wt3,
                            float* __restrict__ u1s, float* __restrict__ u1d,
                            float* __restrict__ u3s, float* __restrict__ u3d,
                            int* __restrict__ counts, float* __restrict__ pooledP,
                            float* __restrict__ cntP, int* __restrict__ bucketCnt,
                            int N, int G, int zc, int NB) {
    const int b = blockIdx.x;
    const int t = threadIdx.x;
    if (b < 32) {
        int i = b * 256 + t;                       // 8192 values
        int h = i >> 11, rem = i & 2047, o = rem >> 5, j = rem & 31;
        float s = 0.0f;
        for (int k = 0; k < 64; k++)
            s += W_enc[j * 64 + k] * W1[k * 256 + h * 64 + o];
        Wc1t[i] = f2b(s);
    } else if (b == 32) {
        float s = b1[t];
        for (int k = 0; k < 64; k++) s += b_enc[k] * W1[k * 256 + t];
        bc1[t] = s;
    } else if (b == 33) {
        int k = t >> 2, h = t & 3;
        float s = 0.0f, d = 0.0f;
        for (int c = 0; c < 64; c++) {
            float w = W1[k * 256 + h * 64 + c];
            s += w * as1[h * 64 + c];
            d += w * ad1[h * 64 + c];
        }
        u1s[k * 4 + h] = s;
        u1d[k * 4 + h] = d;
    } else if (b == 34) {
        float s = 0.0f, d = 0.0f;
        for (int o = 0; o < 64; o++) {
            float w = W3[t * 64 + o];
            s += w * as3[o];
            d += w * ad3[o];
        }
        u3s[t] = s; u3d[t] = d;
    } else if (b < 35 + 256) {
        int i = (b - 35) * 256 + t;                // K=256, M=256
        int k = i >> 8, m = i & 255;
        Wt2[(size_t)m * 256 + k] = f32_to_fp8(W2[i]);
    } else if (b < 35 + 256 + 64) {
        int i = (b - 291) * 256 + t;               // K=256, M=64
        int k = i >> 6, m = i & 63;
        Wt3[(size_t)m * 256 + k] = f32_to_fp8(W3[i]);
    } else if (b < 355 + zc) {
        int i = (b - 355) * 256 + t;
        if (i < N) counts[i] = 0;
    } else {
        int i = (b - 355 - zc) * 256 + t;
        if (i < 64 * G * 64) pooledP[i] = 0.0f;    // [64 partitions][G][64]
        if (i < 64 * G) cntP[i] = 0.0f;            // [64 partitions][G]
        if (i <= NB) bucketCnt[i] = 0;
    }
}

// ---------------- score_x: conv1 scores from fp32 x + x -> fp8 table ----------------
__global__ __launch_bounds__(256) void score_x(
        const float* __restrict__ x, const float* __restrict__ W_enc,
        const float* __restrict__ b_enc,
        const float* __restrict__ u1s, const float* __restrict__ u1d,
        unsigned char* __restrict__ x8, float* __restrict__ a_s,
        float* __restrict__ a_d, int N) {
    __shared__ float sUs[32][4], sUd[32][4], sC[8];
    __shared__ float sX[32][33];
    const int t = threadIdx.x;
    if (t < 128) {
        int j = t >> 2, h = t & 3;
        float s = 0.0f, d = 0.0f;
        for (int k = 0; k < 64; k++) {
            float w = W_enc[j * 64 + k];
            s += w * u1s[k * 4 + h];
            d += w * u1d[k * 4 + h];
        }
        sUs[j][h] = s; sUd[j][h] = d;
    } else if (t < 136) {
        int hh = t - 128;                           // 0..3 -> s, 4..7 -> d
        const float* u = (hh < 4) ? u1s : u1d;
        int h = hh & 3;
        float c = 0.0f;
        for (int k = 0; k < 64; k++) c += b_enc[k] * u[k * 4 + h];
        sC[hh] = c;
    }
    const int n0 = blockIdx.x * 32;
    const int row = t >> 3, col = (t & 7) << 2;
    float4 xv = {0, 0, 0, 0};
    if (n0 + row < N) xv = *(const float4*)&x[(size_t)(n0 + row) * 32 + col];
    sX[row][col + 0] = xv.x; sX[row][col + 1] = xv.y;
    sX[row][col + 2] = xv.z; sX[row][col + 3] = xv.w;
    __syncthreads();
    const int ni = t >> 3, oi = t & 7, h = oi & 3;
    const bool isS = oi < 4;
    float acc = sC[oi];
    #pragma unroll 8
    for (int j = 0; j < 32; j++) acc += sX[ni][j] * (isS ? sUs[j][h] : sUd[j][h]);
    if (n0 + ni < N) {
        float* out = isS ? a_s : a_d;
        out[(size_t)(n0 + ni) * 4 + h] = acc * LOG2E;
    }
    if (n0 + row < N) {
        unsigned int o = (unsigned int)f32_to_fp8(xv.x)
                       | ((unsigned int)f32_to_fp8(xv.y) << 8)
                       | ((unsigned int)f32_to_fp8(xv.z) << 16)
                       | ((unsigned int)f32_to_fp8(xv.w) << 24);
        *(unsigned int*)&x8[(size_t)(n0 + row) * 32 + col] = o;
    }
}

// ---------------- FUSED conv1+conv2 GEMM: phase1 bf16 MFMA -> sH fp8; phase2 fp8 MFMA
// (Wt2 fp8, LDS ~39KB -> 4 blocks/CU). Scores fp32. fp8 table out. ----------------
__global__ __launch_bounds__(256) void gemm_c12(
        const unsigned short* __restrict__ aggX,   // [N,128] bf16
        const unsigned short* __restrict__ Wc1t,   // bf16
        const float* __restrict__ bc1,
        const unsigned char* __restrict__ Wt2,     // [256][256] fp8 B^T
        const float* __restrict__ att_s,
        const float* __restrict__ att_d,
        float* __restrict__ a_s, float* __restrict__ a_d,
        unsigned char* __restrict__ C8,            // [N,256] fp8 conv2 gather table
        int Nrows) {
    __shared__ unsigned char sH8[64][264];         // h2 tile, fp8
    __shared__ unsigned short sB[256][40];         // phase1 staging; byte-aliased in phase2
    __shared__ float sSD[64][4][2];
    const int tid = threadIdx.x;
    const int wave = tid >> 6;
    const int lane = tid & 63;
    const int quad = lane >> 4;
    const int l16 = lane & 15;
    const int row0 = blockIdx.x * 64;
    const int sr = tid >> 2;
    const int sk = (tid & 3) << 3;
    unsigned char* sB8 = (unsigned char*)sB;       // row stride 80 bytes

    // ---- phase 1: conv1 (folded, K=32, bf16 MFMA) per head -> sH8 fp8 ----
    #pragma unroll
    for (int h = 0; h < 4; h++) {
        __syncthreads();
        {
            int r = row0 + sr;
            uint4 z = {0,0,0,0};
            *(uint4*)&sB[sr][sk] = (r < Nrows)
                ? *(const uint4*)&aggX[(size_t)r * 128 + h * 32 + sk] : z;
            *(uint4*)&sB[64 + sr][sk] = *(const uint4*)&Wc1t[(size_t)(h * 64 + sr) * 32 + sk];
        }
        __syncthreads();
        short8 bf = *(const short8*)&sB[64 + wave * 16 + l16][quad * 8];
        const int col = h * 64 + wave * 16 + l16;
        const float bb = bc1[col];
        #pragma unroll
        for (int i = 0; i < 4; i++) {
            short8 af = *(const short8*)&sB[i * 16 + l16][quad * 8];
            f32x4 acc = __builtin_amdgcn_mfma_f32_16x16x32_bf16(af, bf, (f32x4){0,0,0,0}, 0, 0, 0);
            #pragma unroll
            for (int r = 0; r < 4; r++) {
                float v = acc[r] + bb;
                v = (v > 0.0f) ? v : expm1f(v);        // ELU
                sH8[i * 16 + quad * 4 + r][col] = f32_to_fp8(v);
            }
        }
    }

    // ---- phase 2: conv2 GEMM (fp8 MFMA), A from sH8, B = Wt2 fp8, BN=256 ----
    f32x4 acc2[4][4];
    #pragma unroll
    for (int i = 0; i < 4; i++)
        #pragma unroll
        for (int j = 0; j < 4; j++) acc2[i][j] = (f32x4){0,0,0,0};

    for (int kt = 0; kt < 256; kt += 32) {
        __syncthreads();
        {
            const unsigned char* src = &Wt2[(size_t)tid * 256 + kt];
            *(uint4*)&sB8[tid * 80]      = *(const uint4*)src;
            *(uint4*)&sB8[tid * 80 + 16] = *(const uint4*)(src + 16);
        }
        __syncthreads();
        i64 bf2[4];
        #pragma unroll
        for (int j = 0; j < 4; j++)
            bf2[j] = *(const i64*)&sB8[(wave * 64 + j * 16 + l16) * 80 + quad * 8];
        #pragma unroll
        for (int i = 0; i < 4; i++) {
            i64 af = *(const i64*)&sH8[i * 16 + l16][kt + quad * 8];
            #pragma unroll
            for (int j = 0; j < 4; j++)
                acc2[i][j] = __builtin_amdgcn_mfma_f32_16x16x32_fp8_fp8(af, bf2[j], acc2[i][j], 0, 0, 0);
        }
    }

    // ---- conv2 scores (fp32, before fp8 encode) ----
    {
        for (int t = tid; t < 512; t += 256) ((float*)sSD)[t] = 0.0f;
        __syncthreads();
        float avs[4], avd[4];
        #pragma unroll
        for (int j = 0; j < 4; j++) {
            int c = wave * 64 + j * 16 + l16;
            avs[j] = att_s[c];
            avd[j] = att_d[c];
        }
        #pragma unroll
        for (int i = 0; i < 4; i++) {
            float ps[4] = {0,0,0,0}, pd[4] = {0,0,0,0};
            #pragma unroll
            for (int j = 0; j < 4; j++)
                #pragma unroll
                for (int r = 0; r < 4; r++) {
                    ps[r] += acc2[i][j][r] * avs[j];
                    pd[r] += acc2[i][j][r] * avd[j];
                }
            #pragma unroll
            for (int off = 1; off < 16; off <<= 1)
                #pragma unroll
                for (int r = 0; r < 4; r++) {
                    ps[r] += __shfl_xor(ps[r], off);
                    pd[r] += __shfl_xor(pd[r], off);
                }
            if (l16 == 0) {
                #pragma unroll
                for (int r = 0; r < 4; r++) {
                    atomicAdd(&sSD[i * 16 + quad * 4 + r][wave][0], ps[r]);
                    atomicAdd(&sSD[i * 16 + quad * 4 + r][wave][1], pd[r]);
                }
            }
        }
        __syncthreads();
        {
            int row = tid & 63, hb = tid >> 6;
            int r = row0 + row;
            if (r < Nrows) {
                a_s[r * 4 + hb] = sSD[row][hb][0] * LOG2E;
                a_d[r * 4 + hb] = sSD[row][hb][1] * LOG2E;
            }
        }
    }
    // ---- C write (fp8 e4m3) ----
    #pragma unroll
    for (int i = 0; i < 4; i++) {
        #pragma unroll
        for (int j = 0; j < 4; j++) {
            int col = wave * 64 + j * 16 + l16;
            #pragma unroll
            for (int r = 0; r < 4; r++) {
                int row = row0 + i * 16 + quad * 4 + r;
                if (row < Nrows) C8[(size_t)row * 256 + col] = f32_to_fp8(acc2[i][j][r]);
            }
        }
    }
}

// ---------------- conv3 GEMM (all-fp8): C8[N,64] = A8[N,256] @ Wt3_8^T ----------------
__global__ __launch_bounds__(256) void gemm_c3(const unsigned char* __restrict__ A8,
                                               const unsigned char* __restrict__ Bt8,
                                               unsigned char* __restrict__ C8,
                                               int Nrows) {
    __shared__ unsigned char sA8[64][40];
    __shared__ unsigned char sB8[64][40];
    const int tid = threadIdx.x;
    const int wave = tid >> 6;
    const int lane = tid & 63;
    const int quad = lane >> 4;
    const int l16 = lane & 15;
    const int row0 = blockIdx.x * 64;

    f32x4 acc[4];
    #pragma unroll
    for (int i = 0; i < 4; i++) acc[i] = (f32x4){0,0,0,0};

    for (int kt = 0; kt < 256; kt += 32) {
        __syncthreads();
        if (tid < 128) {
            int r = tid >> 1, o = (tid & 1) << 4;
            int row = row0 + r;
            uint4 z = {0,0,0,0};
            *(uint4*)&sA8[r][o] = (row < Nrows)
                ? *(const uint4*)&A8[(size_t)row * 256 + kt + o] : z;
        } else {
            int t2 = tid - 128;
            int r = t2 >> 1, o = (t2 & 1) << 4;
            *(uint4*)&sB8[r][o] = *(const uint4*)&Bt8[(size_t)r * 256 + kt + o];
        }
        __syncthreads();
        i64 bf = *(const i64*)&sB8[wave * 16 + l16][quad * 8];
        #pragma unroll
        for (int i = 0; i < 4; i++) {
            i64 af = *(const i64*)&sA8[i * 16 + l16][quad * 8];
            acc[i] = __builtin_amdgcn_mfma_f32_16x16x32_fp8_fp8(af, bf, acc[i], 0, 0, 0);
        }
    }
    const int col = wave * 16 + l16;
    #pragma unroll
    for (int i = 0; i < 4; i++) {
        #pragma unroll
        for (int r = 0; r < 4; r++) {
            int row = row0 + i * 16 + quad * 4 + r;
            if (row < Nrows) C8[(size_t)row * 64 + col] = f32_to_fp8(acc[i][r]);
        }
    }
}

// ------------- CSR build: node hist + dst-bucket hist (fused, LDS-aggregated buckets) -------------
__global__ __launch_bounds__(256) void edge_hist_kernel(const int* __restrict__ ei,
                                                        int* __restrict__ counts,
                                                        int* __restrict__ bucketCnt,
                                                        int E, int Et, int NB) {
    __shared__ int lhist[1024];
    const int tid = threadIdx.x;
    for (int b = tid; b < NB; b += 256) lhist[b] = 0;
    __syncthreads();
    const int base = blockIdx.x * 4096;
    #pragma unroll
    for (int k = 0; k < 16; k++) {
        int e = base + k * 256 + tid;
        if (e < Et) {
            int d = (e < E) ? ei[E + e] : e - E;
            atomicAdd(&counts[d], 1);
            atomicAdd(&lhist[d >> BSH], 1);
        }
    }
    __syncthreads();
    for (int b = tid; b < NB; b += 256) {
        int h = lhist[b];
        if (h > 0) atomicAdd(&bucketCnt[b], h);
    }
}

__global__ __launch_bounds__(1024) void scan_blocks(int* __restrict__ counts,
                                                    int* __restrict__ blockSums, int N) {
    __shared__ int wsum[16];
    const int tid = threadIdx.x;
    const int lane = tid & 63;
    const int wave = tid >> 6;
    int i = blockIdx.x * 1024 + tid;
    int v = (i < N) ? counts[i] : 0;
    int s = v;
    #pragma unroll
    for (int off = 1; off < 64; off <<= 1) {
        int t = __shfl_up(s, off);
        if (lane >= off) s += t;
    }
    if (lane == 63) wsum[wave] = s;
    __syncthreads();
    if (wave == 0 && lane < 16) {
        int ws = wsum[lane];
        #pragma unroll
        for (int off = 1; off < 16; off <<= 1) {
            int t = __shfl_up(ws, off);
            if (lane >= off) ws += t;
        }
        wsum[lane] = ws;
    }
    __syncthreads();
    int waveOff = (wave > 0) ? wsum[wave - 1] : 0;
    int incl = s + waveOff;
    if (i < N) counts[i] = incl - v;
    if (tid == 1023) blockSums[blockIdx.x] = incl;
}

__global__ void scan_add2(const int* __restrict__ excl, const int* __restrict__ blockSums,
                          int nb, int* __restrict__ offsets, int N, int Et) {
    __shared__ int sbs[64];
    if (threadIdx.x < 64) {
        int lane = threadIdx.x;
        int v = (lane < nb) ? blockSums[lane] : 0;
        int s = v;
        #pragma unroll
        for (int off = 1; off < 64; off <<= 1) {
            int t = __shfl_up(s, off);
            if (lane >= off) s += t;
        }
        sbs[lane] = s - v;                 // exclusive
    }
    __syncthreads();
    int i = blockIdx.x * 256 + threadIdx.x;
    if (i < N) offsets[i] = excl[i] + sbs[i >> 10];
    if (i == N) offsets[N] = Et;
}

// ------------- bucket scan: exclusive prefix over NB buckets (single block) -------------
__global__ __launch_bounds__(1024) void bucket_scan(const int* __restrict__ bucketCnt,
                                                    int* __restrict__ bucketOff,
                                                    int* __restrict__ bucketCur,
                                                    int NB, int Et) {
    __shared__ int s[1024];
    const int tid = threadIdx.x;
    int v = (tid < NB) ? bucketCnt[tid] : 0;
    s[tid] = v;
    __syncthreads();
    #pragma unroll
    for (int off = 1; off < 1024; off <<= 1) {
        int t = (tid >= off) ? s[tid - off] : 0;
        __syncthreads();
        s[tid] += t;
        __syncthreads();
    }
    if (tid < NB) {
        int ex = s[tid] - v;               // exclusive
        bucketOff[tid] = ex;
        bucketCur[tid] = ex;
    }
    if (tid == 0) bucketOff[NB] = Et;
}

// ------------- bucket scatter: edges -> bucketBuf (block-aggregated base claims) -------------
__global__ __launch_bounds__(256) void bucket_scatter(const int* __restrict__ ei,
                                                      int* __restrict__ bucketCur,
                                                      uint2* __restrict__ bucketBuf,
                                                      int E, int Et, int NB) {
    __shared__ int lhist[1024];
    __shared__ int lbase[1024];
    const int tid = threadIdx.x;
    for (int b = tid; b < NB; b += 256) lhist[b] = 0;
    __syncthreads();
    const int base = blockIdx.x * 4096;
    int sv[16], dv[16];
    #pragma unroll
    for (int k = 0; k < 16; k++) {
        int e = base + k * 256 + tid;
        if (e < Et) {
            int ss, dd;
            if (e < E) { ss = ei[e]; dd = ei[E + e]; } else { ss = dd = e - E; }
            sv[k] = ss; dv[k] = dd;
            atomicAdd(&lhist[dd >> BSH], 1);
        } else dv[k] = -1;
    }
    __syncthreads();
    for (int b = tid; b < NB; b += 256) {
        int h = lhist[b];
        lbase[b] = (h > 0) ? atomicAdd(&bucketCur[b], h) : 0;
    }
    __syncthreads();
    // reuse lhist as rank counters
    for (int b = tid; b < NB; b += 256) lhist[b] = 0;
    __syncthreads();
    #pragma unroll
    for (int k = 0; k < 16; k++) {
        if (dv[k] >= 0) {
            int b = dv[k] >> BSH;
            int r = atomicAdd(&lhist[b], 1);
            bucketBuf[lbase[b] + r] = (uint2){(unsigned int)sv[k], (unsigned int)dv[k]};
        }
    }
}

// ------------- bucket-local sort: one block per bucket; writes srcS within a ~9KB window -------------
__global__ __launch_bounds__(256) void bucket_sort(const uint2* __restrict__ bucketBuf,
                                                   const int* __restrict__ bucketOff,
                                                   const int* __restrict__ offsets,
                                                   int* __restrict__ srcS) {
    __shared__ int cnt[128];
    const int tid = threadIdx.x;
    const int b = blockIdx.x;
    if (tid < 128) cnt[tid] = 0;
    __syncthreads();
    const int node0 = b << BSH;
    const int s0 = bucketOff[b], s1 = bucketOff[b + 1];
    for (int i = s0 + tid; i < s1; i += 256) {
        uint2 e = bucketBuf[i];
        int dl = (int)e.y - node0;
        int r = atomicAdd(&cnt[dl], 1);
        srcS[offsets[e.y] + r] = (int)e.x;
    }
}

// ------------- conv1 aggregate of RAW x (32-dim fp8, 32 B/row, 1.6 MB table) -------------
__global__ __launch_bounds__(256) void gat_agg_x32(
        const int* __restrict__ offsets, const int* __restrict__ srcS,
        const float4* __restrict__ a_s4, const float4* __restrict__ a_d4,
        const unsigned char* __restrict__ x8,      // [N,32] fp8
        unsigned short* __restrict__ aggX,         // [N,128]
        int N) {
    __shared__ float4 wlds[4][64];
    __shared__ int slds[4][64];
    const int wid = threadIdx.x >> 6;
    const int n = blockIdx.x * 4 + wid;
    if (n >= N) return;
    const int lane = threadIdx.x & 63;
    const int q = lane >> 4;
    const int l16 = lane & 15;
    const int start = offsets[n], end = offsets[n + 1];
    const float4 ad = a_d4[n];
    float2 acc0 = {0,0}, acc1 = {0,0}, acc2 = {0,0}, acc3 = {0,0};
    float4 den = {0,0,0,0};
    const int loff = l16 << 1;     // 2 channels of 32 (bytes in fp8)

    for (int e0 = start; e0 < end; e0 += 64) {
        const int cnt = min(64, end - e0);
        if (lane < cnt) {
            int sB = srcS[e0 + lane];
            slds[wid][lane] = sB;
            const float4 as = a_s4[sB];
            float x0 = as.x + ad.x; x0 = fmaxf(x0, NEG_SLOPE * x0);
            float x1 = as.y + ad.y; x1 = fmaxf(x1, NEG_SLOPE * x1);
            float x2 = as.z + ad.z; x2 = fmaxf(x2, NEG_SLOPE * x2);
            float x3 = as.w + ad.w; x3 = fmaxf(x3, NEG_SLOPE * x3);
            wlds[wid][lane] = (float4){exp2f(x0), exp2f(x1), exp2f(x2), exp2f(x3)};
        }
        int j = q;
        for (; j + 12 < cnt; j += 16) {
            int ss[4]; float4 ww[4]; unsigned int gg[4];
            #pragma unroll
            for (int u = 0; u < 4; u++) {
                ss[u] = slds[wid][j + 4 * u];
                ww[u] = wlds[wid][j + 4 * u];
            }
            #pragma unroll
            for (int u = 0; u < 4; u++)
                gg[u] = *(const unsigned short*)&x8[((size_t)ss[u] << 5) + loff];
            #pragma unroll
            for (int u = 0; u < 4; u++) {
                float vl, vh;
                fp8x2_to_f32(gg[u], vl, vh);
                acc0.x += ww[u].x * vl; acc0.y += ww[u].x * vh;
                acc1.x += ww[u].y * vl; acc1.y += ww[u].y * vh;
                acc2.x += ww[u].z * vl; acc2.y += ww[u].z * vh;
                acc3.x += ww[u].w * vl; acc3.y += ww[u].w * vh;
                den.x += ww[u].x; den.y += ww[u].y; den.z += ww[u].z; den.w += ww[u].w;
            }
        }
        for (; j + 4 < cnt; j += 8) {
            const int s0 = slds[wid][j], s1 = slds[wid][j + 4];
            const float4 w0 = wlds[wid][j], w1 = wlds[wid][j + 4];
            const unsigned int g0 = *(const unsigned short*)&x8[((size_t)s0 << 5) + loff];
            const unsigned int g1 = *(const unsigned short*)&x8[((size_t)s1 << 5) + loff];
            float vl0, vh0, vl1, vh1;
            fp8x2_to_f32(g0, vl0, vh0);
            fp8x2_to_f32(g1, vl1, vh1);
            acc0.x += w0.x * vl0 + w1.x * vl1; acc0.y += w0.x * vh0 + w1.x * vh1;
            acc1.x += w0.y * vl0 + w1.y * vl1; acc1.y += w0.y * vh0 + w1.y * vh1;
            acc2.x += w0.z * vl0 + w1.z * vl1; acc2.y += w0.z * vh0 + w1.z * vh1;
            acc3.x += w0.w * vl0 + w1.w * vl1; acc3.y += w0.w * vh0 + w1.w * vh1;
            den.x += w0.x + w1.x; den.y += w0.y + w1.y;
            den.z += w0.z + w1.z; den.w += w0.w + w1.w;
        }
        for (; j < cnt; j += 4) {
            const int s = slds[wid][j];
            const float4 w = wlds[wid][j];
            const unsigned int g = *(const unsigned short*)&x8[((size_t)s << 5) + loff];
            float vl, vh;
            fp8x2_to_f32(g, vl, vh);
            acc0.x += w.x * vl; acc0.y += w.x * vh;
            acc1.x += w.y * vl; acc1.y += w.y * vh;
            acc2.x += w.z * vl; acc2.y += w.z * vh;
            acc3.x += w.w * vl; acc3.y += w.w * vh;
            den.x += w.x; den.y += w.y; den.z += w.z; den.w += w.w;
        }
    }
    #pragma unroll
    for (int off = 16; off < 64; off <<= 1) {
        acc0.x += __shfl_xor(acc0.x, off); acc0.y += __shfl_xor(acc0.y, off);
        acc1.x += __shfl_xor(acc1.x, off); acc1.y += __shfl_xor(acc1.y, off);
        acc2.x += __shfl_xor(acc2.x, off); acc2.y += __shfl_xor(acc2.y, off);
        acc3.x += __shfl_xor(acc3.x, off); acc3.y += __shfl_xor(acc3.y, off);
        den.x += __shfl_xor(den.x, off); den.y += __shfl_xor(den.y, off);
        den.z += __shfl_xor(den.z, off); den.w += __shfl_xor(den.w, off);
    }
    if (q == 0) {
        const float i0 = 1.0f / (den.x + 1e-16f);
        const float i1 = 1.0f / (den.y + 1e-16f);
        const float i2 = 1.0f / (den.z + 1e-16f);
        const float i3 = 1.0f / (den.w + 1e-16f);
        unsigned int o0 = (unsigned int)f2b(acc0.x * i0) | ((unsigned int)f2b(acc0.y * i0) << 16);
        unsigned int o1 = (unsigned int)f2b(acc1.x * i1) | ((unsigned int)f2b(acc1.y * i1) << 16);
        unsigned int o2 = (unsigned int)f2b(acc2.x * i2) | ((unsigned int)f2b(acc2.y * i2) << 16);
        unsigned int o3 = (unsigned int)f2b(acc3.x * i3) | ((unsigned int)f2b(acc3.y * i3) << 16);
        *(unsigned int*)&aggX[((size_t)n << 7) + 0 * 32 + loff] = o0;
        *(unsigned int*)&aggX[((size_t)n << 7) + 1 * 32 + loff] = o1;
        *(unsigned int*)&aggX[((size_t)n << 7) + 2 * 32 + loff] = o2;
        *(unsigned int*)&aggX[((size_t)n << 7) + 3 * 32 + loff] = o3;
    }
}

// ------------- conv2 aggregate over FP8 table (4B/lane gather) + bias + ELU + conv3 scores;
// output table written fp8 (feeds all-fp8 conv3 GEMM) -------------
__global__ __launch_bounds__(256) void gat_fused4(
        const int* __restrict__ offsets, const int* __restrict__ srcS,
        const float4* __restrict__ a_s4, const float4* __restrict__ a_d4,
        const unsigned char* __restrict__ h8, const float* __restrict__ bias,
        const float* __restrict__ u3s, const float* __restrict__ u3d,
        float* __restrict__ a_s3, float* __restrict__ a_d3,
        unsigned char* __restrict__ outC8, int N) {
    __shared__ float wlds[4][64][4];
    __shared__ int slds[4][64];
    const int wid = threadIdx.x >> 6;
    const int n = blockIdx.x * 4 + wid;
    if (n >= N) return;
    const int lane = threadIdx.x & 63;
    const int quad = lane >> 4;
    const int start = offsets[n], end = offsets[n + 1];
    const float4 ad = a_d4[n];
    float4 acc = {0, 0, 0, 0};
    float den = 0.0f;
    const int loff = lane << 2;                  // channel index == byte offset (fp8)

    for (int e0 = start; e0 < end; e0 += 64) {
        const int cnt = min(64, end - e0);
        if (lane < cnt) {
            int sB = srcS[e0 + lane];
            slds[wid][lane] = sB;
            const float4 as = a_s4[sB];
            float x0 = as.x + ad.x; x0 = fmaxf(x0, NEG_SLOPE * x0);
            float x1 = as.y + ad.y; x1 = fmaxf(x1, NEG_SLOPE * x1);
            float x2 = as.z + ad.z; x2 = fmaxf(x2, NEG_SLOPE * x2);
            float x3 = as.w + ad.w; x3 = fmaxf(x3, NEG_SLOPE * x3);
            wlds[wid][lane][0] = exp2f(x0);
            wlds[wid][lane][1] = exp2f(x1);
            wlds[wid][lane][2] = exp2f(x2);
            wlds[wid][lane][3] = exp2f(x3);
        }
        int j = 0;
        for (; j + 4 <= cnt; j += 4) {
            const int s0 = __builtin_amdgcn_readfirstlane(slds[wid][j + 0]);
            const int s1 = __builtin_amdgcn_readfirstlane(slds[wid][j + 1]);
            const int s2 = __builtin_amdgcn_readfirstlane(slds[wid][j + 2]);
            const int s3 = __builtin_amdgcn_readfirstlane(slds[wid][j + 3]);
            const float w0 = wlds[wid][j + 0][quad];
            const float w1 = wlds[wid][j + 1][quad];
            const float w2 = wlds[wid][j + 2][quad];
            const float w3 = wlds[wid][j + 3][quad];
            const unsigned int g0 = *(const unsigned int*)&h8[((size_t)s0 << 8) + loff];
            const unsigned int g1 = *(const unsigned int*)&h8[((size_t)s1 << 8) + loff];
            const unsigned int g2 = *(const unsigned int*)&h8[((size_t)s2 << 8) + loff];
            const unsigned int g3 = *(const unsigned int*)&h8[((size_t)s3 << 8) + loff];
            float v0, v1, v2, v3;
            fp8x4_to_f32(g0, v0, v1, v2, v3);
            acc.x += w0 * v0; acc.y += w0 * v1; acc.z += w0 * v2; acc.w += w0 * v3;
            fp8x4_to_f32(g1, v0, v1, v2, v3);
            acc.x += w1 * v0; acc.y += w1 * v1; acc.z += w1 * v2; acc.w += w1 * v3;
            fp8x4_to_f32(g2, v0, v1, v2, v3);
            acc.x += w2 * v0; acc.y += w2 * v1; acc.z += w2 * v2; acc.w += w2 * v3;
            fp8x4_to_f32(g3, v0, v1, v2, v3);
            acc.x += w3 * v0; acc.y += w3 * v1; acc.z += w3 * v2; acc.w += w3 * v3;
            den += (w0 + w1) + (w2 + w3);
        }
        for (; j < cnt; j++) {
            const int s = __builtin_amdgcn_readfirstlane(slds[wid][j]);
            const float w = wlds[wid][j][quad];
            const unsigned int g = *(const unsigned int*)&h8[((size_t)s << 8) + loff];
            float v0, v1, v2, v3;
            fp8x4_to_f32(g, v0, v1, v2, v3);
            acc.x += w * v0; acc.y += w * v1; acc.z += w * v2; acc.w += w * v3;
            den += w;
        }
    }

    const float inv = 1.0f / (den + 1e-16f);
    const float4 bb = *(const float4*)&bias[loff];
    float v0 = acc.x * inv + bb.x; v0 = (v0 > 0.0f) ? v0 : expm1f(v0);
    float v1 = acc.y * inv + bb.y; v1 = (v1 > 0.0f) ? v1 : expm1f(v1);
    float v2 = acc.z * inv + bb.z; v2 = (v2 > 0.0f) ? v2 : expm1f(v2);
    float v3 = acc.w * inv + bb.w; v3 = (v3 > 0.0f) ? v3 : expm1f(v3);
    // conv3 scores from the fp32 h3 row (each lane owns 4 channels)
    {
        const float4 us = *(const float4*)&u3s[loff];
        const float4 ud = *(const float4*)&u3d[loff];
        float ps = v0 * us.x + v1 * us.y + v2 * us.z + v3 * us.w;
        float pd = v0 * ud.x + v1 * ud.y + v2 * ud.z + v3 * ud.w;
        #pragma unroll
        for (int off = 1; off < 64; off <<= 1) {
            ps += __shfl_xor(ps, off);
            pd += __shfl_xor(pd, off);
        }
        if (lane == 0) {
            a_s3[n] = ps * LOG2E;
            a_d3[n] = pd * LOG2E;
        }
    }
    unsigned int o = (unsigned int)f32_to_fp8(v0)
                   | ((unsigned int)f32_to_fp8(v1) << 8)
                   | ((unsigned int)f32_to_fp8(v2) << 16)
                   | ((unsigned int)f32_to_fp8(v3) << 24);
    *(unsigned int*)&outC8[(size_t)n * 256 + loff] = o;
}

// ------------- H=1 fused (conv3): wave/node gather over FP8 table + PARTITIONED fused mean-pool -------------
__global__ __launch_bounds__(256) void gat_fused1(
        const int* __restrict__ offsets, const int* __restrict__ srcS,
        const float* __restrict__ a_s, const float* __restrict__ a_d,
        const unsigned char* __restrict__ h8, const float* __restrict__ bias,
        const int* __restrict__ batch,
        float* __restrict__ pooledP, float* __restrict__ cntP, int N, int G) {
    __shared__ float wlds[4][64];
    __shared__ int slds[4][64];
    __shared__ float2 sOut[4][32];
    __shared__ int sG[4];
    const int wid = threadIdx.x >> 6;
    const int n = blockIdx.x * 4 + wid;
    const bool valid = n < N;                  // no early return: all waves reach the barrier
    const int lane = threadIdx.x & 63;
    const int half = lane >> 5;
    const int l32 = lane & 31;
    const int start = valid ? offsets[n] : 0;
    const int end   = valid ? offsets[n + 1] : 0;
    const float ad  = valid ? a_d[n] : 0.0f;
    float accx = 0.0f, accy = 0.0f, den = 0.0f;
    const int loff = l32 << 1;                 // 2 channels (bytes in fp8)

    for (int e0 = start; e0 < end; e0 += 64) {
        const int cnt_ = min(64, end - e0);
        if (lane < cnt_) {
            int sB = srcS[e0 + lane];
            slds[wid][lane] = sB;
            float ev = a_s[sB] + ad;
            ev = fmaxf(ev, NEG_SLOPE * ev);
            wlds[wid][lane] = exp2f(ev);
        }
        int j = half;
        for (; j + 8 <= cnt_ + half; j += 8) {
            const int s0 = slds[wid][j + 0];
            const int s1 = slds[wid][j + 2];
            const int s2 = slds[wid][j + 4];
            const int s3 = slds[wid][j + 6];
            const float w0 = wlds[wid][j + 0];
            const float w1 = wlds[wid][j + 2];
            const float w2 = wlds[wid][j + 4];
            const float w3 = wlds[wid][j + 6];
            const unsigned int g0 = *(const unsigned short*)&h8[((size_t)s0 << 6) + loff];
            const unsigned int g1 = *(const unsigned short*)&h8[((size_t)s1 << 6) + loff];
            const unsigned int g2 = *(const unsigned short*)&h8[((size_t)s2 << 6) + loff];
            const unsigned int g3 = *(const unsigned short*)&h8[((size_t)s3 << 6) + loff];
            float vl, vh;
            fp8x2_to_f32(g0, vl, vh); accx += w0 * vl; accy += w0 * vh;
            fp8x2_to_f32(g1, vl, vh); accx += w1 * vl; accy += w1 * vh;
            fp8x2_to_f32(g2, vl, vh); accx += w2 * vl; accy += w2 * vh;
            fp8x2_to_f32(g3, vl, vh); accx += w3 * vl; accy += w3 * vh;
            den += (w0 + w1) + (w2 + w3);
        }
        for (; j < cnt_; j += 2) {
            const int s = slds[wid][j];
            const float w = wlds[wid][j];
            const unsigned int g = *(const unsigned short*)&h8[((size_t)s << 6) + loff];
            float vl, vh;
            fp8x2_to_f32(g, vl, vh);
            accx += w * vl;
            accy += w * vh;
            den += w;
        }
    }
    accx += __shfl_xor(accx, 32);
    accy += __shfl_xor(accy, 32);
    den  += __shfl_xor(den, 32);
    if (half == 0) {
        if (valid) {
            const float inv = 1.0f / (den + 1e-16f);
            sOut[wid][l32] = (float2){accx * inv + bias[loff], accy * inv + bias[loff + 1]};
        } else {
            sOut[wid][l32] = (float2){0.0f, 0.0f};
        }
        if (l32 == 0) sG[wid] = valid ? batch[n] : -1;
    }
    __syncthreads();
    const int p = blockIdx.x & 63;
    if (wid == 0 && half == 0) {
        const int g0 = sG[0], g1 = sG[1], g2 = sG[2], g3 = sG[3];
        if (g0 >= 0 && g1 == g0 && g2 == g0 && g3 == g0) {
            const float2 s0 = sOut[0][l32], s1 = sOut[1][l32];
            const float2 s2 = sOut[2][l32], s3 = sOut[3][l32];
            float* base = pooledP + ((size_t)p * G + g0) * 64;
            atomicAdd(&base[loff],     (s0.x + s1.x) + (s2.x + s3.x));
            atomicAdd(&base[loff + 1], (s0.y + s1.y) + (s2.y + s3.y));
            if (l32 == 0) atomicAdd(&cntP[p * G + g0], 4.0f);
        } else {
            #pragma unroll
            for (int w = 0; w < 4; w++) {
                const int g = sG[w];
                if (g >= 0) {
                    const float2 s = sOut[w][l32];
                    float* base = pooledP + ((size_t)p * G + g) * 64;
                    atomicAdd(&base[loff], s.x);
                    atomicAdd(&base[loff + 1], s.y);
                    if (l32 == 0) atomicAdd(&cntP[p * G + g], 1.0f);
                }
            }
        }
    }
}

// ------------- decoder head: one block per graph (reduces 64 pool partitions first) -------------
__global__ __launch_bounds__(256) void final_kernel(
        const float* __restrict__ pooledP, const float* __restrict__ cntP,
        const float* __restrict__ gf, const float* __restrict__ Wg,
        const float* __restrict__ bg, const float* __restrict__ Wd1,
        const float* __restrict__ bd1, const float* __restrict__ gamma,
        const float* __restrict__ beta, const float* __restrict__ Wd2,
        const float* __restrict__ bd2, float* __restrict__ out, int G) {
    const int g = blockIdx.x;
    const int tid = threadIdx.x;
    const int lane = tid & 63;
    const int wave = tid >> 6;
    __shared__ float sPart[4][64];
    __shared__ float sCntTot;
    __shared__ float spg[128];
    __shared__ float sz[64];
    __shared__ float wred[8];

    {   // partition reduce: wave pg sums partitions [pg*16, pg*16+16)
        const int c = lane;
        const int pg = wave;
        float a = 0.0f;
        #pragma unroll
        for (int p = 0; p < 16; p++)
            a += pooledP[((size_t)(pg * 16 + p) * G + g) * 64 + c];
        sPart[pg][c] = a;
        if (pg == 1) {
            float cv = cntP[c * G + g];
            #pragma unroll
            for (int off = 32; off > 0; off >>= 1) cv += __shfl_xor(cv, off);
            if (c == 0) sCntTot = cv;
        }
    }
    __syncthreads();
    if (tid < 64) {
        spg[tid] = (sPart[0][tid] + sPart[1][tid] + sPart[2][tid] + sPart[3][tid])
                   / fmaxf(sCntTot, 1.0f);
    } else if (tid < 128) {
        int c = tid - 64;
        float v = bg[c];
        #pragma unroll
        for (int k = 0; k < 4; k++) v += gf[g * 4 + k] * Wg[k * 64 + c];
        spg[64 + c] = fmaxf(v, 0.0f);
    }
    __syncthreads();
    if (tid < 64) {
        float v = bd1[tid];
        #pragma unroll 8
        for (int k = 0; k < 128; k++) v += spg[k] * Wd1[k * 64 + tid];
        v = v * gamma[tid] + beta[tid];
        sz[tid] = fmaxf(v, 0.0f);
    }
    __syncthreads();
    float v = bd2[tid];
    #pragma unroll 8
    for (int k = 0; k < 64; k++) v += sz[k] * Wd2[k * 256 + tid];
    float m = v;
    #pragma unroll
    for (int off = 32; off > 0; off >>= 1) m = fmaxf(m, __shfl_xor(m, off));
    if (lane == 0) wred[wave] = m;
    __syncthreads();
    float M = fmaxf(fmaxf(wred[0], wred[1]), fmaxf(wred[2], wred[3]));
    float e = expf(v - M);
    float s = e;
    #pragma unroll
    for (int off = 32; off > 0; off >>= 1) s += __shfl_xor(s, off);
    if (lane == 0) wred[4 + wave] = s;
    __syncthreads();
    float S = (wred[4] + wred[5]) + (wred[6] + wred[7]);
    out[g * 256 + tid] = e / S;
}

extern "C" void kernel_launch(void* const* d_in, const int* in_sizes, int n_in,
                              void* d_out, int out_size, void* d_ws, size_t ws_size,
                              hipStream_t stream) {
    const float* x     = (const float*)d_in[0];
    const int*   ei    = (const int*)  d_in[1];
    const int*   batch = (const int*)  d_in[2];
    const float* gf    = (const float*)d_in[3];
    const float* W_enc = (const float*)d_in[4];
    const float* b_enc = (const float*)d_in[5];
    const float* W1  = (const float*)d_in[6];
    const float* as1 = (const float*)d_in[7];
    const float* ad1 = (const float*)d_in[8];
    const float* b1  = (const float*)d_in[9];
    const float* W2  = (const float*)d_in[10];
    const float* as2 = (const float*)d_in[11];
    const float* ad2 = (const float*)d_in[12];
    const float* b2  = (const float*)d_in[13];
    const float* W3  = (const float*)d_in[14];
    const float* as3 = (const float*)d_in[15];
    const float* ad3 = (const float*)d_in[16];
    const float* b3  = (const float*)d_in[17];
    const float* Wg  = (const float*)d_in[18];
    const float* bg  = (const float*)d_in[19];
    const float* Wd1 = (const float*)d_in[20];
    const float* bd1 = (const float*)d_in[21];
    const float* gm  = (const float*)d_in[22];
    const float* bt  = (const float*)d_in[23];
    const float* Wd2 = (const float*)d_in[24];
    const float* bd2 = (const float*)d_in[25];

    const int N  = in_sizes[2];
    const int E  = in_sizes[1] / 2;
    const int G  = in_sizes[3] / 4;
    const int Et = E + N;
    const int NB = (N + 127) >> 7;               // dst-buckets of 128 nodes (<=1024)

    unsigned short* h16a = (unsigned short*)d_ws;                // slot: conv2 fp8 table [N,256]B
    unsigned short* h16b = h16a + (size_t)N * 256;               // [N,256]: aggX [N,128] bf16 early, then conv2 agg out fp8
    unsigned short* h1_16 = h16b + (size_t)N * 256;              // slot: conv3 fp8 table [N,64]B
    unsigned short* x16  = h1_16 + (size_t)N * 64;               // slot: x fp8 table [N,32]B
    unsigned short* Wc1t = x16 + (size_t)N * 32;                 // [4][64][32] bf16
    unsigned char* Wt2_8 = (unsigned char*)(Wc1t + 4 * 64 * 32); // [256][256] fp8
    unsigned char* Wt3_8 = Wt2_8 + 256 * 256;                    // [64][256] fp8
    float* bc1    = (float*)(Wt3_8 + 64 * 256);                  // [256]
    float* a_s    = bc1 + 256;                                   // [N,4]
    float* a_d    = a_s + (size_t)N * 4;                         // [N,4]
    float* a_s3   = a_d + (size_t)N * 4;                         // [N]
    float* a_d3   = a_s3 + N;                                    // [N]
    float* u1s    = a_d3 + N;                                    // [64,4]
    float* u1d    = u1s + 256;                                   // [64,4]
    float* u3s    = u1d + 256;                                   // [256]
    float* u3d    = u3s + 256;                                   // [256]
    float* pooledP = u3d + 256;                                  // [64][G][64]
    float* cntP   = pooledP + (size_t)64 * G * 64;               // [64][G]
    int*   offsets = (int*)(cntP + 64 * G);                      // [N+1]
    int*   srcS    = offsets + (N + 1);                          // [Et]
    int*   counts  = srcS + Et;                                  // [N]
    int*   blockSums = counts + N;                               // [cdiv(N,1024)]
    int*   bucketCnt = blockSums + ((N + 1023) / 1024);          // [NB+1]
    int*   bucketOff = bucketCnt + (NB + 1);                     // [NB+1]
    int*   bucketCur = bucketOff + (NB + 1);                     // [NB]
    uint2* bucketBuf = (uint2*)(((size_t)(bucketCur + NB) + 7) & ~(size_t)7);   // [Et]

    unsigned char* h8a  = (unsigned char*)h16a;                  // fp8 conv2 gather table view
    unsigned char* h8b  = (unsigned char*)h16b;                  // fp8 conv3 GEMM-A view (fused4 out)
    unsigned char* h1_8 = (unsigned char*)h1_16;                 // fp8 conv3 gather table view
    unsigned char* x8   = (unsigned char*)x16;                   // fp8 x gather table view

    dim3 blk(256);
    auto cdiv = [](int a, int b) { return (a + b - 1) / b; };
    const int ebBlocks = cdiv(Et, 4096);
    const int rowBlocks = cdiv(N, 64);
    const int nScanBlocks = cdiv(N, 1024);
    const int zc = cdiv(N, 256);
    const int z2 = cdiv(64 * G * 64, 256);

    // ---------------- prep (folded weights + u-vectors + zero-init) + CSR build ----------------
    prep_kernel<<<355 + zc + z2, blk, 0, stream>>>(W_enc, b_enc, W1, W2, W3, as1, ad1, b1,
                                                   as3, ad3, Wc1t, bc1, Wt2_8, Wt3_8,
                                                   u1s, u1d, u3s, u3d,
                                                   counts, pooledP, cntP, bucketCnt,
                                                   N, G, zc, NB);
    edge_hist_kernel<<<ebBlocks, blk, 0, stream>>>(ei, counts, bucketCnt, E, Et, NB);
    scan_blocks<<<nScanBlocks, 1024, 0, stream>>>(counts, blockSums, N);
    scan_add2<<<cdiv(N + 1, 256), blk, 0, stream>>>(counts, blockSums, nScanBlocks,
                                                    offsets, N, Et);
    bucket_scan<<<1, 1024, 0, stream>>>(bucketCnt, bucketOff, bucketCur, NB, Et);
    bucket_scatter<<<ebBlocks, blk, 0, stream>>>(ei, bucketCur, bucketBuf, E, Et, NB);
    bucket_sort<<<NB, blk, 0, stream>>>(bucketBuf, bucketOff, offsets, srcS);

    // conv1 scores from fp32 x + x->fp8 gather table
    score_x<<<cdiv(N, 32), blk, 0, stream>>>(x, W_enc, b_enc, u1s, u1d, x8, a_s, a_d, N);

    // ---------------- conv1 aggregate (fp8 x) -> fused conv1+conv2 GEMM (fp8 MFMA, fp8 out) ----------------
    gat_agg_x32<<<cdiv(N, 4), blk, 0, stream>>>(offsets, srcS, (const float4*)a_s,
                                                (const float4*)a_d, x8, h16b, N);
    gemm_c12<<<rowBlocks, blk, 0, stream>>>(h16b, Wc1t, bc1, Wt2_8, as2, ad2,
                                            a_s, a_d, h8a, N);

    // ---------------- conv2 aggregate over fp8 table (+conv3 scores fused), fp8 out ----------------
    gat_fused4<<<cdiv(N, 4), blk, 0, stream>>>(offsets, srcS, (const float4*)a_s,
                                               (const float4*)a_d, h8a, b2,
                                               u3s, u3d, a_s3, a_d3, h8b, N);

    // ---------------- conv3: all-fp8 GEMM -> aggregate + partitioned pool ----------------
    gemm_c3<<<rowBlocks, blk, 0, stream>>>(h8b, Wt3_8, h1_8, N);
    gat_fused1<<<cdiv(N, 4), blk, 0, stream>>>(offsets, srcS, a_s3, a_d3, h1_8, b3,
                                               batch, pooledP, cntP, N, G);

    // ---------------- decoder head ----------------
    final_kernel<<<G, blk, 0, stream>>>(pooledP, cntP, gf, Wg, bg, Wd1, bd1, gm, bt, Wd2, bd2,
                                        (float*)d_out, G);
}

// Round 13
// 348.449 us; speedup vs baseline: 1.3252x; 1.0012x over previous
//
#include <hip/hip_runtime.h>
#include <math.h>

#define NEG_SLOPE 0.2f
#define LOG2E 1.4426950408889634f
#define BSH 7                      // 128 nodes per dst-bucket

typedef __attribute__((ext_vector_type(8))) short short8;   // 8 bf16 = 4 VGPRs
typedef __attribute__((ext_vector_type(4))) float f32x4;    // MFMA acc
typedef __attribute__((ext_vector_type(2))) float f32x2;
typedef long long i64;

#if __has_builtin(__builtin_amdgcn_cvt_pk_f32_fp8) && __has_builtin(__builtin_amdgcn_cvt_pk_fp8_f32)
#define FP8_HW 1
#else
#define FP8_HW 0
#endif

__device__ inline float b2f_lo(unsigned int u) {
    union { unsigned int i; float f; } x; x.i = u << 16; return x.f;
}
__device__ inline float b2f_hi(unsigned int u) {
    union { unsigned int i; float f; } x; x.i = u & 0xFFFF0000u; return x.f;
}
__device__ inline unsigned short f2b(float f) {
    union { float f; unsigned int i; } u; u.f = f;
    unsigned int r = u.i + 0x7FFF + ((u.i >> 16) & 1);   // round-to-nearest-even
    return (unsigned short)(r >> 16);
}

// ---- OCP e4m3 helpers (HW cvt on gfx950; exact manual fallback) ----
__device__ inline float fp8_decode1(unsigned int b) {
    unsigned int e = (b >> 3) & 15, m = b & 7;
    union { unsigned int i; float f; } u;
    if (e == 0) u.f = (float)m * 0.001953125f;          // subnormal: m * 2^-9
    else u.i = ((e + 120) << 23) | (m << 20);            // (1+m/8) * 2^(e-7)
    if (b & 0x80) u.f = -u.f;
    return u.f;
}
__device__ inline void fp8x4_to_f32(unsigned int g, float& v0, float& v1,
                                    float& v2, float& v3) {
#if FP8_HW
    f32x2 lo = __builtin_amdgcn_cvt_pk_f32_fp8((int)g, false);   // bytes 0,1
    f32x2 hi = __builtin_amdgcn_cvt_pk_f32_fp8((int)g, true);    // bytes 2,3
    v0 = lo[0]; v1 = lo[1]; v2 = hi[0]; v3 = hi[1];
#else
    v0 = fp8_decode1(g & 255);         v1 = fp8_decode1((g >> 8) & 255);
    v2 = fp8_decode1((g >> 16) & 255); v3 = fp8_decode1((g >> 24) & 255);
#endif
}
__device__ inline void fp8x2_to_f32(unsigned int g2, float& v0, float& v1) {
#if FP8_HW
    f32x2 lo = __builtin_amdgcn_cvt_pk_f32_fp8((int)(g2 & 0xFFFF), false);
    v0 = lo[0]; v1 = lo[1];
#else
    v0 = fp8_decode1(g2 & 255);
    v1 = fp8_decode1((g2 >> 8) & 255);
#endif
}
__device__ inline unsigned char f32_to_fp8(float f) {
#if FP8_HW
    return (unsigned char)(__builtin_amdgcn_cvt_pk_fp8_f32(f, f, 0, false) & 0xFF);
#else
    union { float f; unsigned int i; } u; u.f = f;
    unsigned int s = (u.i >> 24) & 0x80;
    float a = fabsf(f);
    if (a < 0.015625f) {                                 // subnormal band
        int m = (int)rintf(a * 512.0f);
        if (m > 7) return (unsigned char)(s | 0x08);
        return (unsigned char)(s | m);
    }
    if (a >= 448.0f) return (unsigned char)(s | 0x7E);
    int e = (int)((u.i >> 23) & 0xFF) - 127;
    union { unsigned int i; float f; } sc; sc.i = (unsigned int)(127 + 3 - e) << 23;
    int q = (int)rintf(a * sc.f);                        // in [8,16]
    if (q >= 16) { q = 8; e += 1; }
    return (unsigned char)(s | ((unsigned int)(e + 7) << 3) | (unsigned int)(q - 8));
#endif
}

// ---------------- prep: folded conv1 weights (fp8), u1/u3 vectors, Wt2/Wt3 (fp8), ALL zero-init ----------------
__global__ void prep_kernel(const float* __restrict__ W_enc, const float* __restrict__ b_enc,
                            const float* __restrict__ W1, const float* __restrict__ W2,
                            const float* __restrict__ W3, const float* __restrict__ as1,
                            const float* __restrict__ ad1, const float* __restrict__ b1,
                            const float* __restrict__ as3, const float* __restrict__ ad3,
                            unsigned char* __restrict__ Wc1t, float* __restrict__ bc1,
                            unsigned char* __restrict__ Wt2, unsigned char* __restrict__ Wt3,
                            float* __restrict__ u1s, float* __restrict__ u1d,
                            float* __restrict__ u3s, float* __restrict__ u3d,
                            int* __restrict__ counts, float* __restrict__ pooledP,
                            float* __restrict__ cntP, int* __restrict__ bucketCnt,
                            int N, int G, int zc, int NB) {
    const int b = blockIdx.x;
    const int t = threadIdx.x;
    if (b < 32) {
        int i = b * 256 + t;                       // 8192 values
        int h = i >> 11, rem = i & 2047, o = rem >> 5, j = rem & 31;
        float s = 0.0f;
        for (int k = 0; k < 64; k++)
            s += W_enc[j * 64 + k] * W1[k * 256 + h * 64 + o];
        Wc1t[i] = f32_to_fp8(s);
    } else if (b == 32) {
        float s = b1[t];
        for (int k = 0; k < 64; k++) s += b_enc[k] * W1[k * 256 + t];
        bc1[t] = s;
    } else if (b == 33) {
        int k = t >> 2, h = t & 3;
        float s = 0.0f, d = 0.0f;
        for (int c = 0; c < 64; c++) {
            float w = W1[k * 256 + h * 64 + c];
            s += w * as1[h * 64 + c];
            d += w * ad1[h * 64 + c];
        }
        u1s[k * 4 + h] = s;
        u1d[k * 4 + h] = d;
    } else if (b == 34) {
        float s = 0.0f, d = 0.0f;
        for (int o = 0; o < 64; o++) {
            float w = W3[t * 64 + o];
            s += w * as3[o];
            d += w * ad3[o];
        }
        u3s[t] = s; u3d[t] = d;
    } else if (b < 35 + 256) {
        int i = (b - 35) * 256 + t;                // K=256, M=256
        int k = i >> 8, m = i & 255;
        Wt2[(size_t)m * 256 + k] = f32_to_fp8(W2[i]);
    } else if (b < 35 + 256 + 64) {
        int i = (b - 291) * 256 + t;               // K=256, M=64
        int k = i >> 6, m = i & 63;
        Wt3[(size_t)m * 256 + k] = f32_to_fp8(W3[i]);
    } else if (b < 355 + zc) {
        int i = (b - 355) * 256 + t;
        if (i < N) counts[i] = 0;
    } else {
        int i = (b - 355 - zc) * 256 + t;
        if (i < 64 * G * 64) pooledP[i] = 0.0f;    // [64 partitions][G][64]
        if (i < 64 * G) cntP[i] = 0.0f;            // [64 partitions][G]
        if (i <= NB) bucketCnt[i] = 0;
    }
}

// ---------------- score_x: conv1 scores from fp32 x + x -> fp8 table ----------------
__global__ __launch_bounds__(256) void score_x(
        const float* __restrict__ x, const float* __restrict__ W_enc,
        const float* __restrict__ b_enc,
        const float* __restrict__ u1s, const float* __restrict__ u1d,
        unsigned char* __restrict__ x8, float* __restrict__ a_s,
        float* __restrict__ a_d, int N) {
    __shared__ float sUs[32][4], sUd[32][4], sC[8];
    __shared__ float sX[32][33];
    const int t = threadIdx.x;
    if (t < 128) {
        int j = t >> 2, h = t & 3;
        float s = 0.0f, d = 0.0f;
        for (int k = 0; k < 64; k++) {
            float w = W_enc[j * 64 + k];
            s += w * u1s[k * 4 + h];
            d += w * u1d[k * 4 + h];
        }
        sUs[j][h] = s; sUd[j][h] = d;
    } else if (t < 136) {
        int hh = t - 128;                           // 0..3 -> s, 4..7 -> d
        const float* u = (hh < 4) ? u1s : u1d;
        int h = hh & 3;
        float c = 0.0f;
        for (int k = 0; k < 64; k++) c += b_enc[k] * u[k * 4 + h];
        sC[hh] = c;
    }
    const int n0 = blockIdx.x * 32;
    const int row = t >> 3, col = (t & 7) << 2;
    float4 xv = {0, 0, 0, 0};
    if (n0 + row < N) xv = *(const float4*)&x[(size_t)(n0 + row) * 32 + col];
    sX[row][col + 0] = xv.x; sX[row][col + 1] = xv.y;
    sX[row][col + 2] = xv.z; sX[row][col + 3] = xv.w;
    __syncthreads();
    const int ni = t >> 3, oi = t & 7, h = oi & 3;
    const bool isS = oi < 4;
    float acc = sC[oi];
    #pragma unroll 8
    for (int j = 0; j < 32; j++) acc += sX[ni][j] * (isS ? sUs[j][h] : sUd[j][h]);
    if (n0 + ni < N) {
        float* out = isS ? a_s : a_d;
        out[(size_t)(n0 + ni) * 4 + h] = acc * LOG2E;
    }
    if (n0 + row < N) {
        unsigned int o = (unsigned int)f32_to_fp8(xv.x)
                       | ((unsigned int)f32_to_fp8(xv.y) << 8)
                       | ((unsigned int)f32_to_fp8(xv.z) << 16)
                       | ((unsigned int)f32_to_fp8(xv.w) << 24);
        *(unsigned int*)&x8[(size_t)(n0 + row) * 32 + col] = o;
    }
}

// ---------------- FUSED conv1+conv2 GEMM: ALL-fp8 MFMA both phases.
// Phase1: aggX8[N,128] fp8 @ Wc1t fp8 (K=32) -> ELU -> sH8 fp8.  (B rows staged at +48: 16B-aligned)
// Phase2: sH8 @ Wt2 fp8 (K=256). Scores fp32. fp8 table out. ----------------
__global__ __launch_bounds__(256) void gemm_c12(
        const unsigned char* __restrict__ aggX8,   // [N,128] fp8
        const unsigned char* __restrict__ Wc1t,    // [(h*64+o)*32 + j] fp8
        const float* __restrict__ bc1,
        const unsigned char* __restrict__ Wt2,     // [256][256] fp8 B^T
        const float* __restrict__ att_s,
        const float* __restrict__ att_d,
        float* __restrict__ a_s, float* __restrict__ a_d,
        unsigned char* __restrict__ C8,            // [N,256] fp8 conv2 gather table
        int Nrows) {
    __shared__ unsigned char sH8[64][264];         // h2 tile, fp8
    __shared__ unsigned char sB8[256 * 80];        // staging (phase1: A rows @+0, B rows @+48; phase2: Wt2 chunk)
    __shared__ float sSD[64][4][2];
    const int tid = threadIdx.x;
    const int wave = tid >> 6;
    const int lane = tid & 63;
    const int quad = lane >> 4;
    const int l16 = lane & 15;
    const int row0 = blockIdx.x * 64;

    // ---- phase 1: conv1 (folded, K=32, fp8 MFMA) per head -> sH8 fp8 ----
    // layout: A row r at sB8[r*80] (32B), B row r at sB8[r*80+48] (32B, 16B-aligned)
    #pragma unroll
    for (int h = 0; h < 4; h++) {
        __syncthreads();
        if (tid < 128) {
            int r = tid >> 1, o = (tid & 1) << 4;
            int row = row0 + r;
            uint4 z = {0,0,0,0};
            *(uint4*)&sB8[r * 80 + o] = (row < Nrows)
                ? *(const uint4*)&aggX8[(size_t)row * 128 + h * 32 + o] : z;
        } else {
            int t2 = tid - 128;
            int r = t2 >> 1, o = (t2 & 1) << 4;
            *(uint4*)&sB8[r * 80 + 48 + o] = *(const uint4*)&Wc1t[(size_t)(h * 64 + r) * 32 + o];
        }
        __syncthreads();
        i64 bf = *(const i64*)&sB8[(wave * 16 + l16) * 80 + 48 + quad * 8];
        const int col = h * 64 + wave * 16 + l16;
        const float bb = bc1[col];
        #pragma unroll
        for (int i = 0; i < 4; i++) {
            i64 af = *(const i64*)&sB8[(i * 16 + l16) * 80 + quad * 8];
            f32x4 acc = __builtin_amdgcn_mfma_f32_16x16x32_fp8_fp8(af, bf, (f32x4){0,0,0,0}, 0, 0, 0);
            #pragma unroll
            for (int r = 0; r < 4; r++) {
                float v = acc[r] + bb;
                v = (v > 0.0f) ? v : expm1f(v);        // ELU
                sH8[i * 16 + quad * 4 + r][col] = f32_to_fp8(v);
            }
        }
    }

    // ---- phase 2: conv2 GEMM (fp8 MFMA), A from sH8, B = Wt2 fp8, BN=256 ----
    f32x4 acc2[4][4];
    #pragma unroll
    for (int i = 0; i < 4; i++)
        #pragma unroll
        for (int j = 0; j < 4; j++) acc2[i][j] = (f32x4){0,0,0,0};

    for (int kt = 0; kt < 256; kt += 32) {
        __syncthreads();
        {
            const unsigned char* src = &Wt2[(size_t)tid * 256 + kt];
            *(uint4*)&sB8[tid * 80]      = *(const uint4*)src;
            *(uint4*)&sB8[tid * 80 + 16] = *(const uint4*)(src + 16);
        }
        __syncthreads();
        i64 bf2[4];
        #pragma unroll
        for (int j = 0; j < 4; j++)
            bf2[j] = *(const i64*)&sB8[(wave * 64 + j * 16 + l16) * 80 + quad * 8];
        #pragma unroll
        for (int i = 0; i < 4; i++) {
            i64 af = *(const i64*)&sH8[i * 16 + l16][kt + quad * 8];
            #pragma unroll
            for (int j = 0; j < 4; j++)
                acc2[i][j] = __builtin_amdgcn_mfma_f32_16x16x32_fp8_fp8(af, bf2[j], acc2[i][j], 0, 0, 0);
        }
    }

    // ---- conv2 scores (fp32, before fp8 encode) ----
    {
        for (int t = tid; t < 512; t += 256) ((float*)sSD)[t] = 0.0f;
        __syncthreads();
        float avs[4], avd[4];
        #pragma unroll
        for (int j = 0; j < 4; j++) {
            int c = wave * 64 + j * 16 + l16;
            avs[j] = att_s[c];
            avd[j] = att_d[c];
        }
        #pragma unroll
        for (int i = 0; i < 4; i++) {
            float ps[4] = {0,0,0,0}, pd[4] = {0,0,0,0};
            #pragma unroll
            for (int j = 0; j < 4; j++)
                #pragma unroll
                for (int r = 0; r < 4; r++) {
                    ps[r] += acc2[i][j][r] * avs[j];
                    pd[r] += acc2[i][j][r] * avd[j];
                }
            #pragma unroll
            for (int off = 1; off < 16; off <<= 1)
                #pragma unroll
                for (int r = 0; r < 4; r++) {
                    ps[r] += __shfl_xor(ps[r], off);
                    pd[r] += __shfl_xor(pd[r], off);
                }
            if (l16 == 0) {
                #pragma unroll
                for (int r = 0; r < 4; r++) {
                    atomicAdd(&sSD[i * 16 + quad * 4 + r][wave][0], ps[r]);
                    atomicAdd(&sSD[i * 16 + quad * 4 + r][wave][1], pd[r]);
                }
            }
        }
        __syncthreads();
        {
            int row = tid & 63, hb = tid >> 6;
            int r = row0 + row;
            if (r < Nrows) {
                a_s[r * 4 + hb] = sSD[row][hb][0] * LOG2E;
                a_d[r * 4 + hb] = sSD[row][hb][1] * LOG2E;
            }
        }
    }
    // ---- C write (fp8 e4m3) ----
    #pragma unroll
    for (int i = 0; i < 4; i++) {
        #pragma unroll
        for (int j = 0; j < 4; j++) {
            int col = wave * 64 + j * 16 + l16;
            #pragma unroll
            for (int r = 0; r < 4; r++) {
                int row = row0 + i * 16 + quad * 4 + r;
                if (row < Nrows) C8[(size_t)row * 256 + col] = f32_to_fp8(acc2[i][j][r]);
            }
        }
    }
}

// ---------------- conv3 GEMM (all-fp8): C8[N,64] = A8[N,256] @ Wt3_8^T ----------------
__global__ __launch_bounds__(256) void gemm_c3(const unsigned char* __restrict__ A8,
                                               const unsigned char* __restrict__ Bt8,
                                               unsigned char* __restrict__ C8,
                                               int Nrows) {
    __shared__ unsigned char sA8[64][40];
    __shared__ unsigned char sB8[64][40];
    const int tid = threadIdx.x;
    const int wave = tid >> 6;
    const int lane = tid & 63;
    const int quad = lane >> 4;
    const int l16 = lane & 15;
    const int row0 = blockIdx.x * 64;

    f32x4 acc[4];
    #pragma unroll
    for (int i = 0; i < 4; i++) acc[i] = (f32x4){0,0,0,0};

    for (int kt = 0; kt < 256; kt += 32) {
        __syncthreads();
        if (tid < 128) {
            int r = tid >> 1, o = (tid & 1) << 4;
            int row = row0 + r;
            uint4 z = {0,0,0,0};
            *(uint4*)&sA8[r][o] = (row < Nrows)
                ? *(const uint4*)&A8[(size_t)row * 256 + kt + o] : z;
        } else {
            int t2 = tid - 128;
            int r = t2 >> 1, o = (t2 & 1) << 4;
            *(uint4*)&sB8[r][o] = *(const uint4*)&Bt8[(size_t)r * 256 + kt + o];
        }
        __syncthreads();
        i64 bf = *(const i64*)&sB8[wave * 16 + l16][quad * 8];
        #pragma unroll
        for (int i = 0; i < 4; i++) {
            i64 af = *(const i64*)&sA8[i * 16 + l16][quad * 8];
            acc[i] = __builtin_amdgcn_mfma_f32_16x16x32_fp8_fp8(af, bf, acc[i], 0, 0, 0);
        }
    }
    const int col = wave * 16 + l16;
    #pragma unroll
    for (int i = 0; i < 4; i++) {
        #pragma unroll
        for (int r = 0; r < 4; r++) {
            int row = row0 + i * 16 + quad * 4 + r;
            if (row < Nrows) C8[(size_t)row * 64 + col] = f32_to_fp8(acc[i][r]);
        }
    }
}

// ------------- CSR build: node hist + dst-bucket hist (fused, LDS-aggregated buckets) -------------
__global__ __launch_bounds__(256) void edge_hist_kernel(const int* __restrict__ ei,
                                                        int* __restrict__ counts,
                                                        int* __restrict__ bucketCnt,
                                                        int E, int Et, int NB) {
    __shared__ int lhist[1024];
    const int tid = threadIdx.x;
    for (int b = tid; b < NB; b += 256) lhist[b] = 0;
    __syncthreads();
    const int base = blockIdx.x * 4096;
    #pragma unroll
    for (int k = 0; k < 16; k++) {
        int e = base + k * 256 + tid;
        if (e < Et) {
            int d = (e < E) ? ei[E + e] : e - E;
            atomicAdd(&counts[d], 1);
            atomicAdd(&lhist[d >> BSH], 1);
        }
    }
    __syncthreads();
    for (int b = tid; b < NB; b += 256) {
        int h = lhist[b];
        if (h > 0) atomicAdd(&bucketCnt[b], h);
    }
}

__global__ __launch_bounds__(1024) void scan_blocks(int* __restrict__ counts,
                                                    int* __restrict__ blockSums, int N) {
    __shared__ int wsum[16];
    const int tid = threadIdx.x;
    const int lane = tid & 63;
    const int wave = tid >> 6;
    int i = blockIdx.x * 1024 + tid;
    int v = (i < N) ? counts[i] : 0;
    int s = v;
    #pragma unroll
    for (int off = 1; off < 64; off <<= 1) {
        int t = __shfl_up(s, off);
        if (lane >= off) s += t;
    }
    if (lane == 63) wsum[wave] = s;
    __syncthreads();
    if (wave == 0 && lane < 16) {
        int ws = wsum[lane];
        #pragma unroll
        for (int off = 1; off < 16; off <<= 1) {
            int t = __shfl_up(ws, off);
            if (lane >= off) ws += t;
        }
        wsum[lane] = ws;
    }
    __syncthreads();
    int waveOff = (wave > 0) ? wsum[wave - 1] : 0;
    int incl = s + waveOff;
    if (i < N) counts[i] = incl - v;
    if (tid == 1023) blockSums[blockIdx.x] = incl;
}

__global__ void scan_add2(const int* __restrict__ excl, const int* __restrict__ blockSums,
                          int nb, int* __restrict__ offsets, int N, int Et) {
    __shared__ int sbs[64];
    if (threadIdx.x < 64) {
        int lane = threadIdx.x;
        int v = (lane < nb) ? blockSums[lane] : 0;
        int s = v;
        #pragma unroll
        for (int off = 1; off < 64; off <<= 1) {
            int t = __shfl_up(s, off);
            if (lane >= off) s += t;
        }
        sbs[lane] = s - v;                 // exclusive
    }
    __syncthreads();
    int i = blockIdx.x * 256 + threadIdx.x;
    if (i < N) offsets[i] = excl[i] + sbs[i >> 10];
    if (i == N) offsets[N] = Et;
}

// ------------- bucket scan: exclusive prefix over NB buckets (single block) -------------
__global__ __launch_bounds__(1024) void bucket_scan(const int* __restrict__ bucketCnt,
                                                    int* __restrict__ bucketOff,
                                                    int* __restrict__ bucketCur,
                                                    int NB, int Et) {
    __shared__ int s[1024];
    const int tid = threadIdx.x;
    int v = (tid < NB) ? bucketCnt[tid] : 0;
    s[tid] = v;
    __syncthreads();
    #pragma unroll
    for (int off = 1; off < 1024; off <<= 1) {
        int t = (tid >= off) ? s[tid - off] : 0;
        __syncthreads();
        s[tid] += t;
        __syncthreads();
    }
    if (tid < NB) {
        int ex = s[tid] - v;               // exclusive
        bucketOff[tid] = ex;
        bucketCur[tid] = ex;
    }
    if (tid == 0) bucketOff[NB] = Et;
}

// ------------- bucket scatter: edges -> bucketBuf (block-aggregated base claims) -------------
__global__ __launch_bounds__(256) void bucket_scatter(const int* __restrict__ ei,
                                                      int* __restrict__ bucketCur,
                                                      uint2* __restrict__ bucketBuf,
                                                      int E, int Et, int NB) {
    __shared__ int lhist[1024];
    __shared__ int lbase[1024];
    const int tid = threadIdx.x;
    for (int b = tid; b < NB; b += 256) lhist[b] = 0;
    __syncthreads();
    const int base = blockIdx.x * 4096;
    int sv[16], dv[16];
    #pragma unroll
    for (int k = 0; k < 16; k++) {
        int e = base + k * 256 + tid;
        if (e < Et) {
            int ss, dd;
            if (e < E) { ss = ei[e]; dd = ei[E + e]; } else { ss = dd = e - E; }
            sv[k] = ss; dv[k] = dd;
            atomicAdd(&lhist[dd >> BSH], 1);
        } else dv[k] = -1;
    }
    __syncthreads();
    for (int b = tid; b < NB; b += 256) {
        int h = lhist[b];
        lbase[b] = (h > 0) ? atomicAdd(&bucketCur[b], h) : 0;
    }
    __syncthreads();
    // reuse lhist as rank counters
    for (int b = tid; b < NB; b += 256) lhist[b] = 0;
    __syncthreads();
    #pragma unroll
    for (int k = 0; k < 16; k++) {
        if (dv[k] >= 0) {
            int b = dv[k] >> BSH;
            int r = atomicAdd(&lhist[b], 1);
            bucketBuf[lbase[b] + r] = (uint2){(unsigned int)sv[k], (unsigned int)dv[k]};
        }
    }
}

// ------------- bucket-local sort: one block per bucket; writes srcS within a ~9KB window -------------
__global__ __launch_bounds__(256) void bucket_sort(const uint2* __restrict__ bucketBuf,
                                                   const int* __restrict__ bucketOff,
                                                   const int* __restrict__ offsets,
                                                   int* __restrict__ srcS) {
    __shared__ int cnt[128];
    const int tid = threadIdx.x;
    const int b = blockIdx.x;
    if (tid < 128) cnt[tid] = 0;
    __syncthreads();
    const int node0 = b << BSH;
    const int s0 = bucketOff[b], s1 = bucketOff[b + 1];
    for (int i = s0 + tid; i < s1; i += 256) {
        uint2 e = bucketBuf[i];
        int dl = (int)e.y - node0;
        int r = atomicAdd(&cnt[dl], 1);
        srcS[offsets[e.y] + r] = (int)e.x;
    }
}

// ------------- conv1 aggregate of RAW x (32-dim fp8) -> aggX8 [N,128] fp8 -------------
__global__ __launch_bounds__(256) void gat_agg_x32(
        const int* __restrict__ offsets, const int* __restrict__ srcS,
        const float4* __restrict__ a_s4, const float4* __restrict__ a_d4,
        const unsigned char* __restrict__ x8,      // [N,32] fp8
        unsigned char* __restrict__ aggX8,         // [N,128] fp8
        int N) {
    __shared__ float4 wlds[4][64];
    __shared__ int slds[4][64];
    const int wid = threadIdx.x >> 6;
    const int n = blockIdx.x * 4 + wid;
    if (n >= N) return;
    const int lane = threadIdx.x & 63;
    const int q = lane >> 4;
    const int l16 = lane & 15;
    const int start = offsets[n], end = offsets[n + 1];
    const float4 ad = a_d4[n];
    float2 acc0 = {0,0}, acc1 = {0,0}, acc2 = {0,0}, acc3 = {0,0};
    float4 den = {0,0,0,0};
    const int loff = l16 << 1;     // 2 channels of 32 (bytes in fp8)

    for (int e0 = start; e0 < end; e0 += 64) {
        const int cnt = min(64, end - e0);
        if (lane < cnt) {
            int sB = srcS[e0 + lane];
            slds[wid][lane] = sB;
            const float4 as = a_s4[sB];
            float x0 = as.x + ad.x; x0 = fmaxf(x0, NEG_SLOPE * x0);
            float x1 = as.y + ad.y; x1 = fmaxf(x1, NEG_SLOPE * x1);
            float x2 = as.z + ad.z; x2 = fmaxf(x2, NEG_SLOPE * x2);
            float x3 = as.w + ad.w; x3 = fmaxf(x3, NEG_SLOPE * x3);
            wlds[wid][lane] = (float4){exp2f(x0), exp2f(x1), exp2f(x2), exp2f(x3)};
        }
        int j = q;
        for (; j + 12 < cnt; j += 16) {
            int ss[4]; float4 ww[4]; unsigned int gg[4];
            #pragma unroll
            for (int u = 0; u < 4; u++) {
                ss[u] = slds[wid][j + 4 * u];
                ww[u] = wlds[wid][j + 4 * u];
            }
            #pragma unroll
            for (int u = 0; u < 4; u++)
                gg[u] = *(const unsigned short*)&x8[((size_t)ss[u] << 5) + loff];
            #pragma unroll
            for (int u = 0; u < 4; u++) {
                float vl, vh;
                fp8x2_to_f32(gg[u], vl, vh);
                acc0.x += ww[u].x * vl; acc0.y += ww[u].x * vh;
                acc1.x += ww[u].y * vl; acc1.y += ww[u].y * vh;
                acc2.x += ww[u].z * vl; acc2.y += ww[u].z * vh;
                acc3.x += ww[u].w * vl; acc3.y += ww[u].w * vh;
                den.x += ww[u].x; den.y += ww[u].y; den.z += ww[u].z; den.w += ww[u].w;
            }
        }
        for (; j + 4 < cnt; j += 8) {
            const int s0 = slds[wid][j], s1 = slds[wid][j + 4];
            const float4 w0 = wlds[wid][j], w1 = wlds[wid][j + 4];
            const unsigned int g0 = *(const unsigned short*)&x8[((size_t)s0 << 5) + loff];
            const unsigned int g1 = *(const unsigned short*)&x8[((size_t)s1 << 5) + loff];
            float vl0, vh0, vl1, vh1;
            fp8x2_to_f32(g0, vl0, vh0);
            fp8x2_to_f32(g1, vl1, vh1);
            acc0.x += w0.x * vl0 + w1.x * vl1; acc0.y += w0.x * vh0 + w1.x * vh1;
            acc1.x += w0.y * vl0 + w1.y * vl1; acc1.y += w0.y * vh0 + w1.y * vh1;
            acc2.x += w0.z * vl0 + w1.z * vl1; acc2.y += w0.z * vh0 + w1.z * vh1;
            acc3.x += w0.w * vl0 + w1.w * vl1; acc3.y += w0.w * vh0 + w1.w * vh1;
            den.x += w0.x + w1.x; den.y += w0.y + w1.y;
            den.z += w0.z + w1.z; den.w += w0.w + w1.w;
        }
        for (; j < cnt; j += 4) {
            const int s = slds[wid][j];
            const float4 w = wlds[wid][j];
            const unsigned int g = *(const unsigned short*)&x8[((size_t)s << 5) + loff];
            float vl, vh;
            fp8x2_to_f32(g, vl, vh);
            acc0.x += w.x * vl; acc0.y += w.x * vh;
            acc1.x += w.y * vl; acc1.y += w.y * vh;
            acc2.x += w.z * vl; acc2.y += w.z * vh;
            acc3.x += w.w * vl; acc3.y += w.w * vh;
            den.x += w.x; den.y += w.y; den.z += w.z; den.w += w.w;
        }
    }
    #pragma unroll
    for (int off = 16; off < 64; off <<= 1) {
        acc0.x += __shfl_xor(acc0.x, off); acc0.y += __shfl_xor(acc0.y, off);
        acc1.x += __shfl_xor(acc1.x, off); acc1.y += __shfl_xor(acc1.y, off);
        acc2.x += __shfl_xor(acc2.x, off); acc2.y += __shfl_xor(acc2.y, off);
        acc3.x += __shfl_xor(acc3.x, off); acc3.y += __shfl_xor(acc3.y, off);
        den.x += __shfl_xor(den.x, off); den.y += __shfl_xor(den.y, off);
        den.z += __shfl_xor(den.z, off); den.w += __shfl_xor(den.w, off);
    }
    if (q == 0) {
        const float i0 = 1.0f / (den.x + 1e-16f);
        const float i1 = 1.0f / (den.y + 1e-16f);
        const float i2 = 1.0f / (den.z + 1e-16f);
        const float i3 = 1.0f / (den.w + 1e-16f);
        unsigned short o0 = (unsigned short)f32_to_fp8(acc0.x * i0)
                          | ((unsigned short)f32_to_fp8(acc0.y * i0) << 8);
        unsigned short o1 = (unsigned short)f32_to_fp8(acc1.x * i1)
                          | ((unsigned short)f32_to_fp8(acc1.y * i1) << 8);
        unsigned short o2 = (unsigned short)f32_to_fp8(acc2.x * i2)
                          | ((unsigned short)f32_to_fp8(acc2.y * i2) << 8);
        unsigned short o3 = (unsigned short)f32_to_fp8(acc3.x * i3)
                          | ((unsigned short)f32_to_fp8(acc3.y * i3) << 8);
        *(unsigned short*)&aggX8[((size_t)n << 7) + 0 * 32 + loff] = o0;
        *(unsigned short*)&aggX8[((size_t)n << 7) + 1 * 32 + loff] = o1;
        *(unsigned short*)&aggX8[((size_t)n << 7) + 2 * 32 + loff] = o2;
        *(unsigned short*)&aggX8[((size_t)n << 7) + 3 * 32 + loff] = o3;
    }
}

// ------------- conv2 aggregate over FP8 table (4B/lane gather) + bias + ELU + conv3 scores;
// output table written fp8 (feeds all-fp8 conv3 GEMM) -------------
__global__ __launch_bounds__(256) void gat_fused4(
        const int* __restrict__ offsets, const int* __restrict__ srcS,
        const float4* __restrict__ a_s4, const float4* __restrict__ a_d4,
        const unsigned char* __restrict__ h8, const float* __restrict__ bias,
        const float* __restrict__ u3s, const float* __restrict__ u3d,
        float* __restrict__ a_s3, float* __restrict__ a_d3,
        unsigned char* __restrict__ outC8, int N) {
    __shared__ float wlds[4][64][4];
    __shared__ int slds[4][64];
    const int wid = threadIdx.x >> 6;
    const int n = blockIdx.x * 4 + wid;
    if (n >= N) return;
    const int lane = threadIdx.x & 63;
    const int quad = lane >> 4;
    const int start = offsets[n], end = offsets[n + 1];
    const float4 ad = a_d4[n];
    float4 acc = {0, 0, 0, 0};
    float den = 0.0f;
    const int loff = lane << 2;                  // channel index == byte offset (fp8)

    for (int e0 = start; e0 < end; e0 += 64) {
        const int cnt = min(64, end - e0);
        if (lane < cnt) {
            int sB = srcS[e0 + lane];
            slds[wid][lane] = sB;
            const float4 as = a_s4[sB];
            float x0 = as.x + ad.x; x0 = fmaxf(x0, NEG_SLOPE * x0);
            float x1 = as.y + ad.y; x1 = fmaxf(x1, NEG_SLOPE * x1);
            float x2 = as.z + ad.z; x2 = fmaxf(x2, NEG_SLOPE * x2);
            float x3 = as.w + ad.w; x3 = fmaxf(x3, NEG_SLOPE * x3);
            wlds[wid][lane][0] = exp2f(x0);
            wlds[wid][lane][1] = exp2f(x1);
            wlds[wid][lane][2] = exp2f(x2);
            wlds[wid][lane][3] = exp2f(x3);
        }
        int j = 0;
        for (; j + 4 <= cnt; j += 4) {
            const int s0 = __builtin_amdgcn_readfirstlane(slds[wid][j + 0]);
            const int s1 = __builtin_amdgcn_readfirstlane(slds[wid][j + 1]);
            const int s2 = __builtin_amdgcn_readfirstlane(slds[wid][j + 2]);
            const int s3 = __builtin_amdgcn_readfirstlane(slds[wid][j + 3]);
            const float w0 = wlds[wid][j + 0][quad];
            const float w1 = wlds[wid][j + 1][quad];
            const float w2 = wlds[wid][j + 2][quad];
            const float w3 = wlds[wid][j + 3][quad];
            const unsigned int g0 = *(const unsigned int*)&h8[((size_t)s0 << 8) + loff];
            const unsigned int g1 = *(const unsigned int*)&h8[((size_t)s1 << 8) + loff];
            const unsigned int g2 = *(const unsigned int*)&h8[((size_t)s2 << 8) + loff];
            const unsigned int g3 = *(const unsigned int*)&h8[((size_t)s3 << 8) + loff];
            float v0, v1, v2, v3;
            fp8x4_to_f32(g0, v0, v1, v2, v3);
            acc.x += w0 * v0; acc.y += w0 * v1; acc.z += w0 * v2; acc.w += w0 * v3;
            fp8x4_to_f32(g1, v0, v1, v2, v3);
            acc.x += w1 * v0; acc.y += w1 * v1; acc.z += w1 * v2; acc.w += w1 * v3;
            fp8x4_to_f32(g2, v0, v1, v2, v3);
            acc.x += w2 * v0; acc.y += w2 * v1; acc.z += w2 * v2; acc.w += w2 * v3;
            fp8x4_to_f32(g3, v0, v1, v2, v3);
            acc.x += w3 * v0; acc.y += w3 * v1; acc.z += w3 * v2; acc.w += w3 * v3;
            den += (w0 + w1) + (w2 + w3);
        }
        for (; j < cnt; j++) {
            const int s = __builtin_amdgcn_readfirstlane(slds[wid][j]);
            const float w = wlds[wid][j][quad];
            const unsigned int g = *(const unsigned int*)&h8[((size_t)s << 8) + loff];
            float v0, v1, v2, v3;
            fp8x4_to_f32(g, v0, v1, v2, v3);
            acc.x += w * v0; acc.y += w * v1; acc.z += w * v2; acc.w += w * v3;
            den += w;
        }
    }

    const float inv = 1.0f / (den + 1e-16f);
    const float4 bb = *(const float4*)&bias[loff];
    float v0 = acc.x * inv + bb.x; v0 = (v0 > 0.0f) ? v0 : expm1f(v0);
    float v1 = acc.y * inv + bb.y; v1 = (v1 > 0.0f) ? v1 : expm1f(v1);
    float v2 = acc.z * inv + bb.z; v2 = (v2 > 0.0f) ? v2 : expm1f(v2);
    float v3 = acc.w * inv + bb.w; v3 = (v3 > 0.0f) ? v3 : expm1f(v3);
    // conv3 scores from the fp32 h3 row (each lane owns 4 channels)
    {
        const float4 us = *(const float4*)&u3s[loff];
        const float4 ud = *(const float4*)&u3d[loff];
        float ps = v0 * us.x + v1 * us.y + v2 * us.z + v3 * us.w;
        float pd = v0 * ud.x + v1 * ud.y + v2 * ud.z + v3 * ud.w;
        #pragma unroll
        for (int off = 1; off < 64; off <<= 1) {
            ps += __shfl_xor(ps, off);
            pd += __shfl_xor(pd, off);
        }
        if (lane == 0) {
            a_s3[n] = ps * LOG2E;
            a_d3[n] = pd * LOG2E;
        }
    }
    unsigned int o = (unsigned int)f32_to_fp8(v0)
                   | ((unsigned int)f32_to_fp8(v1) << 8)
                   | ((unsigned int)f32_to_fp8(v2) << 16)
                   | ((unsigned int)f32_to_fp8(v3) << 24);
    *(unsigned int*)&outC8[(size_t)n * 256 + loff] = o;
}

// ------------- H=1 fused (conv3): wave/node gather over FP8 table + PARTITIONED fused mean-pool -------------
__global__ __launch_bounds__(256) void gat_fused1(
        const int* __restrict__ offsets, const int* __restrict__ srcS,
        const float* __restrict__ a_s, const float* __restrict__ a_d,
        const unsigned char* __restrict__ h8, const float* __restrict__ bias,
        const int* __restrict__ batch,
        float* __restrict__ pooledP, float* __restrict__ cntP, int N, int G) {
    __shared__ float wlds[4][64];
    __shared__ int slds[4][64];
    __shared__ float2 sOut[4][32];
    __shared__ int sG[4];
    const int wid = threadIdx.x >> 6;
    const int n = blockIdx.x * 4 + wid;
    const bool valid = n < N;                  // no early return: all waves reach the barrier
    const int lane = threadIdx.x & 63;
    const int half = lane >> 5;
    const int l32 = lane & 31;
    const int start = valid ? offsets[n] : 0;
    const int end   = valid ? offsets[n + 1] : 0;
    const float ad  = valid ? a_d[n] : 0.0f;
    float accx = 0.0f, accy = 0.0f, den = 0.0f;
    const int loff = l32 << 1;                 // 2 channels (bytes in fp8)

    for (int e0 = start; e0 < end; e0 += 64) {
        const int cnt_ = min(64, end - e0);
        if (lane < cnt_) {
            int sB = srcS[e0 + lane];
            slds[wid][lane] = sB;
            float ev = a_s[sB] + ad;
            ev = fmaxf(ev, NEG_SLOPE * ev);
            wlds[wid][lane] = exp2f(ev);
        }
        int j = half;
        for (; j + 8 <= cnt_ + half; j += 8) {
            const int s0 = slds[wid][j + 0];
            const int s1 = slds[wid][j + 2];
            const int s2 = slds[wid][j + 4];
            const int s3 = slds[wid][j + 6];
            const float w0 = wlds[wid][j + 0];
            const float w1 = wlds[wid][j + 2];
            const float w2 = wlds[wid][j + 4];
            const float w3 = wlds[wid][j + 6];
            const unsigned int g0 = *(const unsigned short*)&h8[((size_t)s0 << 6) + loff];
            const unsigned int g1 = *(const unsigned short*)&h8[((size_t)s1 << 6) + loff];
            const unsigned int g2 = *(const unsigned short*)&h8[((size_t)s2 << 6) + loff];
            const unsigned int g3 = *(const unsigned short*)&h8[((size_t)s3 << 6) + loff];
            float vl, vh;
            fp8x2_to_f32(g0, vl, vh); accx += w0 * vl; accy += w0 * vh;
            fp8x2_to_f32(g1, vl, vh); accx += w1 * vl; accy += w1 * vh;
            fp8x2_to_f32(g2, vl, vh); accx += w2 * vl; accy += w2 * vh;
            fp8x2_to_f32(g3, vl, vh); accx += w3 * vl; accy += w3 * vh;
            den += (w0 + w1) + (w2 + w3);
        }
        for (; j < cnt_; j += 2) {
            const int s = slds[wid][j];
            const float w = wlds[wid][j];
            const unsigned int g = *(const unsigned short*)&h8[((size_t)s << 6) + loff];
            float vl, vh;
            fp8x2_to_f32(g, vl, vh);
            accx += w * vl;
            accy += w * vh;
            den += w;
        }
    }
    accx += __shfl_xor(accx, 32);
    accy += __shfl_xor(accy, 32);
    den  += __shfl_xor(den, 32);
    if (half == 0) {
        if (valid) {
            const float inv = 1.0f / (den + 1e-16f);
            sOut[wid][l32] = (float2){accx * inv + bias[loff], accy * inv + bias[loff + 1]};
        } else {
            sOut[wid][l32] = (float2){0.0f, 0.0f};
        }
        if (l32 == 0) sG[wid] = valid ? batch[n] : -1;
    }
    __syncthreads();
    const int p = blockIdx.x & 63;
    if (wid == 0 && half == 0) {
        const int g0 = sG[0], g1 = sG[1], g2 = sG[2], g3 = sG[3];
        if (g0 >= 0 && g1 == g0 && g2 == g0 && g3 == g0) {
            const float2 s0 = sOut[0][l32], s1 = sOut[1][l32];
            const float2 s2 = sOut[2][l32], s3 = sOut[3][l32];
            float* base = pooledP + ((size_t)p * G + g0) * 64;
            atomicAdd(&base[loff],     (s0.x + s1.x) + (s2.x + s3.x));
            atomicAdd(&base[loff + 1], (s0.y + s1.y) + (s2.y + s3.y));
            if (l32 == 0) atomicAdd(&cntP[p * G + g0], 4.0f);
        } else {
            #pragma unroll
            for (int w = 0; w < 4; w++) {
                const int g = sG[w];
                if (g >= 0) {
                    const float2 s = sOut[w][l32];
                    float* base = pooledP + ((size_t)p * G + g) * 64;
                    atomicAdd(&base[loff], s.x);
                    atomicAdd(&base[loff + 1], s.y);
                    if (l32 == 0) atomicAdd(&cntP[p * G + g], 1.0f);
                }
            }
        }
    }
}

// ------------- decoder head: one block per graph (reduces 64 pool partitions first) -------------
__global__ __launch_bounds__(256) void final_kernel(
        const float* __restrict__ pooledP, const float* __restrict__ cntP,
        const float* __restrict__ gf, const float* __restrict__ Wg,
        const float* __restrict__ bg, const float* __restrict__ Wd1,
        const float* __restrict__ bd1, const float* __restrict__ gamma,
        const float* __restrict__ beta, const float* __restrict__ Wd2,
        const float* __restrict__ bd2, float* __restrict__ out, int G) {
    const int g = blockIdx.x;
    const int tid = threadIdx.x;
    const int lane = tid & 63;
    const int wave = tid >> 6;
    __shared__ float sPart[4][64];
    __shared__ float sCntTot;
    __shared__ float spg[128];
    __shared__ float sz[64];
    __shared__ float wred[8];

    {   // partition reduce: wave pg sums partitions [pg*16, pg*16+16)
        const int c = lane;
        const int pg = wave;
        float a = 0.0f;
        #pragma unroll
        for (int p = 0; p < 16; p++)
            a += pooledP[((size_t)(pg * 16 + p) * G + g) * 64 + c];
        sPart[pg][c] = a;
        if (pg == 1) {
            float cv = cntP[c * G + g];
            #pragma unroll
            for (int off = 32; off > 0; off >>= 1) cv += __shfl_xor(cv, off);
            if (c == 0) sCntTot = cv;
        }
    }
    __syncthreads();
    if (tid < 64) {
        spg[tid] = (sPart[0][tid] + sPart[1][tid] + sPart[2][tid] + sPart[3][tid])
                   / fmaxf(sCntTot, 1.0f);
    } else if (tid < 128) {
        int c = tid - 64;
        float v = bg[c];
        #pragma unroll
        for (int k = 0; k < 4; k++) v += gf[g * 4 + k] * Wg[k * 64 + c];
        spg[64 + c] = fmaxf(v, 0.0f);
    }
    __syncthreads();
    if (tid < 64) {
        float v = bd1[tid];
        #pragma unroll 8
        for (int k = 0; k < 128; k++) v += spg[k] * Wd1[k * 64 + tid];
        v = v * gamma[tid] + beta[tid];
        sz[tid] = fmaxf(v, 0.0f);
    }
    __syncthreads();
    float v = bd2[tid];
    #pragma unroll 8
    for (int k = 0; k < 64; k++) v += sz[k] * Wd2[k * 256 + tid];
    float m = v;
    #pragma unroll
    for (int off = 32; off > 0; off >>= 1) m = fmaxf(m, __shfl_xor(m, off));
    if (lane == 0) wred[wave] = m;
    __syncthreads();
    float M = fmaxf(fmaxf(wred[0], wred[1]), fmaxf(wred[2], wred[3]));
    float e = expf(v - M);
    float s = e;
    #pragma unroll
    for (int off = 32; off > 0; off >>= 1) s += __shfl_xor(s, off);
    if (lane == 0) wred[4 + wave] = s;
    __syncthreads();
    float S = (wred[4] + wred[5]) + (wred[6] + wred[7]);
    out[g * 256 + tid] = e / S;
}

extern "C" void kernel_launch(void* const* d_in, const int* in_sizes, int n_in,
                              void* d_out, int out_size, void* d_ws, size_t ws_size,
                              hipStream_t stream) {
    const float* x     = (const float*)d_in[0];
    const int*   ei    = (const int*)  d_in[1];
    const int*   batch = (const int*)  d_in[2];
    const float* gf    = (const float*)d_in[3];
    const float* W_enc = (const float*)d_in[4];
    const float* b_enc = (const float*)d_in[5];
    const float* W1  = (const float*)d_in[6];
    const float* as1 = (const float*)d_in[7];
    const float* ad1 = (const float*)d_in[8];
    const float* b1  = (const float*)d_in[9];
    const float* W2  = (const float*)d_in[10];
    const float* as2 = (const float*)d_in[11];
    const float* ad2 = (const float*)d_in[12];
    const float* b2  = (const float*)d_in[13];
    const float* W3  = (const float*)d_in[14];
    const float* as3 = (const float*)d_in[15];
    const float* ad3 = (const float*)d_in[16];
    const float* b3  = (const float*)d_in[17];
    const float* Wg  = (const float*)d_in[18];
    const float* bg  = (const float*)d_in[19];
    const float* Wd1 = (const float*)d_in[20];
    const float* bd1 = (const float*)d_in[21];
    const float* gm  = (const float*)d_in[22];
    const float* bt  = (const float*)d_in[23];
    const float* Wd2 = (const float*)d_in[24];
    const float* bd2 = (const float*)d_in[25];

    const int N  = in_sizes[2];
    const int E  = in_sizes[1] / 2;
    const int G  = in_sizes[3] / 4;
    const int Et = E + N;
    const int NB = (N + 127) >> 7;               // dst-buckets of 128 nodes (<=1024)

    unsigned short* h16a = (unsigned short*)d_ws;                // slot: conv2 fp8 table [N,256]B
    unsigned short* h16b = h16a + (size_t)N * 256;               // [N,256]: aggX8 [N,128]B early, then conv2 agg out fp8
    unsigned short* h1_16 = h16b + (size_t)N * 256;              // slot: conv3 fp8 table [N,64]B
    unsigned short* x16  = h1_16 + (size_t)N * 64;               // slot: x fp8 table [N,32]B
    unsigned char* Wc1t8 = (unsigned char*)(x16 + (size_t)N * 32);   // [4][64][32] fp8
    unsigned char* Wt2_8 = Wc1t8 + 4 * 64 * 32;                  // [256][256] fp8
    unsigned char* Wt3_8 = Wt2_8 + 256 * 256;                    // [64][256] fp8
    float* bc1    = (float*)(Wt3_8 + 64 * 256);                  // [256] (16B-aligned by construction)
    float* a_s    = bc1 + 256;                                   // [N,4]
    float* a_d    = a_s + (size_t)N * 4;                         // [N,4]
    float* a_s3   = a_d + (size_t)N * 4;                         // [N]
    float* a_d3   = a_s3 + N;                                    // [N]
    float* u1s    = a_d3 + N;                                    // [64,4]
    float* u1d    = u1s + 256;                                   // [64,4]
    float* u3s    = u1d + 256;                                   // [256]
    float* u3d    = u3s + 256;                                   // [256]
    float* pooledP = u3d + 256;                                  // [64][G][64]
    float* cntP   = pooledP + (size_t)64 * G * 64;               // [64][G]
    int*   offsets = (int*)(cntP + 64 * G);                      // [N+1]
    int*   srcS    = offsets + (N + 1);                          // [Et]
    int*   counts  = srcS + Et;                                  // [N]
    int*   blockSums = counts + N;                               // [cdiv(N,1024)]
    int*   bucketCnt = blockSums + ((N + 1023) / 1024);          // [NB+1]
    int*   bucketOff = bucketCnt + (NB + 1);                     // [NB+1]
    int*   bucketCur = bucketOff + (NB + 1);                     // [NB]
    uint2* bucketBuf = (uint2*)(((size_t)(bucketCur + NB) + 7) & ~(size_t)7);   // [Et]

    unsigned char* h8a  = (unsigned char*)h16a;                  // fp8 conv2 gather table view
    unsigned char* h8b  = (unsigned char*)h16b;                  // aggX8 early / conv3 GEMM-A (fused4 out)
    unsigned char* h1_8 = (unsigned char*)h1_16;                 // fp8 conv3 gather table view
    unsigned char* x8   = (unsigned char*)x16;                   // fp8 x gather table view

    dim3 blk(256);
    auto cdiv = [](int a, int b) { return (a + b - 1) / b; };
    const int ebBlocks = cdiv(Et, 4096);
    const int rowBlocks = cdiv(N, 64);
    const int nScanBlocks = cdiv(N, 1024);
    const int zc = cdiv(N, 256);
    const int z2 = cdiv(64 * G * 64, 256);

    // ---------------- prep (folded weights + u-vectors + zero-init) + CSR build ----------------
    prep_kernel<<<355 + zc + z2, blk, 0, stream>>>(W_enc, b_enc, W1, W2, W3, as1, ad1, b1,
                                                   as3, ad3, Wc1t8, bc1, Wt2_8, Wt3_8,
                                                   u1s, u1d, u3s, u3d,
                                                   counts, pooledP, cntP, bucketCnt,
                                                   N, G, zc, NB);
    edge_hist_kernel<<<ebBlocks, blk, 0, stream>>>(ei, counts, bucketCnt, E, Et, NB);
    scan_blocks<<<nScanBlocks, 1024, 0, stream>>>(counts, blockSums, N);
    scan_add2<<<cdiv(N + 1, 256), blk, 0, stream>>>(counts, blockSums, nScanBlocks,
                                                    offsets, N, Et);
    bucket_scan<<<1, 1024, 0, stream>>>(bucketCnt, bucketOff, bucketCur, NB, Et);
    bucket_scatter<<<ebBlocks, blk, 0, stream>>>(ei, bucketCur, bucketBuf, E, Et, NB);
    bucket_sort<<<NB, blk, 0, stream>>>(bucketBuf, bucketOff, offsets, srcS);

    // conv1 scores from fp32 x + x->fp8 gather table
    score_x<<<cdiv(N, 32), blk, 0, stream>>>(x, W_enc, b_enc, u1s, u1d, x8, a_s, a_d, N);

    // ---------------- conv1 aggregate (fp8 x -> fp8 aggX) -> all-fp8 fused conv1+conv2 GEMM ----------------
    gat_agg_x32<<<cdiv(N, 4), blk, 0, stream>>>(offsets, srcS, (const float4*)a_s,
                                                (const float4*)a_d, x8, h8b, N);
    gemm_c12<<<rowBlocks, blk, 0, stream>>>(h8b, Wc1t8, bc1, Wt2_8, as2, ad2,
                                            a_s, a_d, h8a, N);

    // ---------------- conv2 aggregate over fp8 table (+conv3 scores fused), fp8 out ----------------
    gat_fused4<<<cdiv(N, 4), blk, 0, stream>>>(offsets, srcS, (const float4*)a_s,
                                               (const float4*)a_d, h8a, b2,
                                               u3s, u3d, a_s3, a_d3, h8b, N);

    // ---------------- conv3: all-fp8 GEMM -> aggregate + partitioned pool ----------------
    gemm_c3<<<rowBlocks, blk, 0, stream>>>(h8b, Wt3_8, h1_8, N);
    gat_fused1<<<cdiv(N, 4), blk, 0, stream>>>(offsets, srcS, a_s3, a_d3, h1_8, b3,
                                               batch, pooledP, cntP, N, G);

    // ---------------- decoder head ----------------
    final_kernel<<<G, blk, 0, stream>>>(pooledP, cntP, gf, Wg, bg, Wd1, bd1, gm, bt, Wd2, bd2,
                                        (float*)d_out, G);
}